// Round 3
// baseline (862.235 us; speedup 1.0000x reference)
//
#include <hip/hip_runtime.h>
#include <hip/hip_bf16.h>

typedef __hip_bfloat16 bf16;

// Problem constants
// B=32, N=64, F_ATOM=82, F_PATH=102, H=8, DK=80, HIDDEN=256, DEPTH=3
// Inputs: fp32. Output: fp32. hb = h*B + b  (H-major per reference transpose)

// ---------------------------------------------------------------------------
// Kernel A: a_h0[(h*32+b)*64 + i][k] = sum_f atom[b,i,f] * W_atom_i[f, h*80+k]
// one block per (b,i); 2048 blocks x 256 threads
// ---------------------------------------------------------------------------
__global__ __launch_bounds__(256) void atom_proj_kernel(
    const float* __restrict__ atom, const float* __restrict__ W,
    float* __restrict__ ah0)
{
    __shared__ float arow[82];
    int bi = blockIdx.x;            // b*64 + i
    int b = bi >> 6, i = bi & 63;
    int t = threadIdx.x;
    if (t < 82) arow[t] = atom[(size_t)bi * 82 + t];
    __syncthreads();
    for (int c = t; c < 640; c += 256) {
        float acc = 0.f;
        #pragma unroll 2
        for (int f = 0; f < 82; f++) acc += arow[f] * W[f * 640 + c];
        int h = c / 80, k = c - h * 80;
        ah0[(((size_t)(h * 32 + b)) * 64 + i) * 80 + k] = acc;
    }
}

// ---------------------------------------------------------------------------
// Generic tiled GEMM: out[row, out_col0 + c] (+bias) = A[row,:K] @ W[wrow0:wrow0+K, c]
// Tile: 64 rows x 80 cols, K <= 102. W is fp32 with leading dim 80.
// 256 threads: tx=t&15 (cols c*16+tx, c=0..4), ty=t>>4 (rows ty*4+r, r=0..3)
// ---------------------------------------------------------------------------
template <typename OT>
__global__ __launch_bounds__(256) void gemm_tile64x80(
    const float* __restrict__ A, int K,
    const float* __restrict__ W, int wrow0,
    const float* __restrict__ bias,          // [80] or nullptr
    OT* __restrict__ out, int out_ld, int out_col0)
{
    __shared__ float As[64 * 105];          // padded stride 105 (bank-safe)
    __shared__ float Ws[102 * 80];
    int rowBase = blockIdx.x * 64;
    int t = threadIdx.x;

    for (int e = t; e < 64 * K; e += 256) {
        int r = e / K, c = e - r * K;
        As[r * 105 + c] = A[(size_t)(rowBase + r) * K + c];
    }
    for (int e = t; e < K * 80; e += 256) {
        int r = e / 80, c = e - r * 80;
        Ws[r * 80 + c] = W[(size_t)(wrow0 + r) * 80 + c];
    }
    __syncthreads();

    int tx = t & 15, ty = t >> 4;
    float acc[4][5];
    #pragma unroll
    for (int r = 0; r < 4; r++)
        #pragma unroll
        for (int c = 0; c < 5; c++) acc[r][c] = 0.f;

    for (int k = 0; k < K; k++) {
        float a0 = As[(ty * 4 + 0) * 105 + k];
        float a1 = As[(ty * 4 + 1) * 105 + k];
        float a2 = As[(ty * 4 + 2) * 105 + k];
        float a3 = As[(ty * 4 + 3) * 105 + k];
        float w[5];
        #pragma unroll
        for (int c = 0; c < 5; c++) w[c] = Ws[k * 80 + c * 16 + tx];
        #pragma unroll
        for (int c = 0; c < 5; c++) {
            acc[0][c] += a0 * w[c];
            acc[1][c] += a1 * w[c];
            acc[2][c] += a2 * w[c];
            acc[3][c] += a3 * w[c];
        }
    }

    float bv[5];
    #pragma unroll
    for (int c = 0; c < 5; c++) bv[c] = bias ? bias[c * 16 + tx] : 0.f;
    #pragma unroll
    for (int r = 0; r < 4; r++) {
        size_t row = rowBase + ty * 4 + r;
        #pragma unroll
        for (int c = 0; c < 5; c++)
            out[row * out_ld + out_col0 + c * 16 + tx] = (OT)(acc[r][c] + bv[c]);
    }
}

// ---------------------------------------------------------------------------
// Kernel D: fused score MLP + masked softmax + message + residual relu
// grid = (i=64, hb=256); block = 256 threads; one block per (hb, i)
// UVAM layout per row (hb*64+j): [0:80]=U+b_attn_h  [80:160]=V  [160:240]=AM1  [240:320]=AM2
// ---------------------------------------------------------------------------
__global__ __launch_bounds__(256) void attn_layer_kernel(
    const float* __restrict__ UVAM,
    const bf16* __restrict__ P,        // [32*4096, 80] path part of score pre-act
    const bf16* __restrict__ PM3,      // [32*4096, 80] path @ M3
    const float* __restrict__ mask,    // [32,64,64]
    const float* __restrict__ w_attn_o, // [80]
    const float* __restrict__ b_attn_o, // [1]
    const float* __restrict__ b_msg_h,  // [80]
    const float* __restrict__ ah0,     // residual base [16384,80]
    float* __restrict__ ah_next)
{
    __shared__ float Ps[64 * 80];
    __shared__ float Ms[64 * 80];
    __shared__ float Vs[64 * 80];
    __shared__ float Ub[80], wo[80], bm[80];
    __shared__ float part[4][64];
    __shared__ float probs[64];
    __shared__ float sum_p_sh;

    int i = blockIdx.x, hb = blockIdx.y;
    int b = hb & 31;                    // hb = h*32 + b
    int t = threadIdx.x;
    size_t pbase = ((size_t)b * 4096 + (size_t)i * 64) * 80;  // P row (b,i,0)
    size_t vbase = (size_t)hb * 64 * 320;

    for (int e = t; e < 64 * 80; e += 256) {
        int j = e / 80, k = e - j * 80;
        Ps[e] = (float)P[pbase + e];
        Ms[e] = UVAM[vbase + (size_t)j * 320 + 240 + k] + (float)PM3[pbase + e];
        Vs[e] = UVAM[vbase + (size_t)j * 320 + 80 + k];
    }
    if (t < 80) {
        Ub[t] = UVAM[vbase + (size_t)i * 320 + t];   // b_attn_h already folded in
        wo[t] = w_attn_o[t];
        bm[t] = b_msg_h[t];
    }
    __syncthreads();

    // ---- scores: 4 k-groups of 20 per j ----
    {
        int j = t & 63, kg = t >> 6;
        float partial = 0.f;
        int k0 = kg * 20;
        #pragma unroll 4
        for (int k = k0; k < k0 + 20; k++) {
            float x = Ub[k] + Vs[j * 80 + k] + Ps[j * 80 + k];
            x = x > 0.f ? x : 0.2f * x;   // leaky_relu(0.2)
            partial += x * wo[k];
        }
        part[kg][j] = partial;
    }
    __syncthreads();

    // ---- masked softmax over j (wave 0 only; exact reference semantics) ----
    if (t < 64) {
        float mj = mask[(size_t)b * 4096 + (size_t)i * 64 + t];
        float s = (part[0][t] + part[1][t] + part[2][t] + part[3][t]
                   + b_attn_o[0]) * mj;
        float m = s;
        #pragma unroll
        for (int off = 1; off < 64; off <<= 1) m = fmaxf(m, __shfl_xor(m, off, 64));
        float e = expf(s - m) * mj;
        float d = e;
        #pragma unroll
        for (int off = 1; off < 64; off <<= 1) d += __shfl_xor(d, off, 64);
        float p = e / (d + 1e-20f) * mj;
        probs[t] = p;
        float sp = p;
        #pragma unroll
        for (int off = 1; off < 64; off <<= 1) sp += __shfl_xor(sp, off, 64);
        if (t == 0) sum_p_sh = sp;
    }
    __syncthreads();

    // ---- message + msg@W_msg_h (factored) + bias + residual + relu ----
    if (t < 80) {
        float acc = 0.f;
        for (int jj = 0; jj < 64; jj++) acc += probs[jj] * Ms[jj * 80 + t];
        float am1 = UVAM[vbase + (size_t)i * 320 + 160 + t];
        size_t orow = ((size_t)hb * 64 + i) * 80 + t;
        float pre = sum_p_sh * am1 + acc + bm[t] + ah0[orow];
        ah_next[orow] = pre > 0.f ? pre : 0.f;
    }
}

// ---------------------------------------------------------------------------
// Kernel E: out[row, c] = relu(concat(atom[row,:82], ah_merged[row,:640]) @ W_atom_o + b)
// ah_merged[b*64+i, h*80+k] = ah[(h*32+b)*64+i, k]
// one block per 8 rows; 256 blocks x 256 threads (thread = output col)
// ---------------------------------------------------------------------------
__global__ __launch_bounds__(256) void out_proj_kernel(
    const float* __restrict__ atom, const float* __restrict__ ah,
    const float* __restrict__ W, const float* __restrict__ bo,
    float* __restrict__ out)
{
    __shared__ float xs[8][722];
    int r0 = blockIdx.x * 8;
    int t = threadIdx.x;
    for (int e = t; e < 8 * 722; e += 256) {
        int r = e / 722, f = e - r * 722;
        int row = r0 + r;               // b*64 + i
        float v;
        if (f < 82) {
            v = atom[(size_t)row * 82 + f];
        } else {
            int q = f - 82, h = q / 80, k = q - h * 80;
            int b = row >> 6, i = row & 63;
            v = ah[(((size_t)(h * 32 + b)) * 64 + i) * 80 + k];
        }
        xs[r][f] = v;
    }
    __syncthreads();

    int c = t;
    float bias = bo[c];
    float acc[8];
    #pragma unroll
    for (int r = 0; r < 8; r++) acc[r] = bias;
    for (int f = 0; f < 722; f++) {
        float w = W[(size_t)f * 256 + c];
        #pragma unroll
        for (int r = 0; r < 8; r++) acc[r] += xs[r][f] * w;
    }
    #pragma unroll
    for (int r = 0; r < 8; r++) {
        float v = acc[r] > 0.f ? acc[r] : 0.f;
        out[(size_t)(r0 + r) * 256 + c] = v;
    }
}

// ---------------------------------------------------------------------------
extern "C" void kernel_launch(void* const* d_in, const int* in_sizes, int n_in,
                              void* d_out, int out_size, void* d_ws, size_t ws_size,
                              hipStream_t stream)
{
    const float* atom_input = (const float*)d_in[0];
    const float* path_input = (const float*)d_in[1];
    const float* path_mask  = (const float*)d_in[2];
    const float* W_atom_i   = (const float*)d_in[3];
    const float* W_attn_h   = (const float*)d_in[4];
    const float* b_attn_h   = (const float*)d_in[5];
    const float* W_attn_o   = (const float*)d_in[6];
    const float* b_attn_o   = (const float*)d_in[7];
    const float* W_msg_h    = (const float*)d_in[8];
    const float* b_msg_h    = (const float*)d_in[9];
    const float* W_atom_o   = (const float*)d_in[10];
    const float* b_atom_o   = (const float*)d_in[11];
    float* out = (float*)d_out;

    // workspace carve-up (~79 MB)
    char* ws = (char*)d_ws;
    float* ah0  = (float*)ws;  ws += (size_t)16384 * 80 * 4;
    float* ah1  = (float*)ws;  ws += (size_t)16384 * 80 * 4;
    float* ah2  = (float*)ws;  ws += (size_t)16384 * 80 * 4;
    float* UVAM = (float*)ws;  ws += (size_t)16384 * 320 * 4;
    bf16*  P    = (bf16*)ws;   ws += (size_t)131072 * 80 * 2;
    bf16*  PM3  = (bf16*)ws;   ws += (size_t)131072 * 80 * 2;

    // A0 projection
    atom_proj_kernel<<<2048, 256, 0, stream>>>(atom_input, W_atom_i, ah0);

    // Path GEMMs (once; layer- and head-invariant). Bias NOT folded here (it
    // goes into U).
    gemm_tile64x80<bf16><<<2048, 256, 0, stream>>>(
        path_input, 102, W_attn_h, 160, nullptr, P, 80, 0);
    gemm_tile64x80<bf16><<<2048, 256, 0, stream>>>(
        path_input, 102, W_msg_h, 160, nullptr, PM3, 80, 0);

    const float* cur = ah0;
    float* nxt[2] = { ah1, ah2 };
    for (int layer = 0; layer < 2; layer++) {
        // U (+b_attn_h), V, AM1, AM2 from current a_h
        gemm_tile64x80<float><<<256, 256, 0, stream>>>(
            cur, 80, W_attn_h, 0,  b_attn_h, UVAM, 320, 0);
        gemm_tile64x80<float><<<256, 256, 0, stream>>>(
            cur, 80, W_attn_h, 80, nullptr,  UVAM, 320, 80);
        gemm_tile64x80<float><<<256, 256, 0, stream>>>(
            cur, 80, W_msg_h, 0,   nullptr,  UVAM, 320, 160);
        gemm_tile64x80<float><<<256, 256, 0, stream>>>(
            cur, 80, W_msg_h, 80,  nullptr,  UVAM, 320, 240);

        attn_layer_kernel<<<dim3(64, 256), 256, 0, stream>>>(
            UVAM, P, PM3, path_mask, W_attn_o, b_attn_o, b_msg_h, ah0, nxt[layer]);
        cur = nxt[layer];
    }

    out_proj_kernel<<<256, 256, 0, stream>>>(atom_input, cur, W_atom_o, b_atom_o, out);
}

// Round 4
// 725.873 us; speedup vs baseline: 1.1879x; 1.1879x over previous
//
#include <hip/hip_runtime.h>
#include <hip/hip_bf16.h>

typedef __hip_bfloat16 bf16;
typedef float  float4v __attribute__((ext_vector_type(4)));
typedef unsigned uint4v __attribute__((ext_vector_type(4)));

// B=32, N=64, F_ATOM=82, F_PATH=102, H=8, DK=80, HIDDEN=256, DEPTH=3
// Inputs fp32, output fp32. hb = h*32 + b.

__device__ inline float bflo(unsigned w) { return __uint_as_float(w << 16); }
__device__ inline float bfhi(unsigned w) { return __uint_as_float(w & 0xFFFF0000u); }

// ---------------------------------------------------------------------------
// Prep: pack weights for z-indexed GEMMs.
// Wpath[z][102][80]: z0 = W_attn_h rows 160..261, z1 = W_msg_h rows 160..261
// Wuvam[z][80][80]:  z0 = W_attn_h[0:80], z1 = W_attn_h[80:160],
//                    z2 = W_msg_h[0:80],  z3 = W_msg_h[80:160]
// buvam[4][80]: z0 = b_attn_h, rest 0
// ---------------------------------------------------------------------------
__global__ __launch_bounds__(256) void prep_kernel(
    const float* __restrict__ W_attn_h, const float* __restrict__ b_attn_h,
    const float* __restrict__ W_msg_h,
    float* __restrict__ Wpath, float* __restrict__ Wuvam, float* __restrict__ buvam)
{
    int t = blockIdx.x * 256 + threadIdx.x;
    if (t < 2 * 102 * 80) {
        int z = t / (102 * 80), rc = t - z * (102 * 80);
        const float* src = z ? W_msg_h : W_attn_h;
        Wpath[t] = src[160 * 80 + rc];
    }
    if (t < 4 * 80 * 80) {
        int z = t / 6400, rc = t - z * 6400;
        const float* src = (z < 2) ? W_attn_h : W_msg_h;
        Wuvam[t] = src[(z & 1) * 6400 + rc];
    }
    if (t < 320) buvam[t] = (t < 80) ? b_attn_h[t] : 0.f;
}

// ---------------------------------------------------------------------------
// Kernel A: a_h0[(h*32+b)*64 + i][k] = sum_f atom[b,i,f] * W_atom_i[f, h*80+k]
// ---------------------------------------------------------------------------
__global__ __launch_bounds__(256) void atom_proj_kernel(
    const float* __restrict__ atom, const float* __restrict__ W,
    float* __restrict__ ah0)
{
    __shared__ float arow[82];
    int bi = blockIdx.x;            // b*64 + i
    int b = bi >> 6, i = bi & 63;
    int t = threadIdx.x;
    if (t < 82) arow[t] = atom[(size_t)bi * 82 + t];
    __syncthreads();
    for (int c = t; c < 640; c += 256) {
        float acc = 0.f;
        #pragma unroll 2
        for (int f = 0; f < 82; f++) acc += arow[f] * W[f * 640 + c];
        int h = c / 80, k = c - h * 80;
        ah0[(((size_t)(h * 32 + b)) * 64 + i) * 80 + k] = acc;
    }
}

// ---------------------------------------------------------------------------
// z-indexed tiled GEMM: o[row, c] = A[row,:K] @ Wc[z][:,c] (+ bc[z][c])
// o = out + z*zoff ; blockIdx.x tiles rows by 64, blockIdx.y = z
// ---------------------------------------------------------------------------
template <typename OT>
__global__ __launch_bounds__(256) void gemm_z(
    const float* __restrict__ A, int K,
    const float* __restrict__ Wc, const float* __restrict__ bc,
    OT* __restrict__ out, int out_ld, size_t zoff)
{
    __shared__ float As[64 * 105];
    __shared__ float Ws[102 * 80];
    int z = blockIdx.y;
    const float* W = Wc + (size_t)z * K * 80;
    OT* o = out + (size_t)z * zoff;
    int rowBase = blockIdx.x * 64;
    int t = threadIdx.x;

    for (int e = t; e < 64 * K; e += 256) {
        int r = e / K, c = e - r * K;
        As[r * 105 + c] = A[(size_t)(rowBase + r) * K + c];
    }
    for (int e = t; e < K * 80; e += 256) Ws[e] = W[e];
    __syncthreads();

    int tx = t & 15, ty = t >> 4;
    float acc[4][5];
    #pragma unroll
    for (int r = 0; r < 4; r++)
        #pragma unroll
        for (int c = 0; c < 5; c++) acc[r][c] = 0.f;

    for (int k = 0; k < K; k++) {
        float a0 = As[(ty * 4 + 0) * 105 + k];
        float a1 = As[(ty * 4 + 1) * 105 + k];
        float a2 = As[(ty * 4 + 2) * 105 + k];
        float a3 = As[(ty * 4 + 3) * 105 + k];
        float w[5];
        #pragma unroll
        for (int c = 0; c < 5; c++) w[c] = Ws[k * 80 + c * 16 + tx];
        #pragma unroll
        for (int c = 0; c < 5; c++) {
            acc[0][c] += a0 * w[c];
            acc[1][c] += a1 * w[c];
            acc[2][c] += a2 * w[c];
            acc[3][c] += a3 * w[c];
        }
    }

    float bv[5];
    #pragma unroll
    for (int c = 0; c < 5; c++) bv[c] = bc ? bc[z * 80 + c * 16 + tx] : 0.f;
    #pragma unroll
    for (int r = 0; r < 4; r++) {
        size_t row = rowBase + ty * 4 + r;
        #pragma unroll
        for (int c = 0; c < 5; c++)
            o[row * out_ld + c * 16 + tx] = (OT)(acc[r][c] + bv[c]);
    }
}

// ---------------------------------------------------------------------------
// Fused attention layer. grid = (h=8, y=256) with b = y>>3, i0 = (y&7)*8.
// One block handles 8 i-values for one hb; V/AM2 staged once (used 8x).
// Score partials computed directly while streaming P (no P LDS array).
// LDS strides padded: f32 rows 84 (16B-aligned, spread banks), bf16 rows 41 words.
// ---------------------------------------------------------------------------
__global__ __launch_bounds__(256) void attn_layer_kernel(
    const float* __restrict__ UVAM,    // [256*64][320]: U+b | V | AM1 | AM2
    const bf16* __restrict__ P,        // [32*64*64][80]
    const bf16* __restrict__ PM3,      // [32*64*64][80]
    const float* __restrict__ mask,    // [32,64,64]
    const float* __restrict__ w_attn_o, const float* __restrict__ b_attn_o,
    const float* __restrict__ b_msg_h,
    const float* __restrict__ ah0, float* __restrict__ ah_next)
{
    __shared__ float Vs[64 * 84];
    __shared__ float Ams[64 * 84];
    __shared__ unsigned PMsW[64 * 41];   // bf16 pairs, row stride 41 words
    __shared__ float U8[8 * 80], A18[8 * 80];
    __shared__ float wo[80], bm[80];
    __shared__ float part2[64 * 11];
    __shared__ float probs[64];
    __shared__ float red[240];
    __shared__ float sum_p_sh;

    int h = blockIdx.x, y = blockIdx.y;
    int b = y >> 3, i0 = (y & 7) * 8;
    int hb = h * 32 + b;
    int t = threadIdx.x;
    size_t vbase = (size_t)hb * 64 * 320;
    float b_attn_o0 = b_attn_o[0];

    // ---- stage V/AM2 slabs (used by all 8 i) ----
    for (int e4 = t; e4 < 1280; e4 += 256) {       // 64*80/4 float4 groups
        int j = e4 / 20, kq = e4 - j * 20;
        float4v v = *(const float4v*)(UVAM + vbase + (size_t)j * 320 + 80  + kq * 4);
        float4v a = *(const float4v*)(UVAM + vbase + (size_t)j * 320 + 240 + kq * 4);
        *(float4v*)(&Vs[j * 84 + kq * 4])  = v;
        *(float4v*)(&Ams[j * 84 + kq * 4]) = a;
    }
    for (int e = t; e < 640; e += 256) {           // 8 rows of U / AM1
        int iq = e / 80, k = e - iq * 80;
        U8[e]  = UVAM[vbase + (size_t)(i0 + iq) * 320 + k];
        A18[e] = UVAM[vbase + (size_t)(i0 + iq) * 320 + 160 + k];
    }
    if (t < 80) { wo[t] = w_attn_o[t]; bm[t] = b_msg_h[t]; }
    __syncthreads();

    const unsigned short* Pus  = (const unsigned short*)P;
    const unsigned short* PMus = (const unsigned short*)PM3;

    for (int ii = 0; ii < 8; ii++) {
        int i = i0 + ii;
        size_t pbase = ((size_t)b * 4096 + (size_t)i * 64) * 80;

        // ---- phase 1: stream P/PM3, compute score partials, stage PM3 ----
        for (int g = t; g < 640; g += 256) {       // (j, seg of 8 k)
            int j = g / 10, seg = g - j * 10;
            int k0 = seg * 8;
            uint4v pv = *(const uint4v*)(Pus  + pbase + (size_t)g * 8);
            uint4v mv = *(const uint4v*)(PMus + pbase + (size_t)g * 8);
            int wb = j * 41 + seg * 4;
            PMsW[wb + 0] = mv.x; PMsW[wb + 1] = mv.y;
            PMsW[wb + 2] = mv.z; PMsW[wb + 3] = mv.w;
            float acc = 0.f;
            const float* Uop = &U8[ii * 80 + k0];
            const float* Vop = &Vs[j * 84 + k0];
            const float* Wop = &wo[k0];
            #pragma unroll
            for (int q = 0; q < 4; q++) {
                unsigned w = pv[q];
                float x0 = Uop[2 * q]     + Vop[2 * q]     + bflo(w);
                x0 = x0 > 0.f ? x0 : 0.2f * x0;
                acc += x0 * Wop[2 * q];
                float x1 = Uop[2 * q + 1] + Vop[2 * q + 1] + bfhi(w);
                x1 = x1 > 0.f ? x1 : 0.2f * x1;
                acc += x1 * Wop[2 * q + 1];
            }
            part2[j * 11 + seg] = acc;
        }
        __syncthreads();

        // ---- masked softmax over j (wave 0), exact reference semantics ----
        if (t < 64) {
            float mj = mask[(size_t)b * 4096 + (size_t)i * 64 + t];
            float s = b_attn_o0;
            #pragma unroll
            for (int q = 0; q < 10; q++) s += part2[t * 11 + q];
            s *= mj;
            float m = s;
            #pragma unroll
            for (int off = 1; off < 64; off <<= 1) m = fmaxf(m, __shfl_xor(m, off, 64));
            float e = expf(s - m) * mj;
            float d = e;
            #pragma unroll
            for (int off = 1; off < 64; off <<= 1) d += __shfl_xor(d, off, 64);
            float p = e / (d + 1e-20f) * mj;
            probs[t] = p;
            float sp = p;
            #pragma unroll
            for (int off = 1; off < 64; off <<= 1) sp += __shfl_xor(sp, off, 64);
            if (t == 0) sum_p_sh = sp;
        }
        __syncthreads();

        // ---- message partials: 240 threads = 80 k x 3 j-groups ----
        if (t < 240) {
            int k = t % 80, jg = t / 80;
            float acc = 0.f;
            for (int j2 = jg; j2 < 64; j2 += 3) {
                unsigned w = PMsW[j2 * 41 + (k >> 1)];
                float pm = (k & 1) ? bfhi(w) : bflo(w);
                acc += probs[j2] * (Ams[j2 * 84 + k] + pm);
            }
            red[jg * 80 + k] = acc;
        }
        __syncthreads();

        // ---- combine + residual + relu (safe to overlap with next phase 1) ----
        if (t < 80) {
            float msg = red[t] + red[80 + t] + red[160 + t];
            size_t orow = ((size_t)hb * 64 + i) * 80 + t;
            float pre = sum_p_sh * A18[ii * 80 + t] + msg + bm[t] + ah0[orow];
            ah_next[orow] = pre > 0.f ? pre : 0.f;
        }
    }
}

// ---------------------------------------------------------------------------
// Kernel E: out[row, c] = relu(concat(atom[row,:82], ah_merged[row,:640]) @ W_atom_o + b)
// ---------------------------------------------------------------------------
__global__ __launch_bounds__(256) void out_proj_kernel(
    const float* __restrict__ atom, const float* __restrict__ ah,
    const float* __restrict__ W, const float* __restrict__ bo,
    float* __restrict__ out)
{
    __shared__ float xs[8][722];
    int r0 = blockIdx.x * 8;
    int t = threadIdx.x;
    for (int e = t; e < 8 * 722; e += 256) {
        int r = e / 722, f = e - r * 722;
        int row = r0 + r;               // b*64 + i
        float v;
        if (f < 82) {
            v = atom[(size_t)row * 82 + f];
        } else {
            int q = f - 82, h = q / 80, k = q - h * 80;
            int b = row >> 6, i = row & 63;
            v = ah[(((size_t)(h * 32 + b)) * 64 + i) * 80 + k];
        }
        xs[r][f] = v;
    }
    __syncthreads();

    int c = t;
    float bias = bo[c];
    float acc[8];
    #pragma unroll
    for (int r = 0; r < 8; r++) acc[r] = bias;
    for (int f = 0; f < 722; f++) {
        float w = W[(size_t)f * 256 + c];
        #pragma unroll
        for (int r = 0; r < 8; r++) acc[r] += xs[r][f] * w;
    }
    #pragma unroll
    for (int r = 0; r < 8; r++) {
        float v = acc[r] > 0.f ? acc[r] : 0.f;
        out[(size_t)(r0 + r) * 256 + c] = v;
    }
}

// ---------------------------------------------------------------------------
extern "C" void kernel_launch(void* const* d_in, const int* in_sizes, int n_in,
                              void* d_out, int out_size, void* d_ws, size_t ws_size,
                              hipStream_t stream)
{
    const float* atom_input = (const float*)d_in[0];
    const float* path_input = (const float*)d_in[1];
    const float* path_mask  = (const float*)d_in[2];
    const float* W_atom_i   = (const float*)d_in[3];
    const float* W_attn_h   = (const float*)d_in[4];
    const float* b_attn_h   = (const float*)d_in[5];
    const float* W_attn_o   = (const float*)d_in[6];
    const float* b_attn_o   = (const float*)d_in[7];
    const float* W_msg_h    = (const float*)d_in[8];
    const float* b_msg_h    = (const float*)d_in[9];
    const float* W_atom_o   = (const float*)d_in[10];
    const float* b_atom_o   = (const float*)d_in[11];
    float* out = (float*)d_out;

    // workspace carve-up (~74 MB)
    char* ws = (char*)d_ws;
    float* ah0   = (float*)ws;  ws += (size_t)16384 * 80 * 4;
    float* ah1   = (float*)ws;  ws += (size_t)16384 * 80 * 4;
    float* ah2   = (float*)ws;  ws += (size_t)16384 * 80 * 4;
    float* UVAM  = (float*)ws;  ws += (size_t)16384 * 320 * 4;
    bf16*  P     = (bf16*)ws;   ws += (size_t)131072 * 80 * 2;   // z=0
    bf16*  PM3   = (bf16*)ws;   ws += (size_t)131072 * 80 * 2;   // z=1 (contiguous after P)
    float* Wpath = (float*)ws;  ws += (size_t)2 * 102 * 80 * 4;
    float* Wuvam = (float*)ws;  ws += (size_t)4 * 80 * 80 * 4;
    float* buvam = (float*)ws;  ws += (size_t)4 * 80 * 4;

    prep_kernel<<<100, 256, 0, stream>>>(W_attn_h, b_attn_h, W_msg_h,
                                         Wpath, Wuvam, buvam);

    atom_proj_kernel<<<2048, 256, 0, stream>>>(atom_input, W_atom_i, ah0);

    // Path GEMMs (once): z=0 -> P, z=1 -> PM3
    gemm_z<bf16><<<dim3(2048, 2), 256, 0, stream>>>(
        path_input, 102, Wpath, nullptr, P, 80, (size_t)131072 * 80);

    const float* cur = ah0;
    float* nxt[2] = { ah1, ah2 };
    for (int layer = 0; layer < 2; layer++) {
        // U(+b_attn_h) | V | AM1 | AM2 in one launch (z = column group)
        gemm_z<float><<<dim3(256, 4), 256, 0, stream>>>(
            cur, 80, Wuvam, buvam, UVAM, 320, 80);

        attn_layer_kernel<<<dim3(8, 256), 256, 0, stream>>>(
            UVAM, P, PM3, path_mask, W_attn_o, b_attn_o, b_msg_h, ah0, nxt[layer]);
        cur = nxt[layer];
    }

    out_proj_kernel<<<256, 256, 0, stream>>>(atom_input, cur, W_atom_o, b_atom_o, out);
}

// Round 5
// 674.877 us; speedup vs baseline: 1.2776x; 1.0756x over previous
//
#include <hip/hip_runtime.h>
#include <hip/hip_bf16.h>

typedef __hip_bfloat16 bf16;
typedef float  float4v __attribute__((ext_vector_type(4)));
typedef unsigned uint4v __attribute__((ext_vector_type(4)));

// B=32, N=64, F_ATOM=82, F_PATH=102, H=8, DK=80, HIDDEN=256, DEPTH=3
// Inputs fp32, output fp32. hb = h*32 + b.

__device__ inline float bflo(unsigned w) { return __uint_as_float(w << 16); }
__device__ inline float bfhi(unsigned w) { return __uint_as_float(w & 0xFFFF0000u); }

// ---------------------------------------------------------------------------
// Prep: pack weights for z-indexed GEMMs.
// Wpath[z][102][80]: z0 = W_attn_h rows 160..261, z1 = W_msg_h rows 160..261
// Wuvam[z][80][80]:  z0 = W_attn_h[0:80], z1 = W_attn_h[80:160],
//                    z2 = W_msg_h[0:80],  z3 = W_msg_h[80:160]
// buvam[4][80]: z0 = b_attn_h, rest 0
// ---------------------------------------------------------------------------
__global__ __launch_bounds__(256) void prep_kernel(
    const float* __restrict__ W_attn_h, const float* __restrict__ b_attn_h,
    const float* __restrict__ W_msg_h,
    float* __restrict__ Wpath, float* __restrict__ Wuvam, float* __restrict__ buvam)
{
    int t = blockIdx.x * 256 + threadIdx.x;
    if (t < 2 * 102 * 80) {
        int z = t / (102 * 80), rc = t - z * (102 * 80);
        const float* src = z ? W_msg_h : W_attn_h;
        Wpath[t] = src[160 * 80 + rc];
    }
    if (t < 4 * 80 * 80) {
        int z = t / 6400, rc = t - z * 6400;
        const float* src = (z < 2) ? W_attn_h : W_msg_h;
        Wuvam[t] = src[(z & 1) * 6400 + rc];
    }
    if (t < 320) buvam[t] = (t < 80) ? b_attn_h[t] : 0.f;
}

// ---------------------------------------------------------------------------
// Kernel A: register-tiled GEMM for the atom projection.
// grid = (rowtile=32, h=8). ah0[(h*32+b)*64+i][k] = atom[b,i,:82] @ W[:, h*80+k]
// ---------------------------------------------------------------------------
__global__ __launch_bounds__(256) void atom_proj_kernel(
    const float* __restrict__ atom, const float* __restrict__ W,
    float* __restrict__ ah0)
{
    __shared__ float As[64 * 84];       // K=82, stride 84
    __shared__ float Ws[82 * 80];
    int rowBase = blockIdx.x * 64;
    int h = blockIdx.y;
    int t = threadIdx.x;

    for (int e = t; e < 64 * 82; e += 256) {
        int r = e / 82, c = e - r * 82;
        As[r * 84 + c] = atom[(size_t)(rowBase + r) * 82 + c];
    }
    for (int e = t; e < 82 * 80; e += 256) {
        int r = e / 80, c = e - r * 80;
        Ws[e] = W[(size_t)r * 640 + h * 80 + c];
    }
    __syncthreads();

    int tx = t & 15, ty = t >> 4;
    float acc[4][5];
    #pragma unroll
    for (int r = 0; r < 4; r++)
        #pragma unroll
        for (int c = 0; c < 5; c++) acc[r][c] = 0.f;

    for (int k = 0; k < 82; k++) {
        float a0 = As[(ty * 4 + 0) * 84 + k];
        float a1 = As[(ty * 4 + 1) * 84 + k];
        float a2 = As[(ty * 4 + 2) * 84 + k];
        float a3 = As[(ty * 4 + 3) * 84 + k];
        float w[5];
        #pragma unroll
        for (int c = 0; c < 5; c++) w[c] = Ws[k * 80 + c * 16 + tx];
        #pragma unroll
        for (int c = 0; c < 5; c++) {
            acc[0][c] += a0 * w[c];
            acc[1][c] += a1 * w[c];
            acc[2][c] += a2 * w[c];
            acc[3][c] += a3 * w[c];
        }
    }

    #pragma unroll
    for (int r = 0; r < 4; r++) {
        int row = rowBase + ty * 4 + r;       // b*64 + i
        int b = row >> 6, i = row & 63;
        size_t obase = (((size_t)(h * 32 + b)) * 64 + i) * 80;
        #pragma unroll
        for (int c = 0; c < 5; c++)
            ah0[obase + c * 16 + tx] = acc[r][c];
    }
}

// ---------------------------------------------------------------------------
// z-indexed tiled GEMM: o[row, c] = A[row,:K] @ Wc[z][:,c] (+ bc[z][c])
// o = out + z*zoff ; blockIdx.x tiles rows by 64, blockIdx.y = z
// ---------------------------------------------------------------------------
template <typename OT>
__global__ __launch_bounds__(256) void gemm_z(
    const float* __restrict__ A, int K,
    const float* __restrict__ Wc, const float* __restrict__ bc,
    OT* __restrict__ out, int out_ld, size_t zoff)
{
    __shared__ float As[64 * 105];
    __shared__ float Ws[102 * 80];
    int z = blockIdx.y;
    const float* W = Wc + (size_t)z * K * 80;
    OT* o = out + (size_t)z * zoff;
    int rowBase = blockIdx.x * 64;
    int t = threadIdx.x;

    for (int e = t; e < 64 * K; e += 256) {
        int r = e / K, c = e - r * K;
        As[r * 105 + c] = A[(size_t)(rowBase + r) * K + c];
    }
    for (int e = t; e < K * 80; e += 256) Ws[e] = W[e];
    __syncthreads();

    int tx = t & 15, ty = t >> 4;
    float acc[4][5];
    #pragma unroll
    for (int r = 0; r < 4; r++)
        #pragma unroll
        for (int c = 0; c < 5; c++) acc[r][c] = 0.f;

    for (int k = 0; k < K; k++) {
        float a0 = As[(ty * 4 + 0) * 105 + k];
        float a1 = As[(ty * 4 + 1) * 105 + k];
        float a2 = As[(ty * 4 + 2) * 105 + k];
        float a3 = As[(ty * 4 + 3) * 105 + k];
        float w[5];
        #pragma unroll
        for (int c = 0; c < 5; c++) w[c] = Ws[k * 80 + c * 16 + tx];
        #pragma unroll
        for (int c = 0; c < 5; c++) {
            acc[0][c] += a0 * w[c];
            acc[1][c] += a1 * w[c];
            acc[2][c] += a2 * w[c];
            acc[3][c] += a3 * w[c];
        }
    }

    float bv[5];
    #pragma unroll
    for (int c = 0; c < 5; c++) bv[c] = bc ? bc[z * 80 + c * 16 + tx] : 0.f;
    #pragma unroll
    for (int r = 0; r < 4; r++) {
        size_t row = rowBase + ty * 4 + r;
        #pragma unroll
        for (int c = 0; c < 5; c++)
            o[row * out_ld + c * 16 + tx] = (OT)(acc[r][c] + bv[c]);
    }
}

// ---------------------------------------------------------------------------
// Fused attention layer. grid = (h=8, y=256) with b = y>>3, i0 = (y&7)*8.
// One block handles 8 i-values for one hb; V/AM2 staged once (used 8x).
// ---------------------------------------------------------------------------
__global__ __launch_bounds__(256) void attn_layer_kernel(
    const float* __restrict__ UVAM,    // [256*64][320]: U+b | V | AM1 | AM2
    const bf16* __restrict__ P,        // [32*64*64][80]
    const bf16* __restrict__ PM3,      // [32*64*64][80]
    const float* __restrict__ mask,    // [32,64,64]
    const float* __restrict__ w_attn_o, const float* __restrict__ b_attn_o,
    const float* __restrict__ b_msg_h,
    const float* __restrict__ ah0, float* __restrict__ ah_next)
{
    __shared__ float Vs[64 * 84];
    __shared__ float Ams[64 * 84];
    __shared__ unsigned PMsW[64 * 41];   // bf16 pairs, row stride 41 words
    __shared__ float U8[8 * 80], A18[8 * 80];
    __shared__ float wo[80], bm[80];
    __shared__ float part2[64 * 11];
    __shared__ float probs[64];
    __shared__ float red[240];
    __shared__ float sum_p_sh;

    int h = blockIdx.x, y = blockIdx.y;
    int b = y >> 3, i0 = (y & 7) * 8;
    int hb = h * 32 + b;
    int t = threadIdx.x;
    size_t vbase = (size_t)hb * 64 * 320;
    float b_attn_o0 = b_attn_o[0];

    for (int e4 = t; e4 < 1280; e4 += 256) {       // 64*80/4 float4 groups
        int j = e4 / 20, kq = e4 - j * 20;
        float4v v = *(const float4v*)(UVAM + vbase + (size_t)j * 320 + 80  + kq * 4);
        float4v a = *(const float4v*)(UVAM + vbase + (size_t)j * 320 + 240 + kq * 4);
        *(float4v*)(&Vs[j * 84 + kq * 4])  = v;
        *(float4v*)(&Ams[j * 84 + kq * 4]) = a;
    }
    for (int e = t; e < 640; e += 256) {           // 8 rows of U / AM1
        int iq = e / 80, k = e - iq * 80;
        U8[e]  = UVAM[vbase + (size_t)(i0 + iq) * 320 + k];
        A18[e] = UVAM[vbase + (size_t)(i0 + iq) * 320 + 160 + k];
    }
    if (t < 80) { wo[t] = w_attn_o[t]; bm[t] = b_msg_h[t]; }
    __syncthreads();

    const unsigned short* Pus  = (const unsigned short*)P;
    const unsigned short* PMus = (const unsigned short*)PM3;

    for (int ii = 0; ii < 8; ii++) {
        int i = i0 + ii;
        size_t pbase = ((size_t)b * 4096 + (size_t)i * 64) * 80;

        // ---- phase 1: stream P/PM3, compute score partials, stage PM3 ----
        for (int g = t; g < 640; g += 256) {       // (j, seg of 8 k)
            int j = g / 10, seg = g - j * 10;
            int k0 = seg * 8;
            uint4v pv = *(const uint4v*)(Pus  + pbase + (size_t)g * 8);
            uint4v mv = *(const uint4v*)(PMus + pbase + (size_t)g * 8);
            int wb = j * 41 + seg * 4;
            PMsW[wb + 0] = mv.x; PMsW[wb + 1] = mv.y;
            PMsW[wb + 2] = mv.z; PMsW[wb + 3] = mv.w;
            float acc = 0.f;
            const float* Uop = &U8[ii * 80 + k0];
            const float* Vop = &Vs[j * 84 + k0];
            const float* Wop = &wo[k0];
            #pragma unroll
            for (int q = 0; q < 4; q++) {
                unsigned w = pv[q];
                float x0 = Uop[2 * q]     + Vop[2 * q]     + bflo(w);
                x0 = x0 > 0.f ? x0 : 0.2f * x0;
                acc += x0 * Wop[2 * q];
                float x1 = Uop[2 * q + 1] + Vop[2 * q + 1] + bfhi(w);
                x1 = x1 > 0.f ? x1 : 0.2f * x1;
                acc += x1 * Wop[2 * q + 1];
            }
            part2[j * 11 + seg] = acc;
        }
        __syncthreads();

        // ---- masked softmax over j (wave 0), exact reference semantics ----
        if (t < 64) {
            float mj = mask[(size_t)b * 4096 + (size_t)i * 64 + t];
            float s = b_attn_o0;
            #pragma unroll
            for (int q = 0; q < 10; q++) s += part2[t * 11 + q];
            s *= mj;
            float m = s;
            #pragma unroll
            for (int off = 1; off < 64; off <<= 1) m = fmaxf(m, __shfl_xor(m, off, 64));
            float e = expf(s - m) * mj;
            float d = e;
            #pragma unroll
            for (int off = 1; off < 64; off <<= 1) d += __shfl_xor(d, off, 64);
            float p = e / (d + 1e-20f) * mj;
            probs[t] = p;
            float sp = p;
            #pragma unroll
            for (int off = 1; off < 64; off <<= 1) sp += __shfl_xor(sp, off, 64);
            if (t == 0) sum_p_sh = sp;
        }
        __syncthreads();

        // ---- message partials: 240 threads = 80 k x 3 j-groups ----
        if (t < 240) {
            int k = t % 80, jg = t / 80;
            float acc = 0.f;
            for (int j2 = jg; j2 < 64; j2 += 3) {
                unsigned w = PMsW[j2 * 41 + (k >> 1)];
                float pm = (k & 1) ? bfhi(w) : bflo(w);
                acc += probs[j2] * (Ams[j2 * 84 + k] + pm);
            }
            red[jg * 80 + k] = acc;
        }
        __syncthreads();

        if (t < 80) {
            float msg = red[t] + red[80 + t] + red[160 + t];
            size_t orow = ((size_t)hb * 64 + i) * 80 + t;
            float pre = sum_p_sh * A18[ii * 80 + t] + msg + bm[t] + ah0[orow];
            ah_next[orow] = pre > 0.f ? pre : 0.f;
        }
    }
}

// ---------------------------------------------------------------------------
// Kernel E: out[row, c] = relu(concat(atom[row,:82], ah_merged[row,:640]) @ W_atom_o + b)
// 512 blocks x 4 rows each (2 blocks/CU, 8 waves/CU); K-loop unrolled x4 for
// load-latency hiding. thread = output col.
// ---------------------------------------------------------------------------
__global__ __launch_bounds__(256) void out_proj_kernel(
    const float* __restrict__ atom, const float* __restrict__ ah,
    const float* __restrict__ W, const float* __restrict__ bo,
    float* __restrict__ out)
{
    __shared__ float xs[4][724];
    int r0 = blockIdx.x * 4;
    int t = threadIdx.x;
    for (int e = t; e < 4 * 722; e += 256) {
        int r = e / 722, f = e - r * 722;
        int row = r0 + r;               // b*64 + i
        float v;
        if (f < 82) {
            v = atom[(size_t)row * 82 + f];
        } else {
            int q = f - 82, h = q / 80, k = q - h * 80;
            int b = row >> 6, i = row & 63;
            v = ah[(((size_t)(h * 32 + b)) * 64 + i) * 80 + k];
        }
        xs[r][f] = v;
    }
    __syncthreads();

    int c = t;
    float acc0 = 0.f, acc1 = 0.f, acc2 = 0.f, acc3 = 0.f;
    const float* Wp = W + c;
    #pragma unroll 4
    for (int f = 0; f < 722; f++) {
        float w = Wp[(size_t)f * 256];
        acc0 += xs[0][f] * w;
        acc1 += xs[1][f] * w;
        acc2 += xs[2][f] * w;
        acc3 += xs[3][f] * w;
    }
    float bias = bo[c];
    float v0 = acc0 + bias, v1 = acc1 + bias, v2 = acc2 + bias, v3 = acc3 + bias;
    out[(size_t)(r0 + 0) * 256 + c] = v0 > 0.f ? v0 : 0.f;
    out[(size_t)(r0 + 1) * 256 + c] = v1 > 0.f ? v1 : 0.f;
    out[(size_t)(r0 + 2) * 256 + c] = v2 > 0.f ? v2 : 0.f;
    out[(size_t)(r0 + 3) * 256 + c] = v3 > 0.f ? v3 : 0.f;
}

// ---------------------------------------------------------------------------
extern "C" void kernel_launch(void* const* d_in, const int* in_sizes, int n_in,
                              void* d_out, int out_size, void* d_ws, size_t ws_size,
                              hipStream_t stream)
{
    const float* atom_input = (const float*)d_in[0];
    const float* path_input = (const float*)d_in[1];
    const float* path_mask  = (const float*)d_in[2];
    const float* W_atom_i   = (const float*)d_in[3];
    const float* W_attn_h   = (const float*)d_in[4];
    const float* b_attn_h   = (const float*)d_in[5];
    const float* W_attn_o   = (const float*)d_in[6];
    const float* b_attn_o   = (const float*)d_in[7];
    const float* W_msg_h    = (const float*)d_in[8];
    const float* b_msg_h    = (const float*)d_in[9];
    const float* W_atom_o   = (const float*)d_in[10];
    const float* b_atom_o   = (const float*)d_in[11];
    float* out = (float*)d_out;

    // workspace carve-up (~74 MB)
    char* ws = (char*)d_ws;
    float* ah0   = (float*)ws;  ws += (size_t)16384 * 80 * 4;
    float* ah1   = (float*)ws;  ws += (size_t)16384 * 80 * 4;
    float* ah2   = (float*)ws;  ws += (size_t)16384 * 80 * 4;
    float* UVAM  = (float*)ws;  ws += (size_t)16384 * 320 * 4;
    bf16*  P     = (bf16*)ws;   ws += (size_t)131072 * 80 * 2;   // z=0
    bf16*  PM3   = (bf16*)ws;   ws += (size_t)131072 * 80 * 2;   // z=1
    float* Wpath = (float*)ws;  ws += (size_t)2 * 102 * 80 * 4;
    float* Wuvam = (float*)ws;  ws += (size_t)4 * 80 * 80 * 4;
    float* buvam = (float*)ws;  ws += (size_t)4 * 80 * 4;

    prep_kernel<<<100, 256, 0, stream>>>(W_attn_h, b_attn_h, W_msg_h,
                                         Wpath, Wuvam, buvam);

    atom_proj_kernel<<<dim3(32, 8), 256, 0, stream>>>(atom_input, W_atom_i, ah0);

    // Path GEMMs (once): z=0 -> P, z=1 -> PM3
    gemm_z<bf16><<<dim3(2048, 2), 256, 0, stream>>>(
        path_input, 102, Wpath, nullptr, P, 80, (size_t)131072 * 80);

    const float* cur = ah0;
    float* nxt[2] = { ah1, ah2 };
    for (int layer = 0; layer < 2; layer++) {
        gemm_z<float><<<dim3(256, 4), 256, 0, stream>>>(
            cur, 80, Wuvam, buvam, UVAM, 320, 80);

        attn_layer_kernel<<<dim3(8, 256), 256, 0, stream>>>(
            UVAM, P, PM3, path_mask, W_attn_o, b_attn_o, b_msg_h, ah0, nxt[layer]);
        cur = nxt[layer];
    }

    out_proj_kernel<<<512, 256, 0, stream>>>(atom_input, cur, W_atom_o, b_atom_o, out);
}

// Round 6
// 595.236 us; speedup vs baseline: 1.4486x; 1.1338x over previous
//
#include <hip/hip_runtime.h>
#include <hip/hip_bf16.h>

typedef __hip_bfloat16 bf16;
typedef float  float4v __attribute__((ext_vector_type(4)));
typedef unsigned uint4v __attribute__((ext_vector_type(4)));

// B=32, N=64, F_ATOM=82, F_PATH=102, H=8, DK=80, HIDDEN=256, DEPTH=3
// Inputs fp32, output fp32. hb = h*32 + b.

__device__ inline float bflo(unsigned w) { return __uint_as_float(w << 16); }
__device__ inline float bfhi(unsigned w) { return __uint_as_float(w & 0xFFFF0000u); }

// ---------------------------------------------------------------------------
// Prep: pack weights for z-indexed GEMMs.
// ---------------------------------------------------------------------------
__global__ __launch_bounds__(256) void prep_kernel(
    const float* __restrict__ W_attn_h, const float* __restrict__ b_attn_h,
    const float* __restrict__ W_msg_h,
    float* __restrict__ Wpath, float* __restrict__ Wuvam, float* __restrict__ buvam)
{
    int t = blockIdx.x * 256 + threadIdx.x;
    if (t < 2 * 102 * 80) {
        int z = t / (102 * 80), rc = t - z * (102 * 80);
        const float* src = z ? W_msg_h : W_attn_h;
        Wpath[t] = src[160 * 80 + rc];
    }
    if (t < 4 * 80 * 80) {
        int z = t / 6400, rc = t - z * 6400;
        const float* src = (z < 2) ? W_attn_h : W_msg_h;
        Wuvam[t] = src[(z & 1) * 6400 + rc];
    }
    if (t < 320) buvam[t] = (t < 80) ? b_attn_h[t] : 0.f;
}

// ---------------------------------------------------------------------------
// Kernel A: register-tiled GEMM for the atom projection.
// grid = (rowtile=32, h=8). ah0[(h*32+b)*64+i][k] = atom[b,i,:82] @ W[:, h*80+k]
// ---------------------------------------------------------------------------
__global__ __launch_bounds__(256) void atom_proj_kernel(
    const float* __restrict__ atom, const float* __restrict__ W,
    float* __restrict__ ah0)
{
    __shared__ float As[64 * 84];
    __shared__ float Ws[82 * 80];
    int rowBase = blockIdx.x * 64;
    int h = blockIdx.y;
    int t = threadIdx.x;

    for (int e = t; e < 64 * 82; e += 256) {
        int r = e / 82, c = e - r * 82;
        As[r * 84 + c] = atom[(size_t)(rowBase + r) * 82 + c];
    }
    for (int e = t; e < 82 * 80; e += 256) {
        int r = e / 80, c = e - r * 80;
        Ws[e] = W[(size_t)r * 640 + h * 80 + c];
    }
    __syncthreads();

    int tx = t & 15, ty = t >> 4;
    float acc[4][5];
    #pragma unroll
    for (int r = 0; r < 4; r++)
        #pragma unroll
        for (int c = 0; c < 5; c++) acc[r][c] = 0.f;

    for (int k = 0; k < 82; k++) {
        float a0 = As[(ty * 4 + 0) * 84 + k];
        float a1 = As[(ty * 4 + 1) * 84 + k];
        float a2 = As[(ty * 4 + 2) * 84 + k];
        float a3 = As[(ty * 4 + 3) * 84 + k];
        float w[5];
        #pragma unroll
        for (int c = 0; c < 5; c++) w[c] = Ws[k * 80 + c * 16 + tx];
        #pragma unroll
        for (int c = 0; c < 5; c++) {
            acc[0][c] += a0 * w[c];
            acc[1][c] += a1 * w[c];
            acc[2][c] += a2 * w[c];
            acc[3][c] += a3 * w[c];
        }
    }

    #pragma unroll
    for (int r = 0; r < 4; r++) {
        int row = rowBase + ty * 4 + r;
        int b = row >> 6, i = row & 63;
        size_t obase = (((size_t)(h * 32 + b)) * 64 + i) * 80;
        #pragma unroll
        for (int c = 0; c < 5; c++)
            ah0[obase + c * 16 + tx] = acc[r][c];
    }
}

// ---------------------------------------------------------------------------
// z-indexed tiled GEMM (as before)
// ---------------------------------------------------------------------------
template <typename OT>
__global__ __launch_bounds__(256) void gemm_z(
    const float* __restrict__ A, int K,
    const float* __restrict__ Wc, const float* __restrict__ bc,
    OT* __restrict__ out, int out_ld, size_t zoff)
{
    __shared__ float As[64 * 105];
    __shared__ float Ws[102 * 80];
    int z = blockIdx.y;
    const float* W = Wc + (size_t)z * K * 80;
    OT* o = out + (size_t)z * zoff;
    int rowBase = blockIdx.x * 64;
    int t = threadIdx.x;

    for (int e = t; e < 64 * K; e += 256) {
        int r = e / K, c = e - r * K;
        As[r * 105 + c] = A[(size_t)(rowBase + r) * K + c];
    }
    for (int e = t; e < K * 80; e += 256) Ws[e] = W[e];
    __syncthreads();

    int tx = t & 15, ty = t >> 4;
    float acc[4][5];
    #pragma unroll
    for (int r = 0; r < 4; r++)
        #pragma unroll
        for (int c = 0; c < 5; c++) acc[r][c] = 0.f;

    for (int k = 0; k < K; k++) {
        float a0 = As[(ty * 4 + 0) * 105 + k];
        float a1 = As[(ty * 4 + 1) * 105 + k];
        float a2 = As[(ty * 4 + 2) * 105 + k];
        float a3 = As[(ty * 4 + 3) * 105 + k];
        float w[5];
        #pragma unroll
        for (int c = 0; c < 5; c++) w[c] = Ws[k * 80 + c * 16 + tx];
        #pragma unroll
        for (int c = 0; c < 5; c++) {
            acc[0][c] += a0 * w[c];
            acc[1][c] += a1 * w[c];
            acc[2][c] += a2 * w[c];
            acc[3][c] += a3 * w[c];
        }
    }

    float bv[5];
    #pragma unroll
    for (int c = 0; c < 5; c++) bv[c] = bc ? bc[z * 80 + c * 16 + tx] : 0.f;
    #pragma unroll
    for (int r = 0; r < 4; r++) {
        size_t row = rowBase + ty * 4 + r;
        #pragma unroll
        for (int c = 0; c < 5; c++)
            o[row * out_ld + c * 16 + tx] = (OT)(acc[r][c] + bv[c]);
    }
}

// ---------------------------------------------------------------------------
// Fused attention layer. grid = (x=256, h=8) with b = x>>3, i0 = (x&7)*8.
// XCD = linear%8 = x%8 = itile -> all 8 head-copies of a (b,itile) share an XCD.
// Vs/Ams stride 85 (odd) -> phase-1 reads <=2-way bank aliasing (free).
// ---------------------------------------------------------------------------
__global__ __launch_bounds__(256) void attn_layer_kernel(
    const float* __restrict__ UVAM,    // [256*64][320]: U+b | V | AM1 | AM2
    const bf16* __restrict__ P,        // [32*64*64][80]
    const bf16* __restrict__ PM3,      // [32*64*64][80]
    const float* __restrict__ mask,    // [32,64,64]
    const float* __restrict__ w_attn_o, const float* __restrict__ b_attn_o,
    const float* __restrict__ b_msg_h,
    const float* __restrict__ ah0, float* __restrict__ ah_next)
{
    __shared__ float Vs[64 * 85];
    __shared__ float Ams[64 * 85];
    __shared__ unsigned PMsW[64 * 41];
    __shared__ float U8[8 * 80], A18[8 * 80];
    __shared__ float wo[80], bm[80];
    __shared__ float part2[64 * 11];
    __shared__ float probs[64];
    __shared__ float red[240];
    __shared__ float sum_p_sh;

    int x = blockIdx.x, h = blockIdx.y;
    int b = x >> 3, i0 = (x & 7) * 8;
    int hb = h * 32 + b;
    int t = threadIdx.x;
    size_t vbase = (size_t)hb * 64 * 320;
    float b_attn_o0 = b_attn_o[0];

    for (int e = t; e < 5120; e += 256) {          // 64*80 scalar
        int j = e / 80, k = e - j * 80;
        Vs[j * 85 + k]  = UVAM[vbase + (size_t)j * 320 + 80  + k];
        Ams[j * 85 + k] = UVAM[vbase + (size_t)j * 320 + 240 + k];
    }
    for (int e = t; e < 640; e += 256) {
        int iq = e / 80, k = e - iq * 80;
        U8[e]  = UVAM[vbase + (size_t)(i0 + iq) * 320 + k];
        A18[e] = UVAM[vbase + (size_t)(i0 + iq) * 320 + 160 + k];
    }
    if (t < 80) { wo[t] = w_attn_o[t]; bm[t] = b_msg_h[t]; }
    __syncthreads();

    const unsigned short* Pus  = (const unsigned short*)P;
    const unsigned short* PMus = (const unsigned short*)PM3;

    for (int ii = 0; ii < 8; ii++) {
        int i = i0 + ii;
        size_t pbase = ((size_t)b * 4096 + (size_t)i * 64) * 80;

        // ---- phase 1: stream P/PM3, compute score partials, stage PM3 ----
        for (int g = t; g < 640; g += 256) {       // (j, seg of 8 k)
            int j = g / 10, seg = g - j * 10;
            int k0 = seg * 8;
            uint4v pv = *(const uint4v*)(Pus  + pbase + (size_t)g * 8);
            uint4v mv = *(const uint4v*)(PMus + pbase + (size_t)g * 8);
            int wb = j * 41 + seg * 4;
            PMsW[wb + 0] = mv.x; PMsW[wb + 1] = mv.y;
            PMsW[wb + 2] = mv.z; PMsW[wb + 3] = mv.w;
            float acc = 0.f;
            const float* Uop = &U8[ii * 80 + k0];
            const float* Vop = &Vs[j * 85 + k0];
            const float* Wop = &wo[k0];
            #pragma unroll
            for (int q = 0; q < 4; q++) {
                unsigned w = pv[q];
                float x0 = Uop[2 * q]     + Vop[2 * q]     + bflo(w);
                x0 = x0 > 0.f ? x0 : 0.2f * x0;
                acc += x0 * Wop[2 * q];
                float x1 = Uop[2 * q + 1] + Vop[2 * q + 1] + bfhi(w);
                x1 = x1 > 0.f ? x1 : 0.2f * x1;
                acc += x1 * Wop[2 * q + 1];
            }
            part2[j * 11 + seg] = acc;
        }
        __syncthreads();

        // ---- masked softmax over j (wave 0), exact reference semantics ----
        if (t < 64) {
            float mj = mask[(size_t)b * 4096 + (size_t)i * 64 + t];
            float s = b_attn_o0;
            #pragma unroll
            for (int q = 0; q < 10; q++) s += part2[t * 11 + q];
            s *= mj;
            float m = s;
            #pragma unroll
            for (int off = 1; off < 64; off <<= 1) m = fmaxf(m, __shfl_xor(m, off, 64));
            float e = expf(s - m) * mj;
            float d = e;
            #pragma unroll
            for (int off = 1; off < 64; off <<= 1) d += __shfl_xor(d, off, 64);
            float p = e / (d + 1e-20f) * mj;
            probs[t] = p;
            float sp = p;
            #pragma unroll
            for (int off = 1; off < 64; off <<= 1) sp += __shfl_xor(sp, off, 64);
            if (t == 0) sum_p_sh = sp;
        }
        __syncthreads();

        // ---- message partials: 240 threads = 80 k x 3 j-groups ----
        if (t < 240) {
            int k = t % 80, jg = t / 80;
            float acc = 0.f;
            for (int j2 = jg; j2 < 64; j2 += 3) {
                unsigned w = PMsW[j2 * 41 + (k >> 1)];
                float pm = (k & 1) ? bfhi(w) : bflo(w);
                acc += probs[j2] * (Ams[j2 * 85 + k] + pm);
            }
            red[jg * 80 + k] = acc;
        }
        __syncthreads();

        if (t < 80) {
            float msg = red[t] + red[80 + t] + red[160 + t];
            size_t orow = ((size_t)hb * 64 + i) * 80 + t;
            float pre = sum_p_sh * A18[ii * 80 + t] + msg + bm[t] + ah0[orow];
            ah_next[orow] = pre > 0.f ? pre : 0.f;
        }
    }
}

// ---------------------------------------------------------------------------
// Merge: X[row][f] = concat(atom[row,:82], ah_merged[row,:640]); ld=724,
// cols 722/723 zeroed. 256 blocks x 8 rows.
// ---------------------------------------------------------------------------
__global__ __launch_bounds__(256) void merge_kernel(
    const float* __restrict__ atom, const float* __restrict__ ah,
    float* __restrict__ X)
{
    int r0 = blockIdx.x * 8;
    int t = threadIdx.x;
    for (int e = t; e < 8 * 724; e += 256) {
        int r = e / 724, f = e - r * 724;
        int row = r0 + r;
        float v;
        if (f < 82) {
            v = atom[(size_t)row * 82 + f];
        } else if (f < 722) {
            int q = f - 82, h = q / 80, k = q - h * 80;
            int b = row >> 6, i = row & 63;
            v = ah[(((size_t)(h * 32 + b)) * 64 + i) * 80 + k];
        } else {
            v = 0.f;
        }
        X[(size_t)row * 724 + f] = v;
    }
}

// ---------------------------------------------------------------------------
// Out GEMM: out[row,c] = relu(X[row,:722] @ W[:,c] + b[c])
// grid (64 rowtiles of 32, 4 coltiles of 64); K chunks of 128 (6 chunks).
// Thread: 2 rows x 4 cols. LDS: As[32][132], Ws[128][68].
// ---------------------------------------------------------------------------
__global__ __launch_bounds__(256) void out_gemm_kernel(
    const float* __restrict__ X, const float* __restrict__ W,
    const float* __restrict__ bo, float* __restrict__ out)
{
    __shared__ float As[32 * 132];
    __shared__ float Ws[128 * 68];
    int r0 = blockIdx.x * 32, c0 = blockIdx.y * 64;
    int t = threadIdx.x;
    int tx = t & 15, ty = t >> 4;

    float acc[2][4];
    #pragma unroll
    for (int r = 0; r < 2; r++)
        #pragma unroll
        for (int q = 0; q < 4; q++) acc[r][q] = 0.f;

    for (int ch = 0; ch < 6; ch++) {
        int f0 = ch * 128;
        // stage A chunk: 32 rows x 128 f (float4 groups)
        for (int e4 = t; e4 < 32 * 32; e4 += 256) {
            int r = e4 >> 5, fq = e4 & 31;
            float4v v;
            if (f0 + fq * 4 + 3 <= 723)
                v = *(const float4v*)(X + (size_t)(r0 + r) * 724 + f0 + fq * 4);
            else
                v = (float4v){0.f, 0.f, 0.f, 0.f};
            *(float4v*)(&As[r * 132 + fq * 4]) = v;
        }
        // stage W chunk: 128 f x 64 c (float4 groups)
        for (int e4 = t; e4 < 128 * 16; e4 += 256) {
            int fr = e4 >> 4, cq = e4 & 15;
            int fg = f0 + fr;
            float4v v;
            if (fg < 722)
                v = *(const float4v*)(W + (size_t)fg * 256 + c0 + cq * 4);
            else
                v = (float4v){0.f, 0.f, 0.f, 0.f};
            *(float4v*)(&Ws[fr * 68 + cq * 4]) = v;
        }
        __syncthreads();

        #pragma unroll 4
        for (int k = 0; k < 128; k++) {
            float a0 = As[(ty * 2 + 0) * 132 + k];
            float a1 = As[(ty * 2 + 1) * 132 + k];
            float4v w = *(const float4v*)(&Ws[k * 68 + tx * 4]);
            #pragma unroll
            for (int q = 0; q < 4; q++) {
                acc[0][q] += a0 * w[q];
                acc[1][q] += a1 * w[q];
            }
        }
        __syncthreads();
    }

    #pragma unroll
    for (int r = 0; r < 2; r++) {
        int row = r0 + ty * 2 + r;
        #pragma unroll
        for (int q = 0; q < 4; q++) {
            int c = c0 + tx * 4 + q;
            float v = acc[r][q] + bo[c];
            out[(size_t)row * 256 + c] = v > 0.f ? v : 0.f;
        }
    }
}

// ---------------------------------------------------------------------------
extern "C" void kernel_launch(void* const* d_in, const int* in_sizes, int n_in,
                              void* d_out, int out_size, void* d_ws, size_t ws_size,
                              hipStream_t stream)
{
    const float* atom_input = (const float*)d_in[0];
    const float* path_input = (const float*)d_in[1];
    const float* path_mask  = (const float*)d_in[2];
    const float* W_atom_i   = (const float*)d_in[3];
    const float* W_attn_h   = (const float*)d_in[4];
    const float* b_attn_h   = (const float*)d_in[5];
    const float* W_attn_o   = (const float*)d_in[6];
    const float* b_attn_o   = (const float*)d_in[7];
    const float* W_msg_h    = (const float*)d_in[8];
    const float* b_msg_h    = (const float*)d_in[9];
    const float* W_atom_o   = (const float*)d_in[10];
    const float* b_atom_o   = (const float*)d_in[11];
    float* out = (float*)d_out;

    // workspace carve-up (~74 MB)
    char* ws = (char*)d_ws;
    float* ah0   = (float*)ws;  ws += (size_t)16384 * 80 * 4;
    float* ah1   = (float*)ws;  ws += (size_t)16384 * 80 * 4;
    float* ah2   = (float*)ws;  ws += (size_t)16384 * 80 * 4;
    float* UVAM  = (float*)ws;  ws += (size_t)16384 * 320 * 4;
    bf16*  P     = (bf16*)ws;   ws += (size_t)131072 * 80 * 2;   // z=0
    bf16*  PM3   = (bf16*)ws;   ws += (size_t)131072 * 80 * 2;   // z=1
    float* Wpath = (float*)ws;  ws += (size_t)2 * 102 * 80 * 4;
    float* Wuvam = (float*)ws;  ws += (size_t)4 * 80 * 80 * 4;
    float* buvam = (float*)ws;  ws += (size_t)4 * 80 * 4;
    float* X = UVAM;   // 2048*724*4 = 5.9 MB, aliases UVAM (dead by then)

    prep_kernel<<<100, 256, 0, stream>>>(W_attn_h, b_attn_h, W_msg_h,
                                         Wpath, Wuvam, buvam);

    atom_proj_kernel<<<dim3(32, 8), 256, 0, stream>>>(atom_input, W_atom_i, ah0);

    // Path GEMMs (once): z=0 -> P, z=1 -> PM3
    gemm_z<bf16><<<dim3(2048, 2), 256, 0, stream>>>(
        path_input, 102, Wpath, nullptr, P, 80, (size_t)131072 * 80);

    const float* cur = ah0;
    float* nxt[2] = { ah1, ah2 };
    for (int layer = 0; layer < 2; layer++) {
        gemm_z<float><<<dim3(256, 4), 256, 0, stream>>>(
            cur, 80, Wuvam, buvam, UVAM, 320, 80);

        attn_layer_kernel<<<dim3(256, 8), 256, 0, stream>>>(
            UVAM, P, PM3, path_mask, W_attn_o, b_attn_o, b_msg_h, ah0, nxt[layer]);
        cur = nxt[layer];
    }

    merge_kernel<<<256, 256, 0, stream>>>(atom_input, cur, X);
    out_gemm_kernel<<<dim3(64, 4), 256, 0, stream>>>(X, W_atom_o, b_atom_o, out);
}

// Round 7
// 527.951 us; speedup vs baseline: 1.6332x; 1.1274x over previous
//
#include <hip/hip_runtime.h>
#include <hip/hip_bf16.h>

typedef __hip_bfloat16 bf16;
typedef float  float4v __attribute__((ext_vector_type(4)));
typedef unsigned uint4v __attribute__((ext_vector_type(4)));

// B=32, N=64, F_ATOM=82, F_PATH=102, H=8, DK=80, HIDDEN=256, DEPTH=3
// Inputs fp32, output fp32. hb = h*32 + b.

// ---------------------------------------------------------------------------
// Prep: pack weights.
// Wpath[z][102][80]: z0 = W_attn_h rows 160..261, z1 = W_msg_h rows 160..261
// Wuvam[z][80][80]:  z0 = W_attn_h[0:80], z1 = W_attn_h[80:160],
//                    z2 = W_msg_h[0:80],  z3 = W_msg_h[80:160]
// buvam[4][80]: z0 = b_attn_h, rest 0
// ---------------------------------------------------------------------------
__global__ __launch_bounds__(256) void prep_kernel(
    const float* __restrict__ W_attn_h, const float* __restrict__ b_attn_h,
    const float* __restrict__ W_msg_h,
    float* __restrict__ Wpath, float* __restrict__ Wuvam, float* __restrict__ buvam)
{
    int t = blockIdx.x * 256 + threadIdx.x;
    if (t < 2 * 102 * 80) {
        int z = t / (102 * 80), rc = t - z * (102 * 80);
        const float* src = z ? W_msg_h : W_attn_h;
        Wpath[t] = src[160 * 80 + rc];
    }
    if (t < 4 * 80 * 80) {
        int z = t / 6400, rc = t - z * 6400;
        const float* src = (z < 2) ? W_attn_h : W_msg_h;
        Wuvam[t] = src[(z & 1) * 6400 + rc];
    }
    if (t < 320) buvam[t] = (t < 80) ? b_attn_h[t] : 0.f;
}

// ---------------------------------------------------------------------------
// Atom projection: ah0[(h*32+b)*64+i][k] = atom[b,i,:82] @ W_atom_i[:, h*80+k]
// ---------------------------------------------------------------------------
__global__ __launch_bounds__(256) void atom_proj_kernel(
    const float* __restrict__ atom, const float* __restrict__ W,
    float* __restrict__ ah0)
{
    __shared__ float As[64 * 84];
    __shared__ float Ws[82 * 80];
    int rowBase = blockIdx.x * 64;
    int h = blockIdx.y;
    int t = threadIdx.x;

    for (int e = t; e < 64 * 82; e += 256) {
        int r = e / 82, c = e - r * 82;
        As[r * 84 + c] = atom[(size_t)(rowBase + r) * 82 + c];
    }
    for (int e = t; e < 82 * 80; e += 256) {
        int r = e / 80, c = e - r * 80;
        Ws[e] = W[(size_t)r * 640 + h * 80 + c];
    }
    __syncthreads();

    int tx = t & 15, ty = t >> 4;
    float acc[4][5];
    #pragma unroll
    for (int r = 0; r < 4; r++)
        #pragma unroll
        for (int c = 0; c < 5; c++) acc[r][c] = 0.f;

    for (int k = 0; k < 82; k++) {
        float a0 = As[(ty * 4 + 0) * 84 + k];
        float a1 = As[(ty * 4 + 1) * 84 + k];
        float a2 = As[(ty * 4 + 2) * 84 + k];
        float a3 = As[(ty * 4 + 3) * 84 + k];
        float w[5];
        #pragma unroll
        for (int c = 0; c < 5; c++) w[c] = Ws[k * 80 + c * 16 + tx];
        #pragma unroll
        for (int c = 0; c < 5; c++) {
            acc[0][c] += a0 * w[c];
            acc[1][c] += a1 * w[c];
            acc[2][c] += a2 * w[c];
            acc[3][c] += a3 * w[c];
        }
    }

    #pragma unroll
    for (int r = 0; r < 4; r++) {
        int row = rowBase + ty * 4 + r;
        int b = row >> 6, i = row & 63;
        size_t obase = (((size_t)(h * 32 + b)) * 64 + i) * 80;
        #pragma unroll
        for (int c = 0; c < 5; c++)
            ah0[obase + c * 16 + tx] = acc[r][c];
    }
}

// ---------------------------------------------------------------------------
// Path GEMM. grid (2048, 2). Rows of a tile = j (fixed b,i). K=102.
// z=0 -> PT[b*64+i][k][j] bf16 (transposed via LDS bounce, reusing Ws)
// z=1 -> PM3[(b,i,j)][k] bf16 (direct)
// ---------------------------------------------------------------------------
__global__ __launch_bounds__(256) void path_gemm_kernel(
    const float* __restrict__ A, const float* __restrict__ Wpath,
    bf16* __restrict__ PT, bf16* __restrict__ PM3)
{
    __shared__ float As[64 * 105];
    __shared__ float Ws[102 * 80];          // reused as TT (bf16, 80x66) for z=0
    int z = blockIdx.y;
    const float* W = Wpath + z * 102 * 80;
    int rowBase = blockIdx.x * 64;
    int t = threadIdx.x;

    for (int e = t; e < 64 * 102; e += 256) {
        int r = e / 102, c = e - r * 102;
        As[r * 105 + c] = A[(size_t)(rowBase + r) * 102 + c];
    }
    for (int e = t; e < 102 * 80; e += 256) Ws[e] = W[e];
    __syncthreads();

    int tx = t & 15, ty = t >> 4;
    float acc[4][5];
    #pragma unroll
    for (int r = 0; r < 4; r++)
        #pragma unroll
        for (int c = 0; c < 5; c++) acc[r][c] = 0.f;

    for (int k = 0; k < 102; k++) {
        float a0 = As[(ty * 4 + 0) * 105 + k];
        float a1 = As[(ty * 4 + 1) * 105 + k];
        float a2 = As[(ty * 4 + 2) * 105 + k];
        float a3 = As[(ty * 4 + 3) * 105 + k];
        float w[5];
        #pragma unroll
        for (int c = 0; c < 5; c++) w[c] = Ws[k * 80 + c * 16 + tx];
        #pragma unroll
        for (int c = 0; c < 5; c++) {
            acc[0][c] += a0 * w[c];
            acc[1][c] += a1 * w[c];
            acc[2][c] += a2 * w[c];
            acc[3][c] += a3 * w[c];
        }
    }

    if (z == 1) {
        #pragma unroll
        for (int r = 0; r < 4; r++) {
            size_t row = rowBase + ty * 4 + r;
            #pragma unroll
            for (int c = 0; c < 5; c++)
                PM3[row * 80 + c * 16 + tx] = (bf16)acc[r][c];
        }
    } else {
        __syncthreads();                    // Ws dead everywhere
        bf16* TT = (bf16*)Ws;               // [80][66] padded
        #pragma unroll
        for (int r = 0; r < 4; r++)
            #pragma unroll
            for (int c = 0; c < 5; c++)
                TT[(c * 16 + tx) * 66 + ty * 4 + r] = (bf16)acc[r][c];
        __syncthreads();
        size_t pb = (size_t)blockIdx.x * 5120;
        for (int e = t; e < 5120; e += 256)
            PT[pb + e] = TT[(e >> 6) * 66 + (e & 63)];
    }
}

// ---------------------------------------------------------------------------
// UVAM GEMM. grid (256, 4). blockIdx.x = hb (64 rows = j). K=80.
// z=0 -> UVAM col 0 (U + b_attn_h); z=2 -> col 80 (AM1); z=3 -> col 160 (AM2)
// z=1 -> VT[hb][k][j] bf16 (transposed via LDS bounce)
// ---------------------------------------------------------------------------
__global__ __launch_bounds__(256) void uvam_gemm_kernel(
    const float* __restrict__ A, const float* __restrict__ Wuvam,
    const float* __restrict__ buvam,
    float* __restrict__ UVAM, bf16* __restrict__ VT)
{
    __shared__ float As[64 * 105];
    __shared__ float Ws[80 * 80];           // reused as TT for z=1
    int z = blockIdx.y;
    const float* W = Wuvam + z * 6400;
    int rowBase = blockIdx.x * 64;
    int t = threadIdx.x;

    for (int e = t; e < 64 * 80; e += 256) {
        int r = e / 80, c = e - r * 80;
        As[r * 105 + c] = A[(size_t)(rowBase + r) * 80 + c];
    }
    for (int e = t; e < 6400; e += 256) Ws[e] = W[e];
    __syncthreads();

    int tx = t & 15, ty = t >> 4;
    float acc[4][5];
    #pragma unroll
    for (int r = 0; r < 4; r++)
        #pragma unroll
        for (int c = 0; c < 5; c++) acc[r][c] = 0.f;

    for (int k = 0; k < 80; k++) {
        float a0 = As[(ty * 4 + 0) * 105 + k];
        float a1 = As[(ty * 4 + 1) * 105 + k];
        float a2 = As[(ty * 4 + 2) * 105 + k];
        float a3 = As[(ty * 4 + 3) * 105 + k];
        float w[5];
        #pragma unroll
        for (int c = 0; c < 5; c++) w[c] = Ws[k * 80 + c * 16 + tx];
        #pragma unroll
        for (int c = 0; c < 5; c++) {
            acc[0][c] += a0 * w[c];
            acc[1][c] += a1 * w[c];
            acc[2][c] += a2 * w[c];
            acc[3][c] += a3 * w[c];
        }
    }

    if (z == 1) {
        __syncthreads();
        bf16* TT = (bf16*)Ws;               // [80][66]
        #pragma unroll
        for (int r = 0; r < 4; r++)
            #pragma unroll
            for (int c = 0; c < 5; c++)
                TT[(c * 16 + tx) * 66 + ty * 4 + r] = (bf16)acc[r][c];
        __syncthreads();
        size_t pb = (size_t)blockIdx.x * 5120;
        for (int e = t; e < 5120; e += 256)
            VT[pb + e] = TT[(e >> 6) * 66 + (e & 63)];
    } else {
        int col0 = (z == 0) ? 0 : (z == 2 ? 80 : 160);
        float bv[5];
        #pragma unroll
        for (int c = 0; c < 5; c++) bv[c] = buvam[z * 80 + c * 16 + tx];
        #pragma unroll
        for (int r = 0; r < 4; r++) {
            size_t row = rowBase + ty * 4 + r;
            #pragma unroll
            for (int c = 0; c < 5; c++)
                UVAM[row * 240 + col0 + c * 16 + tx] = acc[r][c] + bv[c];
        }
    }
}

// ---------------------------------------------------------------------------
// Fused attention layer: one wave per (hb,i). Zero barriers after staging.
// grid x = it4*256 + hb (1024 blocks, 4 waves, 4 i per wave).
// Score: lane=j, reads PT[b,i,k,j] (global bf16) + VTs (LDS bf16).
// Softmax: in-wave shuffles, exact reference mask semantics.
// Message: lane=k, reads PM3[b,i,j,k] (global bf16) + AMs (LDS bf16).
// ---------------------------------------------------------------------------
__global__ __launch_bounds__(256) void attn_layer_kernel(
    const float* __restrict__ UVAM,   // [16384][240]: U+b | AM1 | AM2
    const bf16* __restrict__ VT,      // [256][80][64]
    const bf16* __restrict__ PT,      // [2048][80][64]
    const bf16* __restrict__ PM3,     // [131072][80]
    const float* __restrict__ mask,
    const float* __restrict__ w_attn_o, const float* __restrict__ b_attn_o,
    const float* __restrict__ b_msg_h,
    const float* __restrict__ ah0, float* __restrict__ ah_next)
{
    __shared__ bf16 VTs[80 * 64];
    __shared__ bf16 AMs[64 * 80];
    __shared__ float U16[16 * 80], A116[16 * 80];
    __shared__ float wo[80], bm[80];
    __shared__ float PS[4][64];

    int x = blockIdx.x;
    int hb = x & 255, it4 = x >> 8;
    int b = hb & 31;
    int i0 = it4 * 16;
    int t = threadIdx.x;
    size_t vbase = (size_t)hb * 64 * 240;

    {   // VT slab: 5120 bf16 = 640 uint4
        const uint4v* src = (const uint4v*)(VT + (size_t)hb * 5120);
        uint4v* dst = (uint4v*)VTs;
        for (int e = t; e < 640; e += 256) dst[e] = src[e];
    }
    for (int e = t; e < 5120; e += 256) {
        int j = e / 80, k = e - j * 80;
        AMs[e] = (bf16)UVAM[vbase + (size_t)j * 240 + 160 + k];
    }
    for (int e = t; e < 1280; e += 256) {
        int iq = e / 80, k = e - iq * 80;
        U16[e]  = UVAM[vbase + (size_t)(i0 + iq) * 240 + k];
        A116[e] = UVAM[vbase + (size_t)(i0 + iq) * 240 + 80 + k];
    }
    if (t < 80) { wo[t] = w_attn_o[t]; bm[t] = b_msg_h[t]; }
    __syncthreads();

    int wave = t >> 6, lane = t & 63;
    float b0 = b_attn_o[0];

    for (int q = 0; q < 4; q++) {
        int ii = wave * 4 + q;
        int i = i0 + ii;

        // ---- score: lane = j ----
        const bf16* ptp = PT + ((size_t)(b * 64 + i)) * 5120 + lane;
        float s = 0.f;
        #pragma unroll 8
        for (int k = 0; k < 80; k++) {
            float pt = (float)ptp[k * 64];
            float vt = (float)VTs[k * 64 + lane];
            float xx = U16[ii * 80 + k] + vt + pt;
            xx = xx > 0.f ? xx : 0.2f * xx;
            s += xx * wo[k];
        }
        float mj = mask[(size_t)b * 4096 + (size_t)i * 64 + lane];
        float sc = (s + b0) * mj;
        float m = sc;
        #pragma unroll
        for (int off = 1; off < 64; off <<= 1) m = fmaxf(m, __shfl_xor(m, off, 64));
        float e = expf(sc - m) * mj;
        float d = e;
        #pragma unroll
        for (int off = 1; off < 64; off <<= 1) d += __shfl_xor(d, off, 64);
        float p = e / (d + 1e-20f) * mj;
        PS[wave][lane] = p;
        float sp = p;
        #pragma unroll
        for (int off = 1; off < 64; off <<= 1) sp += __shfl_xor(sp, off, 64);

        // ---- message: lane = k (k=lane, plus k=64+lane for lane<16) ----
        const bf16* pmp = PM3 + ((size_t)(b * 4096 + i * 64)) * 80;
        float m0 = 0.f, m1 = 0.f;
        bool hi = lane < 16;
        #pragma unroll 4
        for (int j = 0; j < 64; j++) {
            float pj = PS[wave][j];
            float q0 = (float)pmp[j * 80 + lane] + (float)AMs[j * 80 + lane];
            m0 += pj * q0;
            if (hi) {
                float q1 = (float)pmp[j * 80 + 64 + lane] + (float)AMs[j * 80 + 64 + lane];
                m1 += pj * q1;
            }
        }

        size_t orow = ((size_t)hb * 64 + i) * 80;
        {
            float pre = sp * A116[ii * 80 + lane] + m0 + bm[lane] + ah0[orow + lane];
            ah_next[orow + lane] = pre > 0.f ? pre : 0.f;
            if (hi) {
                int k2 = 64 + lane;
                float pre2 = sp * A116[ii * 80 + k2] + m1 + bm[k2] + ah0[orow + k2];
                ah_next[orow + k2] = pre2 > 0.f ? pre2 : 0.f;
            }
        }
    }
}

// ---------------------------------------------------------------------------
// Merge: X[row][f] = concat(atom[row,:82], ah_merged[row,:640]); ld=724.
// ---------------------------------------------------------------------------
__global__ __launch_bounds__(256) void merge_kernel(
    const float* __restrict__ atom, const float* __restrict__ ah,
    float* __restrict__ X)
{
    int r0 = blockIdx.x * 8;
    int t = threadIdx.x;
    for (int e = t; e < 8 * 724; e += 256) {
        int r = e / 724, f = e - r * 724;
        int row = r0 + r;
        float v;
        if (f < 82) {
            v = atom[(size_t)row * 82 + f];
        } else if (f < 722) {
            int q = f - 82, h = q / 80, k = q - h * 80;
            int b = row >> 6, i = row & 63;
            v = ah[(((size_t)(h * 32 + b)) * 64 + i) * 80 + k];
        } else {
            v = 0.f;
        }
        X[(size_t)row * 724 + f] = v;
    }
}

// ---------------------------------------------------------------------------
// Out GEMM: out[row,c] = relu(X[row,:722] @ W[:,c] + b[c])
// ---------------------------------------------------------------------------
__global__ __launch_bounds__(256) void out_gemm_kernel(
    const float* __restrict__ X, const float* __restrict__ W,
    const float* __restrict__ bo, float* __restrict__ out)
{
    __shared__ float As[32 * 132];
    __shared__ float Ws[128 * 68];
    int r0 = blockIdx.x * 32, c0 = blockIdx.y * 64;
    int t = threadIdx.x;
    int tx = t & 15, ty = t >> 4;

    float acc[2][4];
    #pragma unroll
    for (int r = 0; r < 2; r++)
        #pragma unroll
        for (int q = 0; q < 4; q++) acc[r][q] = 0.f;

    for (int ch = 0; ch < 6; ch++) {
        int f0 = ch * 128;
        for (int e4 = t; e4 < 32 * 32; e4 += 256) {
            int r = e4 >> 5, fq = e4 & 31;
            float4v v;
            if (f0 + fq * 4 + 3 <= 723)
                v = *(const float4v*)(X + (size_t)(r0 + r) * 724 + f0 + fq * 4);
            else
                v = (float4v){0.f, 0.f, 0.f, 0.f};
            *(float4v*)(&As[r * 132 + fq * 4]) = v;
        }
        for (int e4 = t; e4 < 128 * 16; e4 += 256) {
            int fr = e4 >> 4, cq = e4 & 15;
            int fg = f0 + fr;
            float4v v;
            if (fg < 722)
                v = *(const float4v*)(W + (size_t)fg * 256 + c0 + cq * 4);
            else
                v = (float4v){0.f, 0.f, 0.f, 0.f};
            *(float4v*)(&Ws[fr * 68 + cq * 4]) = v;
        }
        __syncthreads();

        #pragma unroll 4
        for (int k = 0; k < 128; k++) {
            float a0 = As[(ty * 2 + 0) * 132 + k];
            float a1 = As[(ty * 2 + 1) * 132 + k];
            float4v w = *(const float4v*)(&Ws[k * 68 + tx * 4]);
            #pragma unroll
            for (int q = 0; q < 4; q++) {
                acc[0][q] += a0 * w[q];
                acc[1][q] += a1 * w[q];
            }
        }
        __syncthreads();
    }

    #pragma unroll
    for (int r = 0; r < 2; r++) {
        int row = r0 + ty * 2 + r;
        #pragma unroll
        for (int q = 0; q < 4; q++) {
            int c = c0 + tx * 4 + q;
            float v = acc[r][q] + bo[c];
            out[(size_t)row * 256 + c] = v > 0.f ? v : 0.f;
        }
    }
}

// ---------------------------------------------------------------------------
extern "C" void kernel_launch(void* const* d_in, const int* in_sizes, int n_in,
                              void* d_out, int out_size, void* d_ws, size_t ws_size,
                              hipStream_t stream)
{
    const float* atom_input = (const float*)d_in[0];
    const float* path_input = (const float*)d_in[1];
    const float* path_mask  = (const float*)d_in[2];
    const float* W_atom_i   = (const float*)d_in[3];
    const float* W_attn_h   = (const float*)d_in[4];
    const float* b_attn_h   = (const float*)d_in[5];
    const float* W_attn_o   = (const float*)d_in[6];
    const float* b_attn_o   = (const float*)d_in[7];
    const float* W_msg_h    = (const float*)d_in[8];
    const float* b_msg_h    = (const float*)d_in[9];
    const float* W_atom_o   = (const float*)d_in[10];
    const float* b_atom_o   = (const float*)d_in[11];
    float* out = (float*)d_out;

    // workspace carve-up (~71 MB)
    char* ws = (char*)d_ws;
    float* ah0   = (float*)ws;  ws += (size_t)16384 * 80 * 4;    // 5.25 MB
    float* ah1   = (float*)ws;  ws += (size_t)16384 * 80 * 4;    // 5.25 MB
    float* UVAM  = (float*)ws;  ws += (size_t)16384 * 240 * 4;   // 15.7 MB
    bf16*  PT    = (bf16*)ws;   ws += (size_t)2048 * 5120 * 2;   // 21 MB
    bf16*  PM3   = (bf16*)ws;   ws += (size_t)131072 * 80 * 2;   // 21 MB
    bf16*  VT    = (bf16*)ws;   ws += (size_t)256 * 5120 * 2;    // 2.6 MB
    float* Wpath = (float*)ws;  ws += (size_t)2 * 102 * 80 * 4;
    float* Wuvam = (float*)ws;  ws += (size_t)4 * 80 * 80 * 4;
    float* buvam = (float*)ws;  ws += (size_t)4 * 80 * 4;
    float* X = UVAM;   // 2048*724*4 = 5.9 MB, aliases UVAM (dead by then)

    prep_kernel<<<100, 256, 0, stream>>>(W_attn_h, b_attn_h, W_msg_h,
                                         Wpath, Wuvam, buvam);

    atom_proj_kernel<<<dim3(32, 8), 256, 0, stream>>>(atom_input, W_atom_i, ah0);

    path_gemm_kernel<<<dim3(2048, 2), 256, 0, stream>>>(path_input, Wpath, PT, PM3);

    const float* cur = ah0;
    float* nxt[2] = { ah1, ah1 };   // layer2 may safely reuse ah1 (attn doesn't read cur)
    for (int layer = 0; layer < 2; layer++) {
        uvam_gemm_kernel<<<dim3(256, 4), 256, 0, stream>>>(
            cur, Wuvam, buvam, UVAM, VT);

        attn_layer_kernel<<<1024, 256, 0, stream>>>(
            UVAM, VT, PT, PM3, path_mask, W_attn_o, b_attn_o, b_msg_h,
            ah0, nxt[layer]);
        cur = nxt[layer];
    }

    merge_kernel<<<256, 256, 0, stream>>>(atom_input, cur, X);
    out_gemm_kernel<<<dim3(64, 4), 256, 0, stream>>>(X, W_atom_o, b_atom_o, out);
}

// Round 8
// 490.896 us; speedup vs baseline: 1.7564x; 1.0755x over previous
//
#include <hip/hip_runtime.h>
#include <hip/hip_bf16.h>

typedef __hip_bfloat16 bf16;
typedef float  float4v __attribute__((ext_vector_type(4)));
typedef unsigned uint4v __attribute__((ext_vector_type(4)));
typedef short  short8 __attribute__((ext_vector_type(8)));
typedef float  f32x4  __attribute__((ext_vector_type(4)));

// B=32, N=64, F_ATOM=82, F_PATH=102, H=8, DK=80, HIDDEN=256, DEPTH=3
// Inputs fp32, output fp32. hb = h*32 + b.

// ---------------------------------------------------------------------------
// Prep: pack weights.
// WTg[z][80][128] bf16: WTg[z][n][k] = Wsrc_z[160+k][n]  (k<102, else 0)
// Wuvam[z][80][80] fp32, buvam[4][80] fp32 (z0 = b_attn_h, rest 0)
// ---------------------------------------------------------------------------
__global__ __launch_bounds__(256) void prep_kernel(
    const float* __restrict__ W_attn_h, const float* __restrict__ b_attn_h,
    const float* __restrict__ W_msg_h,
    bf16* __restrict__ WTg, float* __restrict__ Wuvam, float* __restrict__ buvam)
{
    int t = blockIdx.x * 256 + threadIdx.x;
    if (t < 2 * 80 * 128) {
        int z = t / 10240, rem = t - z * 10240;
        int n = rem >> 7, k = rem & 127;
        const float* src = z ? W_msg_h : W_attn_h;
        float v = (k < 102) ? src[(160 + k) * 80 + n] : 0.f;
        WTg[t] = (bf16)v;
    }
    if (t < 4 * 80 * 80) {
        int z = t / 6400, rc = t - z * 6400;
        const float* src = (z < 2) ? W_attn_h : W_msg_h;
        Wuvam[t] = src[(z & 1) * 6400 + rc];
    }
    if (t < 320) buvam[t] = (t < 80) ? b_attn_h[t] : 0.f;
}

// ---------------------------------------------------------------------------
// Atom projection: ah0[(h*32+b)*64+i][k] = atom[b,i,:82] @ W_atom_i[:, h*80+k]
// ---------------------------------------------------------------------------
__global__ __launch_bounds__(256) void atom_proj_kernel(
    const float* __restrict__ atom, const float* __restrict__ W,
    float* __restrict__ ah0)
{
    __shared__ float As[64 * 84];
    __shared__ float Ws[82 * 80];
    int rowBase = blockIdx.x * 64;
    int h = blockIdx.y;
    int t = threadIdx.x;

    for (int e = t; e < 64 * 82; e += 256) {
        int r = e / 82, c = e - r * 82;
        As[r * 84 + c] = atom[(size_t)(rowBase + r) * 82 + c];
    }
    for (int e = t; e < 82 * 80; e += 256) {
        int r = e / 80, c = e - r * 80;
        Ws[e] = W[(size_t)r * 640 + h * 80 + c];
    }
    __syncthreads();

    int tx = t & 15, ty = t >> 4;
    float acc[4][5];
    #pragma unroll
    for (int r = 0; r < 4; r++)
        #pragma unroll
        for (int c = 0; c < 5; c++) acc[r][c] = 0.f;

    for (int k = 0; k < 82; k++) {
        float a0 = As[(ty * 4 + 0) * 84 + k];
        float a1 = As[(ty * 4 + 1) * 84 + k];
        float a2 = As[(ty * 4 + 2) * 84 + k];
        float a3 = As[(ty * 4 + 3) * 84 + k];
        float w[5];
        #pragma unroll
        for (int c = 0; c < 5; c++) w[c] = Ws[k * 80 + c * 16 + tx];
        #pragma unroll
        for (int c = 0; c < 5; c++) {
            acc[0][c] += a0 * w[c];
            acc[1][c] += a1 * w[c];
            acc[2][c] += a2 * w[c];
            acc[3][c] += a3 * w[c];
        }
    }

    #pragma unroll
    for (int r = 0; r < 4; r++) {
        int row = rowBase + ty * 4 + r;
        int b = row >> 6, i = row & 63;
        size_t obase = (((size_t)(h * 32 + b)) * 64 + i) * 80;
        #pragma unroll
        for (int c = 0; c < 5; c++)
            ah0[obase + c * 16 + tx] = acc[r][c];
    }
}

// ---------------------------------------------------------------------------
// Path GEMM via MFMA (bf16 in, fp32 acc). 2048 blocks, one per (b,i).
// Computes both z from one A staging:
//   z=0 -> PT[b*64+i][k][j]   (transposed, via LDS bounce)
//   z=1 -> PM3[(b,i,j)][k]    (direct, via LDS bounce)
// A tile 64(j) x 128(K, padded from 102), LDS pitch 136 bf16 (2-way only).
// Wave w = row-tile w (16 j); per K=32 chunk: 1 a-frag + 10 b-frags, 10 MFMA.
// C/D layout (16x16x32): col n = lane&15, row m = (lane>>4)*4 + reg.
// ---------------------------------------------------------------------------
__global__ __launch_bounds__(256) void path_gemm_mfma(
    const float* __restrict__ A,      // [131072][102]
    const bf16* __restrict__ WTg,     // [2][80][128]
    bf16* __restrict__ PT, bf16* __restrict__ PM3)
{
    __shared__ bf16 Als[64 * 136];        // 17.4 KB; epilogue: Cb[64][80]
    __shared__ bf16 WTs[2 * 80 * 136];    // 43.5 KB; epilogue: CbT[80][66]

    int t = threadIdx.x;
    int bx = blockIdx.x;
    size_t abase = (size_t)bx * 64 * 102;

    // stage A (fp32 -> bf16, zero-pad K to 128)
    for (int e = t; e < 8192; e += 256) {
        int r = e >> 7, c = e & 127;
        float v = (c < 102) ? A[abase + (size_t)r * 102 + c] : 0.f;
        Als[r * 136 + c] = (bf16)v;
    }
    // stage WT (uint = 2 bf16; 136 bf16 = 68 uints per row)
    {
        const unsigned* src = (const unsigned*)WTg;
        unsigned* dst = (unsigned*)WTs;
        for (int e2 = t; e2 < 10240; e2 += 256) {
            int zr = e2 >> 6, c2 = e2 & 63;
            dst[zr * 68 + c2] = src[e2];
        }
    }
    __syncthreads();

    int wave = t >> 6, lane = t & 63;
    int ln = lane & 15, quad = lane >> 4;

    f32x4 acc[2][5];
    #pragma unroll
    for (int z = 0; z < 2; z++)
        #pragma unroll
        for (int c = 0; c < 5; c++) acc[z][c] = (f32x4){0.f, 0.f, 0.f, 0.f};

    const short* Ap = (const short*)Als + (wave * 16 + ln) * 136;
    const short* Wp = (const short*)WTs;

    #pragma unroll
    for (int kc = 0; kc < 4; kc++) {
        int k0 = kc * 32 + quad * 8;
        short8 af = *(const short8*)(Ap + k0);
        #pragma unroll
        for (int z = 0; z < 2; z++)
            #pragma unroll
            for (int c = 0; c < 5; c++) {
                short8 bfr = *(const short8*)(Wp + (z * 80 + c * 16 + ln) * 136 + k0);
                acc[z][c] = __builtin_amdgcn_mfma_f32_16x16x32_bf16(
                    af, bfr, acc[z][c], 0, 0, 0);
            }
    }
    __syncthreads();

    // epilogue bounce: CbT[80][66] (z=0 transposed), Cb[64][80] (z=1 direct)
    bf16* Cb  = Als;
    bf16* CbT = WTs;
    #pragma unroll
    for (int c = 0; c < 5; c++) {
        int n = c * 16 + ln;
        #pragma unroll
        for (int r = 0; r < 4; r++) {
            int m = wave * 16 + quad * 4 + r;
            CbT[n * 66 + m] = (bf16)acc[0][c][r];
            Cb[m * 80 + n]  = (bf16)acc[1][c][r];
        }
    }
    __syncthreads();

    size_t pb = (size_t)bx * 5120;
    for (int e = t; e < 5120; e += 256) {
        PT[pb + e]  = CbT[(e >> 6) * 66 + (e & 63)];
        PM3[pb + e] = Cb[e];
    }
}

// ---------------------------------------------------------------------------
// UVAM GEMM. grid (256, 4). blockIdx.x = hb (64 rows = j). K=80.
// z=0 -> UVAM col 0 (U + b_attn_h); z=2 -> col 80 (AM1); z=3 -> col 160 (AM2)
// z=1 -> VT[hb][k][j] bf16 (transposed via LDS bounce)
// ---------------------------------------------------------------------------
__global__ __launch_bounds__(256) void uvam_gemm_kernel(
    const float* __restrict__ A, const float* __restrict__ Wuvam,
    const float* __restrict__ buvam,
    float* __restrict__ UVAM, bf16* __restrict__ VT)
{
    __shared__ float As[64 * 105];
    __shared__ float Ws[80 * 80];           // reused as TT for z=1
    int z = blockIdx.y;
    const float* W = Wuvam + z * 6400;
    int rowBase = blockIdx.x * 64;
    int t = threadIdx.x;

    for (int e = t; e < 64 * 80; e += 256) {
        int r = e / 80, c = e - r * 80;
        As[r * 105 + c] = A[(size_t)(rowBase + r) * 80 + c];
    }
    for (int e = t; e < 6400; e += 256) Ws[e] = W[e];
    __syncthreads();

    int tx = t & 15, ty = t >> 4;
    float acc[4][5];
    #pragma unroll
    for (int r = 0; r < 4; r++)
        #pragma unroll
        for (int c = 0; c < 5; c++) acc[r][c] = 0.f;

    for (int k = 0; k < 80; k++) {
        float a0 = As[(ty * 4 + 0) * 105 + k];
        float a1 = As[(ty * 4 + 1) * 105 + k];
        float a2 = As[(ty * 4 + 2) * 105 + k];
        float a3 = As[(ty * 4 + 3) * 105 + k];
        float w[5];
        #pragma unroll
        for (int c = 0; c < 5; c++) w[c] = Ws[k * 80 + c * 16 + tx];
        #pragma unroll
        for (int c = 0; c < 5; c++) {
            acc[0][c] += a0 * w[c];
            acc[1][c] += a1 * w[c];
            acc[2][c] += a2 * w[c];
            acc[3][c] += a3 * w[c];
        }
    }

    if (z == 1) {
        __syncthreads();
        bf16* TT = (bf16*)Ws;               // [80][66]
        #pragma unroll
        for (int r = 0; r < 4; r++)
            #pragma unroll
            for (int c = 0; c < 5; c++)
                TT[(c * 16 + tx) * 66 + ty * 4 + r] = (bf16)acc[r][c];
        __syncthreads();
        size_t pb = (size_t)blockIdx.x * 5120;
        for (int e = t; e < 5120; e += 256)
            VT[pb + e] = TT[(e >> 6) * 66 + (e & 63)];
    } else {
        int col0 = (z == 0) ? 0 : (z == 2 ? 80 : 160);
        float bv[5];
        #pragma unroll
        for (int c = 0; c < 5; c++) bv[c] = buvam[z * 80 + c * 16 + tx];
        #pragma unroll
        for (int r = 0; r < 4; r++) {
            size_t row = rowBase + ty * 4 + r;
            #pragma unroll
            for (int c = 0; c < 5; c++)
                UVAM[row * 240 + col0 + c * 16 + tx] = acc[r][c] + bv[c];
        }
    }
}

// ---------------------------------------------------------------------------
// Fused attention layer: one wave per (hb,i). Zero barriers after staging.
// ---------------------------------------------------------------------------
__global__ __launch_bounds__(256) void attn_layer_kernel(
    const float* __restrict__ UVAM,   // [16384][240]: U+b | AM1 | AM2
    const bf16* __restrict__ VT,      // [256][80][64]
    const bf16* __restrict__ PT,      // [2048][80][64]
    const bf16* __restrict__ PM3,     // [131072][80]
    const float* __restrict__ mask,
    const float* __restrict__ w_attn_o, const float* __restrict__ b_attn_o,
    const float* __restrict__ b_msg_h,
    const float* __restrict__ ah0, float* __restrict__ ah_next)
{
    __shared__ bf16 VTs[80 * 64];
    __shared__ bf16 AMs[64 * 80];
    __shared__ float U16[16 * 80], A116[16 * 80];
    __shared__ float wo[80], bm[80];
    __shared__ float PS[4][64];

    int x = blockIdx.x;
    int hb = x & 255, it4 = x >> 8;
    int b = hb & 31;
    int i0 = it4 * 16;
    int t = threadIdx.x;
    size_t vbase = (size_t)hb * 64 * 240;

    {
        const uint4v* src = (const uint4v*)(VT + (size_t)hb * 5120);
        uint4v* dst = (uint4v*)VTs;
        for (int e = t; e < 640; e += 256) dst[e] = src[e];
    }
    for (int e = t; e < 5120; e += 256) {
        int j = e / 80, k = e - j * 80;
        AMs[e] = (bf16)UVAM[vbase + (size_t)j * 240 + 160 + k];
    }
    for (int e = t; e < 1280; e += 256) {
        int iq = e / 80, k = e - iq * 80;
        U16[e]  = UVAM[vbase + (size_t)(i0 + iq) * 240 + k];
        A116[e] = UVAM[vbase + (size_t)(i0 + iq) * 240 + 80 + k];
    }
    if (t < 80) { wo[t] = w_attn_o[t]; bm[t] = b_msg_h[t]; }
    __syncthreads();

    int wave = t >> 6, lane = t & 63;
    float b0 = b_attn_o[0];

    for (int q = 0; q < 4; q++) {
        int ii = wave * 4 + q;
        int i = i0 + ii;

        // ---- score: lane = j ----
        const bf16* ptp = PT + ((size_t)(b * 64 + i)) * 5120 + lane;
        float s = 0.f;
        #pragma unroll 8
        for (int k = 0; k < 80; k++) {
            float pt = (float)ptp[k * 64];
            float vt = (float)VTs[k * 64 + lane];
            float xx = U16[ii * 80 + k] + vt + pt;
            xx = xx > 0.f ? xx : 0.2f * xx;
            s += xx * wo[k];
        }
        float mj = mask[(size_t)b * 4096 + (size_t)i * 64 + lane];
        float sc = (s + b0) * mj;
        float m = sc;
        #pragma unroll
        for (int off = 1; off < 64; off <<= 1) m = fmaxf(m, __shfl_xor(m, off, 64));
        float e = expf(sc - m) * mj;
        float d = e;
        #pragma unroll
        for (int off = 1; off < 64; off <<= 1) d += __shfl_xor(d, off, 64);
        float p = e / (d + 1e-20f) * mj;
        PS[wave][lane] = p;
        float sp = p;
        #pragma unroll
        for (int off = 1; off < 64; off <<= 1) sp += __shfl_xor(sp, off, 64);

        // ---- message: lane = k ----
        const bf16* pmp = PM3 + ((size_t)(b * 4096 + i * 64)) * 80;
        float m0 = 0.f, m1 = 0.f;
        bool hi = lane < 16;
        #pragma unroll 4
        for (int j = 0; j < 64; j++) {
            float pj = PS[wave][j];
            float q0 = (float)pmp[j * 80 + lane] + (float)AMs[j * 80 + lane];
            m0 += pj * q0;
            if (hi) {
                float q1 = (float)pmp[j * 80 + 64 + lane] + (float)AMs[j * 80 + 64 + lane];
                m1 += pj * q1;
            }
        }

        size_t orow = ((size_t)hb * 64 + i) * 80;
        {
            float pre = sp * A116[ii * 80 + lane] + m0 + bm[lane] + ah0[orow + lane];
            ah_next[orow + lane] = pre > 0.f ? pre : 0.f;
            if (hi) {
                int k2 = 64 + lane;
                float pre2 = sp * A116[ii * 80 + k2] + m1 + bm[k2] + ah0[orow + k2];
                ah_next[orow + k2] = pre2 > 0.f ? pre2 : 0.f;
            }
        }
    }
}

// ---------------------------------------------------------------------------
// Merge: X[row][f] = concat(atom[row,:82], ah_merged[row,:640]); ld=724.
// ---------------------------------------------------------------------------
__global__ __launch_bounds__(256) void merge_kernel(
    const float* __restrict__ atom, const float* __restrict__ ah,
    float* __restrict__ X)
{
    int r0 = blockIdx.x * 8;
    int t = threadIdx.x;
    for (int e = t; e < 8 * 724; e += 256) {
        int r = e / 724, f = e - r * 724;
        int row = r0 + r;
        float v;
        if (f < 82) {
            v = atom[(size_t)row * 82 + f];
        } else if (f < 722) {
            int q = f - 82, h = q / 80, k = q - h * 80;
            int b = row >> 6, i = row & 63;
            v = ah[(((size_t)(h * 32 + b)) * 64 + i) * 80 + k];
        } else {
            v = 0.f;
        }
        X[(size_t)row * 724 + f] = v;
    }
}

// ---------------------------------------------------------------------------
// Out GEMM: out[row,c] = relu(X[row,:722] @ W[:,c] + b[c])
// ---------------------------------------------------------------------------
__global__ __launch_bounds__(256) void out_gemm_kernel(
    const float* __restrict__ X, const float* __restrict__ W,
    const float* __restrict__ bo, float* __restrict__ out)
{
    __shared__ float As[32 * 132];
    __shared__ float Ws[128 * 68];
    int r0 = blockIdx.x * 32, c0 = blockIdx.y * 64;
    int t = threadIdx.x;
    int tx = t & 15, ty = t >> 4;

    float acc[2][4];
    #pragma unroll
    for (int r = 0; r < 2; r++)
        #pragma unroll
        for (int q = 0; q < 4; q++) acc[r][q] = 0.f;

    for (int ch = 0; ch < 6; ch++) {
        int f0 = ch * 128;
        for (int e4 = t; e4 < 32 * 32; e4 += 256) {
            int r = e4 >> 5, fq = e4 & 31;
            float4v v;
            if (f0 + fq * 4 + 3 <= 723)
                v = *(const float4v*)(X + (size_t)(r0 + r) * 724 + f0 + fq * 4);
            else
                v = (float4v){0.f, 0.f, 0.f, 0.f};
            *(float4v*)(&As[r * 132 + fq * 4]) = v;
        }
        for (int e4 = t; e4 < 128 * 16; e4 += 256) {
            int fr = e4 >> 4, cq = e4 & 15;
            int fg = f0 + fr;
            float4v v;
            if (fg < 722)
                v = *(const float4v*)(W + (size_t)fg * 256 + c0 + cq * 4);
            else
                v = (float4v){0.f, 0.f, 0.f, 0.f};
            *(float4v*)(&Ws[fr * 68 + cq * 4]) = v;
        }
        __syncthreads();

        #pragma unroll 4
        for (int k = 0; k < 128; k++) {
            float a0 = As[(ty * 2 + 0) * 132 + k];
            float a1 = As[(ty * 2 + 1) * 132 + k];
            float4v w = *(const float4v*)(&Ws[k * 68 + tx * 4]);
            #pragma unroll
            for (int q = 0; q < 4; q++) {
                acc[0][q] += a0 * w[q];
                acc[1][q] += a1 * w[q];
            }
        }
        __syncthreads();
    }

    #pragma unroll
    for (int r = 0; r < 2; r++) {
        int row = r0 + ty * 2 + r;
        #pragma unroll
        for (int q = 0; q < 4; q++) {
            int c = c0 + tx * 4 + q;
            float v = acc[r][q] + bo[c];
            out[(size_t)row * 256 + c] = v > 0.f ? v : 0.f;
        }
    }
}

// ---------------------------------------------------------------------------
extern "C" void kernel_launch(void* const* d_in, const int* in_sizes, int n_in,
                              void* d_out, int out_size, void* d_ws, size_t ws_size,
                              hipStream_t stream)
{
    const float* atom_input = (const float*)d_in[0];
    const float* path_input = (const float*)d_in[1];
    const float* path_mask  = (const float*)d_in[2];
    const float* W_atom_i   = (const float*)d_in[3];
    const float* W_attn_h   = (const float*)d_in[4];
    const float* b_attn_h   = (const float*)d_in[5];
    const float* W_attn_o   = (const float*)d_in[6];
    const float* b_attn_o   = (const float*)d_in[7];
    const float* W_msg_h    = (const float*)d_in[8];
    const float* b_msg_h    = (const float*)d_in[9];
    const float* W_atom_o   = (const float*)d_in[10];
    const float* b_atom_o   = (const float*)d_in[11];
    float* out = (float*)d_out;

    // workspace carve-up (~71 MB)
    char* ws = (char*)d_ws;
    float* ah0   = (float*)ws;  ws += (size_t)16384 * 80 * 4;    // 5.25 MB
    float* ah1   = (float*)ws;  ws += (size_t)16384 * 80 * 4;    // 5.25 MB
    float* UVAM  = (float*)ws;  ws += (size_t)16384 * 240 * 4;   // 15.7 MB
    bf16*  PT    = (bf16*)ws;   ws += (size_t)2048 * 5120 * 2;   // 21 MB
    bf16*  PM3   = (bf16*)ws;   ws += (size_t)131072 * 80 * 2;   // 21 MB
    bf16*  VT    = (bf16*)ws;   ws += (size_t)256 * 5120 * 2;    // 2.6 MB
    bf16*  WTg   = (bf16*)ws;   ws += (size_t)2 * 80 * 128 * 2;  // 40 KB
    float* Wuvam = (float*)ws;  ws += (size_t)4 * 80 * 80 * 4;
    float* buvam = (float*)ws;  ws += (size_t)4 * 80 * 4;
    float* X = UVAM;   // 2048*724*4 = 5.9 MB, aliases UVAM (dead by then)

    prep_kernel<<<100, 256, 0, stream>>>(W_attn_h, b_attn_h, W_msg_h,
                                         WTg, Wuvam, buvam);

    atom_proj_kernel<<<dim3(32, 8), 256, 0, stream>>>(atom_input, W_atom_i, ah0);

    path_gemm_mfma<<<2048, 256, 0, stream>>>(path_input, WTg, PT, PM3);

    const float* cur = ah0;
    float* nxt[2] = { ah1, ah1 };   // layer2 may reuse ah1 (attn reads ah0/UVAM only)
    for (int layer = 0; layer < 2; layer++) {
        uvam_gemm_kernel<<<dim3(256, 4), 256, 0, stream>>>(
            cur, Wuvam, buvam, UVAM, VT);

        attn_layer_kernel<<<1024, 256, 0, stream>>>(
            UVAM, VT, PT, PM3, path_mask, W_attn_o, b_attn_o, b_msg_h,
            ah0, nxt[layer]);
        cur = nxt[layer];
    }

    merge_kernel<<<256, 256, 0, stream>>>(atom_input, cur, X);
    out_gemm_kernel<<<dim3(64, 4), 256, 0, stream>>>(X, W_atom_o, b_atom_o, out);
}

// Round 9
// 407.251 us; speedup vs baseline: 2.1172x; 1.2054x over previous
//
#include <hip/hip_runtime.h>
#include <hip/hip_bf16.h>

typedef __hip_bfloat16 bf16;
typedef float  float4v __attribute__((ext_vector_type(4)));
typedef unsigned uint4v __attribute__((ext_vector_type(4)));
typedef short  short8 __attribute__((ext_vector_type(8)));
typedef float  f32x4  __attribute__((ext_vector_type(4)));

// B=32, N=64, F_ATOM=82, F_PATH=102, H=8, DK=80, HIDDEN=256, DEPTH=3
// Inputs fp32, output fp32. hb = h*32 + b.

__device__ inline float bflo(unsigned w) { return __uint_as_float(w << 16); }
__device__ inline float bfhi(unsigned w) { return __uint_as_float(w & 0xFFFF0000u); }
__device__ inline unsigned pack2bf(float x, float y) {
    bf16 a = (bf16)x, c = (bf16)y;
    unsigned short ua = *(unsigned short*)&a, uc = *(unsigned short*)&c;
    return (unsigned)ua | ((unsigned)uc << 16);
}

// ---------------------------------------------------------------------------
// Prep: WTg[z][80][128] bf16 (transposed, K-padded); Wuvam fp32; buvam fp32.
// ---------------------------------------------------------------------------
__global__ __launch_bounds__(256) void prep_kernel(
    const float* __restrict__ W_attn_h, const float* __restrict__ b_attn_h,
    const float* __restrict__ W_msg_h,
    bf16* __restrict__ WTg, float* __restrict__ Wuvam, float* __restrict__ buvam)
{
    int t = blockIdx.x * 256 + threadIdx.x;
    if (t < 2 * 80 * 128) {
        int z = t / 10240, rem = t - z * 10240;
        int n = rem >> 7, k = rem & 127;
        const float* src = z ? W_msg_h : W_attn_h;
        float v = (k < 102) ? src[(160 + k) * 80 + n] : 0.f;
        WTg[t] = (bf16)v;
    }
    if (t < 4 * 80 * 80) {
        int z = t / 6400, rc = t - z * 6400;
        const float* src = (z < 2) ? W_attn_h : W_msg_h;
        Wuvam[t] = src[(z & 1) * 6400 + rc];
    }
    if (t < 320) buvam[t] = (t < 80) ? b_attn_h[t] : 0.f;
}

// ---------------------------------------------------------------------------
// Atom projection (unchanged).
// ---------------------------------------------------------------------------
__global__ __launch_bounds__(256) void atom_proj_kernel(
    const float* __restrict__ atom, const float* __restrict__ W,
    float* __restrict__ ah0)
{
    __shared__ float As[64 * 84];
    __shared__ float Ws[82 * 80];
    int rowBase = blockIdx.x * 64;
    int h = blockIdx.y;
    int t = threadIdx.x;

    for (int e = t; e < 64 * 82; e += 256) {
        int r = e / 82, c = e - r * 82;
        As[r * 84 + c] = atom[(size_t)(rowBase + r) * 82 + c];
    }
    for (int e = t; e < 82 * 80; e += 256) {
        int r = e / 80, c = e - r * 80;
        Ws[e] = W[(size_t)r * 640 + h * 80 + c];
    }
    __syncthreads();

    int tx = t & 15, ty = t >> 4;
    float acc[4][5];
    #pragma unroll
    for (int r = 0; r < 4; r++)
        #pragma unroll
        for (int c = 0; c < 5; c++) acc[r][c] = 0.f;

    for (int k = 0; k < 82; k++) {
        float a0 = As[(ty * 4 + 0) * 84 + k];
        float a1 = As[(ty * 4 + 1) * 84 + k];
        float a2 = As[(ty * 4 + 2) * 84 + k];
        float a3 = As[(ty * 4 + 3) * 84 + k];
        float w[5];
        #pragma unroll
        for (int c = 0; c < 5; c++) w[c] = Ws[k * 80 + c * 16 + tx];
        #pragma unroll
        for (int c = 0; c < 5; c++) {
            acc[0][c] += a0 * w[c];
            acc[1][c] += a1 * w[c];
            acc[2][c] += a2 * w[c];
            acc[3][c] += a3 * w[c];
        }
    }

    #pragma unroll
    for (int r = 0; r < 4; r++) {
        int row = rowBase + ty * 4 + r;
        int b = row >> 6, i = row & 63;
        size_t obase = (((size_t)(h * 32 + b)) * 64 + i) * 80;
        #pragma unroll
        for (int c = 0; c < 5; c++)
            ah0[obase + c * 16 + tx] = acc[r][c];
    }
}

// ---------------------------------------------------------------------------
// Path GEMM via MFMA. Both outputs ROW-MAJOR now (no transpose):
//   z=0 -> P2 [(b,i,j)][k] bf16 ; z=1 -> PM3 [(b,i,j)][k] bf16
// ---------------------------------------------------------------------------
__global__ __launch_bounds__(256) void path_gemm_mfma(
    const float* __restrict__ A,      // [131072][102]
    const bf16* __restrict__ WTg,     // [2][80][128]
    bf16* __restrict__ P2, bf16* __restrict__ PM3)
{
    __shared__ bf16 Als[64 * 136];        // epilogue: Cb0[64][80]
    __shared__ bf16 WTs[2 * 80 * 136];    // epilogue: Cb1[64][80]

    int t = threadIdx.x;
    int bx = blockIdx.x;
    size_t abase = (size_t)bx * 64 * 102;

    for (int e = t; e < 8192; e += 256) {
        int r = e >> 7, c = e & 127;
        float v = (c < 102) ? A[abase + (size_t)r * 102 + c] : 0.f;
        Als[r * 136 + c] = (bf16)v;
    }
    {
        const unsigned* src = (const unsigned*)WTg;
        unsigned* dst = (unsigned*)WTs;
        for (int e2 = t; e2 < 10240; e2 += 256) {
            int zr = e2 >> 6, c2 = e2 & 63;
            dst[zr * 68 + c2] = src[e2];
        }
    }
    __syncthreads();

    int wave = t >> 6, lane = t & 63;
    int ln = lane & 15, quad = lane >> 4;

    f32x4 acc[2][5];
    #pragma unroll
    for (int z = 0; z < 2; z++)
        #pragma unroll
        for (int c = 0; c < 5; c++) acc[z][c] = (f32x4){0.f, 0.f, 0.f, 0.f};

    const short* Ap = (const short*)Als + (wave * 16 + ln) * 136;
    const short* Wp = (const short*)WTs;

    #pragma unroll
    for (int kc = 0; kc < 4; kc++) {
        int k0 = kc * 32 + quad * 8;
        short8 af = *(const short8*)(Ap + k0);
        #pragma unroll
        for (int z = 0; z < 2; z++)
            #pragma unroll
            for (int c = 0; c < 5; c++) {
                short8 bfr = *(const short8*)(Wp + (z * 80 + c * 16 + ln) * 136 + k0);
                acc[z][c] = __builtin_amdgcn_mfma_f32_16x16x32_bf16(
                    af, bfr, acc[z][c], 0, 0, 0);
            }
    }
    __syncthreads();

    bf16* Cb0 = Als;
    bf16* Cb1 = WTs;
    #pragma unroll
    for (int c = 0; c < 5; c++) {
        int n = c * 16 + ln;
        #pragma unroll
        for (int r = 0; r < 4; r++) {
            int m = wave * 16 + quad * 4 + r;
            Cb0[m * 80 + n] = (bf16)acc[0][c][r];
            Cb1[m * 80 + n] = (bf16)acc[1][c][r];
        }
    }
    __syncthreads();

    size_t pb = (size_t)bx * 5120;
    for (int e = t; e < 5120; e += 256) {
        P2[pb + e]  = Cb0[e];
        PM3[pb + e] = Cb1[e];
    }
}

// ---------------------------------------------------------------------------
// UVAM GEMM. grid (256, 4). z=0 -> UVAM col 0 (U+b); z=2 -> col 80 (AM1);
// z=3 -> col 160 (AM2); z=1 -> VB[hb][j][k] bf16 ROW-MAJOR (no transpose).
// ---------------------------------------------------------------------------
__global__ __launch_bounds__(256) void uvam_gemm_kernel(
    const float* __restrict__ A, const float* __restrict__ Wuvam,
    const float* __restrict__ buvam,
    float* __restrict__ UVAM, bf16* __restrict__ VB)
{
    __shared__ float As[64 * 105];
    __shared__ float Ws[80 * 80];           // reused as bf16 bounce for z=1
    int z = blockIdx.y;
    const float* W = Wuvam + z * 6400;
    int rowBase = blockIdx.x * 64;
    int t = threadIdx.x;

    for (int e = t; e < 64 * 80; e += 256) {
        int r = e / 80, c = e - r * 80;
        As[r * 105 + c] = A[(size_t)(rowBase + r) * 80 + c];
    }
    for (int e = t; e < 6400; e += 256) Ws[e] = W[e];
    __syncthreads();

    int tx = t & 15, ty = t >> 4;
    float acc[4][5];
    #pragma unroll
    for (int r = 0; r < 4; r++)
        #pragma unroll
        for (int c = 0; c < 5; c++) acc[r][c] = 0.f;

    for (int k = 0; k < 80; k++) {
        float a0 = As[(ty * 4 + 0) * 105 + k];
        float a1 = As[(ty * 4 + 1) * 105 + k];
        float a2 = As[(ty * 4 + 2) * 105 + k];
        float a3 = As[(ty * 4 + 3) * 105 + k];
        float w[5];
        #pragma unroll
        for (int c = 0; c < 5; c++) w[c] = Ws[k * 80 + c * 16 + tx];
        #pragma unroll
        for (int c = 0; c < 5; c++) {
            acc[0][c] += a0 * w[c];
            acc[1][c] += a1 * w[c];
            acc[2][c] += a2 * w[c];
            acc[3][c] += a3 * w[c];
        }
    }

    if (z == 1) {
        __syncthreads();
        bf16* TT = (bf16*)Ws;               // [64][80]
        #pragma unroll
        for (int r = 0; r < 4; r++)
            #pragma unroll
            for (int c = 0; c < 5; c++)
                TT[(ty * 4 + r) * 80 + c * 16 + tx] = (bf16)acc[r][c];
        __syncthreads();
        size_t pb = (size_t)blockIdx.x * 5120;
        for (int e = t; e < 5120; e += 256)
            VB[pb + e] = TT[e];
    } else {
        int col0 = (z == 0) ? 0 : (z == 2 ? 80 : 160);
        float bv[5];
        #pragma unroll
        for (int c = 0; c < 5; c++) bv[c] = buvam[z * 80 + c * 16 + tx];
        #pragma unroll
        for (int r = 0; r < 4; r++) {
            size_t row = rowBase + ty * 4 + r;
            #pragma unroll
            for (int c = 0; c < 5; c++)
                UVAM[row * 240 + col0 + c * 16 + tx] = acc[r][c] + bv[c];
        }
    }
}

// ---------------------------------------------------------------------------
// Fused attention layer v3: grid 2048 (x&255=hb, x>>8=itile of 8 i),
// 4 waves x 2 i. Score: lane=j, P row in registers (10x16B loads), V from
// LDS (odd pitch). Message: lanes 0..39 handle k-pairs via uint loads, both
// i of the wave fused in one j-loop. One barrier total.
// ---------------------------------------------------------------------------
__global__ __launch_bounds__(256, 5) void attn_layer_kernel(
    const float* __restrict__ UVAM,   // [16384][240]: U+b | AM1 | AM2
    const bf16* __restrict__ VB,      // [256][64][80] row-major
    const bf16* __restrict__ P2,      // [131072][80] row-major
    const bf16* __restrict__ PM3,     // [131072][80] row-major
    const float* __restrict__ mask,
    const float* __restrict__ w_attn_o, const float* __restrict__ b_attn_o,
    const float* __restrict__ b_msg_h,
    const float* __restrict__ ah0, float* __restrict__ ah_next)
{
    __shared__ unsigned VBu[64 * 41];   // V rows, bf16 pairs, pitch 41 words
    __shared__ unsigned AMu[64 * 40];   // AM2 rows, bf16 pairs
    __shared__ unsigned Uu[8 * 40];     // U rows (this block's 8 i)
    __shared__ unsigned A1u[8 * 40];    // AM1 rows
    __shared__ float wo[80], bm[80];
    __shared__ float PS[4][2][64];

    int x = blockIdx.x;
    int hb = x & 255, it = x >> 8;
    int b = hb & 31;
    int i0 = it * 8;
    int t = threadIdx.x;
    size_t vbase = (size_t)hb * 64 * 240;

    // ---- staging ----
    {
        const unsigned* src = (const unsigned*)(VB + (size_t)hb * 5120);
        for (int e = t; e < 2560; e += 256) {
            int j = e / 40, w = e - j * 40;
            VBu[j * 41 + w] = src[e];
        }
    }
    for (int e = t; e < 2560; e += 256) {
        int j = e / 40, kp = e - j * 40;
        const float* p = UVAM + vbase + (size_t)j * 240 + 160 + 2 * kp;
        AMu[e] = pack2bf(p[0], p[1]);
    }
    for (int e = t; e < 320; e += 256) {
        int iq = e / 40, kp = e - iq * 40;
        const float* pu = UVAM + vbase + (size_t)(i0 + iq) * 240 + 2 * kp;
        Uu[e]  = pack2bf(pu[0], pu[1]);
        const float* pa = pu + 80;
        A1u[e] = pack2bf(pa[0], pa[1]);
    }
    if (t < 80) { wo[t] = w_attn_o[t]; bm[t] = b_msg_h[t]; }
    __syncthreads();

    int wave = t >> 6, lane = t & 63;
    float b0 = b_attn_o[0];
    int iA = i0 + wave * 2;

    float sp[2];

    #pragma unroll
    for (int q = 0; q < 2; q++) {
        int i = iA + q;
        int iq = wave * 2 + q;

        // ---- score: lane = j, P row in registers ----
        const uint4v* prow = (const uint4v*)(P2 + ((size_t)(b * 64 + i) * 64 + lane) * 80);
        uint4v pr[10];
        #pragma unroll
        for (int u = 0; u < 10; u++) pr[u] = prow[u];
        const unsigned* pu = (const unsigned*)pr;

        float s = 0.f;
        #pragma unroll
        for (int kp = 0; kp < 40; kp++) {
            unsigned pw = pu[kp];
            unsigned vw = VBu[lane * 41 + kp];
            unsigned uw = Uu[iq * 40 + kp];
            float x0 = bflo(uw) + bflo(vw) + bflo(pw);
            x0 = fmaxf(x0, 0.2f * x0);
            s += x0 * wo[2 * kp];
            float x1 = bfhi(uw) + bfhi(vw) + bfhi(pw);
            x1 = fmaxf(x1, 0.2f * x1);
            s += x1 * wo[2 * kp + 1];
        }

        float mj = mask[(size_t)b * 4096 + (size_t)i * 64 + lane];
        float sc = (s + b0) * mj;
        float m = sc;
        #pragma unroll
        for (int off = 1; off < 64; off <<= 1) m = fmaxf(m, __shfl_xor(m, off, 64));
        float e = expf(sc - m) * mj;
        float d = e;
        #pragma unroll
        for (int off = 1; off < 64; off <<= 1) d += __shfl_xor(d, off, 64);
        float p = e / (d + 1e-20f) * mj;
        PS[wave][q][lane] = p;
        float spv = p;
        #pragma unroll
        for (int off = 1; off < 64; off <<= 1) spv += __shfl_xor(spv, off, 64);
        sp[q] = spv;
    }

    // ---- message: lanes 0..39, k-pairs, both i fused ----
    if (lane < 40) {
        const unsigned* pm0 = (const unsigned*)(PM3 + ((size_t)(b * 64 + iA) * 64) * 80);
        const unsigned* pm1 = pm0 + 2560;   // next i
        float a00 = 0.f, a01 = 0.f, a10 = 0.f, a11 = 0.f;
        #pragma unroll 4
        for (int j = 0; j < 64; j++) {
            unsigned u0 = pm0[j * 40 + lane];
            unsigned u1 = pm1[j * 40 + lane];
            unsigned aw = AMu[j * 40 + lane];
            float am0 = bflo(aw), am1 = bfhi(aw);
            float p0 = PS[wave][0][j];
            float p1 = PS[wave][1][j];
            a00 += p0 * (bflo(u0) + am0);
            a01 += p0 * (bfhi(u0) + am1);
            a10 += p1 * (bflo(u1) + am0);
            a11 += p1 * (bfhi(u1) + am1);
        }

        int k0 = 2 * lane, k1 = 2 * lane + 1;
        #pragma unroll
        for (int q = 0; q < 2; q++) {
            int i = iA + q;
            int iq = wave * 2 + q;
            unsigned aw1 = A1u[iq * 40 + lane];
            size_t orow = ((size_t)hb * 64 + i) * 80;
            float mlo = (q == 0) ? a00 : a10;
            float mhi = (q == 0) ? a01 : a11;
            float pre0 = sp[q] * bflo(aw1) + mlo + bm[k0] + ah0[orow + k0];
            float pre1 = sp[q] * bfhi(aw1) + mhi + bm[k1] + ah0[orow + k1];
            ah_next[orow + k0] = pre0 > 0.f ? pre0 : 0.f;
            ah_next[orow + k1] = pre1 > 0.f ? pre1 : 0.f;
        }
    }
}

// ---------------------------------------------------------------------------
// Merge: X[row][f] = concat(atom[row,:82], ah_merged[row,:640]); ld=724.
// ---------------------------------------------------------------------------
__global__ __launch_bounds__(256) void merge_kernel(
    const float* __restrict__ atom, const float* __restrict__ ah,
    float* __restrict__ X)
{
    int r0 = blockIdx.x * 8;
    int t = threadIdx.x;
    for (int e = t; e < 8 * 724; e += 256) {
        int r = e / 724, f = e - r * 724;
        int row = r0 + r;
        float v;
        if (f < 82) {
            v = atom[(size_t)row * 82 + f];
        } else if (f < 722) {
            int q = f - 82, h = q / 80, k = q - h * 80;
            int b = row >> 6, i = row & 63;
            v = ah[(((size_t)(h * 32 + b)) * 64 + i) * 80 + k];
        } else {
            v = 0.f;
        }
        X[(size_t)row * 724 + f] = v;
    }
}

// ---------------------------------------------------------------------------
// Out GEMM: out[row,c] = relu(X[row,:722] @ W[:,c] + b[c])
// ---------------------------------------------------------------------------
__global__ __launch_bounds__(256) void out_gemm_kernel(
    const float* __restrict__ X, const float* __restrict__ W,
    const float* __restrict__ bo, float* __restrict__ out)
{
    __shared__ float As[32 * 132];
    __shared__ float Ws[128 * 68];
    int r0 = blockIdx.x * 32, c0 = blockIdx.y * 64;
    int t = threadIdx.x;
    int tx = t & 15, ty = t >> 4;

    float acc[2][4];
    #pragma unroll
    for (int r = 0; r < 2; r++)
        #pragma unroll
        for (int q = 0; q < 4; q++) acc[r][q] = 0.f;

    for (int ch = 0; ch < 6; ch++) {
        int f0 = ch * 128;
        for (int e4 = t; e4 < 32 * 32; e4 += 256) {
            int r = e4 >> 5, fq = e4 & 31;
            float4v v;
            if (f0 + fq * 4 + 3 <= 723)
                v = *(const float4v*)(X + (size_t)(r0 + r) * 724 + f0 + fq * 4);
            else
                v = (float4v){0.f, 0.f, 0.f, 0.f};
            *(float4v*)(&As[r * 132 + fq * 4]) = v;
        }
        for (int e4 = t; e4 < 128 * 16; e4 += 256) {
            int fr = e4 >> 4, cq = e4 & 15;
            int fg = f0 + fr;
            float4v v;
            if (fg < 722)
                v = *(const float4v*)(W + (size_t)fg * 256 + c0 + cq * 4);
            else
                v = (float4v){0.f, 0.f, 0.f, 0.f};
            *(float4v*)(&Ws[fr * 68 + cq * 4]) = v;
        }
        __syncthreads();

        #pragma unroll 4
        for (int k = 0; k < 128; k++) {
            float a0 = As[(ty * 2 + 0) * 132 + k];
            float a1 = As[(ty * 2 + 1) * 132 + k];
            float4v w = *(const float4v*)(&Ws[k * 68 + tx * 4]);
            #pragma unroll
            for (int q = 0; q < 4; q++) {
                acc[0][q] += a0 * w[q];
                acc[1][q] += a1 * w[q];
            }
        }
        __syncthreads();
    }

    #pragma unroll
    for (int r = 0; r < 2; r++) {
        int row = r0 + ty * 2 + r;
        #pragma unroll
        for (int q = 0; q < 4; q++) {
            int c = c0 + tx * 4 + q;
            float v = acc[r][q] + bo[c];
            out[(size_t)row * 256 + c] = v > 0.f ? v : 0.f;
        }
    }
}

// ---------------------------------------------------------------------------
extern "C" void kernel_launch(void* const* d_in, const int* in_sizes, int n_in,
                              void* d_out, int out_size, void* d_ws, size_t ws_size,
                              hipStream_t stream)
{
    const float* atom_input = (const float*)d_in[0];
    const float* path_input = (const float*)d_in[1];
    const float* path_mask  = (const float*)d_in[2];
    const float* W_atom_i   = (const float*)d_in[3];
    const float* W_attn_h   = (const float*)d_in[4];
    const float* b_attn_h   = (const float*)d_in[5];
    const float* W_attn_o   = (const float*)d_in[6];
    const float* b_attn_o   = (const float*)d_in[7];
    const float* W_msg_h    = (const float*)d_in[8];
    const float* b_msg_h    = (const float*)d_in[9];
    const float* W_atom_o   = (const float*)d_in[10];
    const float* b_atom_o   = (const float*)d_in[11];
    float* out = (float*)d_out;

    // workspace carve-up (~71 MB)
    char* ws = (char*)d_ws;
    float* ah0   = (float*)ws;  ws += (size_t)16384 * 80 * 4;    // 5.25 MB
    float* ah1   = (float*)ws;  ws += (size_t)16384 * 80 * 4;    // 5.25 MB
    float* UVAM  = (float*)ws;  ws += (size_t)16384 * 240 * 4;   // 15.7 MB
    bf16*  P2    = (bf16*)ws;   ws += (size_t)131072 * 80 * 2;   // 21 MB
    bf16*  PM3   = (bf16*)ws;   ws += (size_t)131072 * 80 * 2;   // 21 MB
    bf16*  VB    = (bf16*)ws;   ws += (size_t)256 * 5120 * 2;    // 2.6 MB
    bf16*  WTg   = (bf16*)ws;   ws += (size_t)2 * 80 * 128 * 2;  // 40 KB
    float* Wuvam = (float*)ws;  ws += (size_t)4 * 80 * 80 * 4;
    float* buvam = (float*)ws;  ws += (size_t)4 * 80 * 4;
    float* X = UVAM;   // 2048*724*4 = 5.9 MB, aliases UVAM (dead by then)

    prep_kernel<<<100, 256, 0, stream>>>(W_attn_h, b_attn_h, W_msg_h,
                                         WTg, Wuvam, buvam);

    atom_proj_kernel<<<dim3(32, 8), 256, 0, stream>>>(atom_input, W_atom_i, ah0);

    path_gemm_mfma<<<2048, 256, 0, stream>>>(path_input, WTg, P2, PM3);

    const float* cur = ah0;
    float* nxt[2] = { ah1, ah1 };
    for (int layer = 0; layer < 2; layer++) {
        uvam_gemm_kernel<<<dim3(256, 4), 256, 0, stream>>>(
            cur, Wuvam, buvam, UVAM, VB);

        attn_layer_kernel<<<2048, 256, 0, stream>>>(
            UVAM, VB, P2, PM3, path_mask, W_attn_o, b_attn_o, b_msg_h,
            ah0, nxt[layer]);
        cur = nxt[layer];
    }

    merge_kernel<<<256, 256, 0, stream>>>(atom_input, cur, X);
    out_gemm_kernel<<<dim3(64, 4), 256, 0, stream>>>(X, W_atom_o, b_atom_o, out);
}

// Round 10
// 366.452 us; speedup vs baseline: 2.3529x; 1.1113x over previous
//
#include <hip/hip_runtime.h>
#include <hip/hip_bf16.h>

typedef __hip_bfloat16 bf16;
typedef float  float4v __attribute__((ext_vector_type(4)));
typedef unsigned uint4v __attribute__((ext_vector_type(4)));
typedef short  short8 __attribute__((ext_vector_type(8)));
typedef float  f32x4  __attribute__((ext_vector_type(4)));

// B=32, N=64, F_ATOM=82, F_PATH=102, H=8, DK=80, HIDDEN=256, DEPTH=3
// Inputs fp32, output fp32. hb = h*32 + b.

__device__ inline float bflo(unsigned w) { return __uint_as_float(w << 16); }
__device__ inline float bfhi(unsigned w) { return __uint_as_float(w & 0xFFFF0000u); }
__device__ inline unsigned pack2bf(float x, float y) {
    bf16 a = (bf16)x, c = (bf16)y;
    unsigned short ua = *(unsigned short*)&a, uc = *(unsigned short*)&c;
    return (unsigned)ua | ((unsigned)uc << 16);
}

// ---------------------------------------------------------------------------
// Prep: WTg[z][80][128] bf16 (transposed, K-padded); Wuvam fp32; buvam fp32.
// ---------------------------------------------------------------------------
__global__ __launch_bounds__(256) void prep_kernel(
    const float* __restrict__ W_attn_h, const float* __restrict__ b_attn_h,
    const float* __restrict__ W_msg_h,
    bf16* __restrict__ WTg, float* __restrict__ Wuvam, float* __restrict__ buvam)
{
    int t = blockIdx.x * 256 + threadIdx.x;
    if (t < 2 * 80 * 128) {
        int z = t / 10240, rem = t - z * 10240;
        int n = rem >> 7, k = rem & 127;
        const float* src = z ? W_msg_h : W_attn_h;
        float v = (k < 102) ? src[(160 + k) * 80 + n] : 0.f;
        WTg[t] = (bf16)v;
    }
    if (t < 4 * 80 * 80) {
        int z = t / 6400, rc = t - z * 6400;
        const float* src = (z < 2) ? W_attn_h : W_msg_h;
        Wuvam[t] = src[(z & 1) * 6400 + rc];
    }
    if (t < 320) buvam[t] = (t < 80) ? b_attn_h[t] : 0.f;
}

// ---------------------------------------------------------------------------
// Atom projection (unchanged).
// ---------------------------------------------------------------------------
__global__ __launch_bounds__(256) void atom_proj_kernel(
    const float* __restrict__ atom, const float* __restrict__ W,
    float* __restrict__ ah0)
{
    __shared__ float As[64 * 84];
    __shared__ float Ws[82 * 80];
    int rowBase = blockIdx.x * 64;
    int h = blockIdx.y;
    int t = threadIdx.x;

    for (int e = t; e < 64 * 82; e += 256) {
        int r = e / 82, c = e - r * 82;
        As[r * 84 + c] = atom[(size_t)(rowBase + r) * 82 + c];
    }
    for (int e = t; e < 82 * 80; e += 256) {
        int r = e / 80, c = e - r * 80;
        Ws[e] = W[(size_t)r * 640 + h * 80 + c];
    }
    __syncthreads();

    int tx = t & 15, ty = t >> 4;
    float acc[4][5];
    #pragma unroll
    for (int r = 0; r < 4; r++)
        #pragma unroll
        for (int c = 0; c < 5; c++) acc[r][c] = 0.f;

    for (int k = 0; k < 82; k++) {
        float a0 = As[(ty * 4 + 0) * 84 + k];
        float a1 = As[(ty * 4 + 1) * 84 + k];
        float a2 = As[(ty * 4 + 2) * 84 + k];
        float a3 = As[(ty * 4 + 3) * 84 + k];
        float w[5];
        #pragma unroll
        for (int c = 0; c < 5; c++) w[c] = Ws[k * 80 + c * 16 + tx];
        #pragma unroll
        for (int c = 0; c < 5; c++) {
            acc[0][c] += a0 * w[c];
            acc[1][c] += a1 * w[c];
            acc[2][c] += a2 * w[c];
            acc[3][c] += a3 * w[c];
        }
    }

    #pragma unroll
    for (int r = 0; r < 4; r++) {
        int row = rowBase + ty * 4 + r;
        int b = row >> 6, i = row & 63;
        size_t obase = (((size_t)(h * 32 + b)) * 64 + i) * 80;
        #pragma unroll
        for (int c = 0; c < 5; c++)
            ah0[obase + c * 16 + tx] = acc[r][c];
    }
}

// ---------------------------------------------------------------------------
// Path GEMM via MFMA v2: 2048 blocks x 320 threads (5 waves).
// Wave w owns column-group w (n = w*16+ln), both z; B-frags in VGPRs loaded
// straight from L2-hot WTg (no weight LDS). LDS holds only A (64x136 bf16,
// k>=102 zeroed). One barrier; direct global stores.
//   z=0 -> P2 [(b,i,j)][k] ; z=1 -> PM3 [(b,i,j)][k]
// ---------------------------------------------------------------------------
__global__ __launch_bounds__(320) void path_gemm_mfma(
    const float* __restrict__ A,      // [131072][102]
    const bf16* __restrict__ WTg,     // [2][80][128]
    bf16* __restrict__ P2, bf16* __restrict__ PM3)
{
    __shared__ bf16 Als[64 * 136];    // 17.4 KB

    int t = threadIdx.x;
    int bx = blockIdx.x;
    size_t abase = (size_t)bx * 6528;     // flat dword index into A

    int wave = t >> 6, lane = t & 63;
    int ln = lane & 15, quad = lane >> 4;

    // B-fragments in registers (L2-hot; independent of LDS staging)
    const short* Wp = (const short*)WTg;
    short8 bfrag[2][4];
    #pragma unroll
    for (int z = 0; z < 2; z++)
        #pragma unroll
        for (int kc = 0; kc < 4; kc++)
            bfrag[z][kc] = *(const short8*)(
                Wp + (size_t)(z * 80 + wave * 16 + ln) * 128 + kc * 32 + quad * 8);

    // stage A (fp32 -> bf16), zero-fill k in [102,136)
    for (int e = t; e < 6528; e += 320) {
        int r = e / 102, c = e - r * 102;
        Als[r * 136 + c] = (bf16)A[abase + e];
    }
    for (int e = t; e < 2176; e += 320) {
        int r = e / 34, c = 102 + (e - r * 34);
        Als[r * 136 + c] = (bf16)0.f;
    }
    __syncthreads();

    const short* Ap = (const short*)Als;
    int nc = wave * 16 + ln;              // output column

    #pragma unroll
    for (int rt = 0; rt < 4; rt++) {
        f32x4 acc0 = (f32x4){0.f, 0.f, 0.f, 0.f};
        f32x4 acc1 = (f32x4){0.f, 0.f, 0.f, 0.f};
        #pragma unroll
        for (int kc = 0; kc < 4; kc++) {
            short8 af = *(const short8*)(
                Ap + (rt * 16 + ln) * 136 + kc * 32 + quad * 8);
            acc0 = __builtin_amdgcn_mfma_f32_16x16x32_bf16(af, bfrag[0][kc], acc0, 0, 0, 0);
            acc1 = __builtin_amdgcn_mfma_f32_16x16x32_bf16(af, bfrag[1][kc], acc1, 0, 0, 0);
        }
        #pragma unroll
        for (int r = 0; r < 4; r++) {
            int m = rt * 16 + quad * 4 + r;
            size_t row = (size_t)bx * 64 + m;
            P2[row * 80 + nc]  = (bf16)acc0[r];
            PM3[row * 80 + nc] = (bf16)acc1[r];
        }
    }
}

// ---------------------------------------------------------------------------
// UVAM GEMM. grid (256, 4). z=0 -> UVAM col 0 (U+b); z=2 -> col 80 (AM1);
// z=3 -> col 160 (AM2); z=1 -> VB[hb][j][k] bf16 ROW-MAJOR.
// ---------------------------------------------------------------------------
__global__ __launch_bounds__(256) void uvam_gemm_kernel(
    const float* __restrict__ A, const float* __restrict__ Wuvam,
    const float* __restrict__ buvam,
    float* __restrict__ UVAM, bf16* __restrict__ VB)
{
    __shared__ float As[64 * 105];
    __shared__ float Ws[80 * 80];           // reused as bf16 bounce for z=1
    int z = blockIdx.y;
    const float* W = Wuvam + z * 6400;
    int rowBase = blockIdx.x * 64;
    int t = threadIdx.x;

    for (int e = t; e < 64 * 80; e += 256) {
        int r = e / 80, c = e - r * 80;
        As[r * 105 + c] = A[(size_t)(rowBase + r) * 80 + c];
    }
    for (int e = t; e < 6400; e += 256) Ws[e] = W[e];
    __syncthreads();

    int tx = t & 15, ty = t >> 4;
    float acc[4][5];
    #pragma unroll
    for (int r = 0; r < 4; r++)
        #pragma unroll
        for (int c = 0; c < 5; c++) acc[r][c] = 0.f;

    for (int k = 0; k < 80; k++) {
        float a0 = As[(ty * 4 + 0) * 105 + k];
        float a1 = As[(ty * 4 + 1) * 105 + k];
        float a2 = As[(ty * 4 + 2) * 105 + k];
        float a3 = As[(ty * 4 + 3) * 105 + k];
        float w[5];
        #pragma unroll
        for (int c = 0; c < 5; c++) w[c] = Ws[k * 80 + c * 16 + tx];
        #pragma unroll
        for (int c = 0; c < 5; c++) {
            acc[0][c] += a0 * w[c];
            acc[1][c] += a1 * w[c];
            acc[2][c] += a2 * w[c];
            acc[3][c] += a3 * w[c];
        }
    }

    if (z == 1) {
        __syncthreads();
        bf16* TT = (bf16*)Ws;               // [64][80]
        #pragma unroll
        for (int r = 0; r < 4; r++)
            #pragma unroll
            for (int c = 0; c < 5; c++)
                TT[(ty * 4 + r) * 80 + c * 16 + tx] = (bf16)acc[r][c];
        __syncthreads();
        size_t pb = (size_t)blockIdx.x * 5120;
        for (int e = t; e < 5120; e += 256)
            VB[pb + e] = TT[e];
    } else {
        int col0 = (z == 0) ? 0 : (z == 2 ? 80 : 160);
        float bv[5];
        #pragma unroll
        for (int c = 0; c < 5; c++) bv[c] = buvam[z * 80 + c * 16 + tx];
        #pragma unroll
        for (int r = 0; r < 4; r++) {
            size_t row = rowBase + ty * 4 + r;
            #pragma unroll
            for (int c = 0; c < 5; c++)
                UVAM[row * 240 + col0 + c * 16 + tx] = acc[r][c] + bv[c];
        }
    }
}

// ---------------------------------------------------------------------------
// Fused attention layer v3 (unchanged from R8).
// ---------------------------------------------------------------------------
__global__ __launch_bounds__(256, 5) void attn_layer_kernel(
    const float* __restrict__ UVAM,   // [16384][240]: U+b | AM1 | AM2
    const bf16* __restrict__ VB,      // [256][64][80] row-major
    const bf16* __restrict__ P2,      // [131072][80] row-major
    const bf16* __restrict__ PM3,     // [131072][80] row-major
    const float* __restrict__ mask,
    const float* __restrict__ w_attn_o, const float* __restrict__ b_attn_o,
    const float* __restrict__ b_msg_h,
    const float* __restrict__ ah0, float* __restrict__ ah_next)
{
    __shared__ unsigned VBu[64 * 41];
    __shared__ unsigned AMu[64 * 40];
    __shared__ unsigned Uu[8 * 40];
    __shared__ unsigned A1u[8 * 40];
    __shared__ float wo[80], bm[80];
    __shared__ float PS[4][2][64];

    int x = blockIdx.x;
    int hb = x & 255, it = x >> 8;
    int b = hb & 31;
    int i0 = it * 8;
    int t = threadIdx.x;
    size_t vbase = (size_t)hb * 64 * 240;

    {
        const unsigned* src = (const unsigned*)(VB + (size_t)hb * 5120);
        for (int e = t; e < 2560; e += 256) {
            int j = e / 40, w = e - j * 40;
            VBu[j * 41 + w] = src[e];
        }
    }
    for (int e = t; e < 2560; e += 256) {
        int j = e / 40, kp = e - j * 40;
        const float* p = UVAM + vbase + (size_t)j * 240 + 160 + 2 * kp;
        AMu[e] = pack2bf(p[0], p[1]);
    }
    for (int e = t; e < 320; e += 256) {
        int iq = e / 40, kp = e - iq * 40;
        const float* pu = UVAM + vbase + (size_t)(i0 + iq) * 240 + 2 * kp;
        Uu[e]  = pack2bf(pu[0], pu[1]);
        const float* pa = pu + 80;
        A1u[e] = pack2bf(pa[0], pa[1]);
    }
    if (t < 80) { wo[t] = w_attn_o[t]; bm[t] = b_msg_h[t]; }
    __syncthreads();

    int wave = t >> 6, lane = t & 63;
    float b0 = b_attn_o[0];
    int iA = i0 + wave * 2;

    float sp[2];

    #pragma unroll
    for (int q = 0; q < 2; q++) {
        int i = iA + q;
        int iq = wave * 2 + q;

        const uint4v* prow = (const uint4v*)(P2 + ((size_t)(b * 64 + i) * 64 + lane) * 80);
        uint4v pr[10];
        #pragma unroll
        for (int u = 0; u < 10; u++) pr[u] = prow[u];
        const unsigned* pu = (const unsigned*)pr;

        float s = 0.f;
        #pragma unroll
        for (int kp = 0; kp < 40; kp++) {
            unsigned pw = pu[kp];
            unsigned vw = VBu[lane * 41 + kp];
            unsigned uw = Uu[iq * 40 + kp];
            float x0 = bflo(uw) + bflo(vw) + bflo(pw);
            x0 = fmaxf(x0, 0.2f * x0);
            s += x0 * wo[2 * kp];
            float x1 = bfhi(uw) + bfhi(vw) + bfhi(pw);
            x1 = fmaxf(x1, 0.2f * x1);
            s += x1 * wo[2 * kp + 1];
        }

        float mj = mask[(size_t)b * 4096 + (size_t)i * 64 + lane];
        float sc = (s + b0) * mj;
        float m = sc;
        #pragma unroll
        for (int off = 1; off < 64; off <<= 1) m = fmaxf(m, __shfl_xor(m, off, 64));
        float e = expf(sc - m) * mj;
        float d = e;
        #pragma unroll
        for (int off = 1; off < 64; off <<= 1) d += __shfl_xor(d, off, 64);
        float p = e / (d + 1e-20f) * mj;
        PS[wave][q][lane] = p;
        float spv = p;
        #pragma unroll
        for (int off = 1; off < 64; off <<= 1) spv += __shfl_xor(spv, off, 64);
        sp[q] = spv;
    }

    if (lane < 40) {
        const unsigned* pm0 = (const unsigned*)(PM3 + ((size_t)(b * 64 + iA) * 64) * 80);
        const unsigned* pm1 = pm0 + 2560;
        float a00 = 0.f, a01 = 0.f, a10 = 0.f, a11 = 0.f;
        #pragma unroll 4
        for (int j = 0; j < 64; j++) {
            unsigned u0 = pm0[j * 40 + lane];
            unsigned u1 = pm1[j * 40 + lane];
            unsigned aw = AMu[j * 40 + lane];
            float am0 = bflo(aw), am1 = bfhi(aw);
            float p0 = PS[wave][0][j];
            float p1 = PS[wave][1][j];
            a00 += p0 * (bflo(u0) + am0);
            a01 += p0 * (bfhi(u0) + am1);
            a10 += p1 * (bflo(u1) + am0);
            a11 += p1 * (bfhi(u1) + am1);
        }

        int k0 = 2 * lane, k1 = 2 * lane + 1;
        #pragma unroll
        for (int q = 0; q < 2; q++) {
            int i = iA + q;
            int iq = wave * 2 + q;
            unsigned aw1 = A1u[iq * 40 + lane];
            size_t orow = ((size_t)hb * 64 + i) * 80;
            float mlo = (q == 0) ? a00 : a10;
            float mhi = (q == 0) ? a01 : a11;
            float pre0 = sp[q] * bflo(aw1) + mlo + bm[k0] + ah0[orow + k0];
            float pre1 = sp[q] * bfhi(aw1) + mhi + bm[k1] + ah0[orow + k1];
            ah_next[orow + k0] = pre0 > 0.f ? pre0 : 0.f;
            ah_next[orow + k1] = pre1 > 0.f ? pre1 : 0.f;
        }
    }
}

// ---------------------------------------------------------------------------
// Merge: X[row][f] = concat(atom[row,:82], ah_merged[row,:640]); ld=724.
// ---------------------------------------------------------------------------
__global__ __launch_bounds__(256) void merge_kernel(
    const float* __restrict__ atom, const float* __restrict__ ah,
    float* __restrict__ X)
{
    int r0 = blockIdx.x * 8;
    int t = threadIdx.x;
    for (int e = t; e < 8 * 724; e += 256) {
        int r = e / 724, f = e - r * 724;
        int row = r0 + r;
        float v;
        if (f < 82) {
            v = atom[(size_t)row * 82 + f];
        } else if (f < 722) {
            int q = f - 82, h = q / 80, k = q - h * 80;
            int b = row >> 6, i = row & 63;
            v = ah[(((size_t)(h * 32 + b)) * 64 + i) * 80 + k];
        } else {
            v = 0.f;
        }
        X[(size_t)row * 724 + f] = v;
    }
}

// ---------------------------------------------------------------------------
// Out GEMM: out[row,c] = relu(X[row,:722] @ W[:,c] + b[c])
// ---------------------------------------------------------------------------
__global__ __launch_bounds__(256) void out_gemm_kernel(
    const float* __restrict__ X, const float* __restrict__ W,
    const float* __restrict__ bo, float* __restrict__ out)
{
    __shared__ float As[32 * 132];
    __shared__ float Ws[128 * 68];
    int r0 = blockIdx.x * 32, c0 = blockIdx.y * 64;
    int t = threadIdx.x;
    int tx = t & 15, ty = t >> 4;

    float acc[2][4];
    #pragma unroll
    for (int r = 0; r < 2; r++)
        #pragma unroll
        for (int q = 0; q < 4; q++) acc[r][q] = 0.f;

    for (int ch = 0; ch < 6; ch++) {
        int f0 = ch * 128;
        for (int e4 = t; e4 < 32 * 32; e4 += 256) {
            int r = e4 >> 5, fq = e4 & 31;
            float4v v;
            if (f0 + fq * 4 + 3 <= 723)
                v = *(const float4v*)(X + (size_t)(r0 + r) * 724 + f0 + fq * 4);
            else
                v = (float4v){0.f, 0.f, 0.f, 0.f};
            *(float4v*)(&As[r * 132 + fq * 4]) = v;
        }
        for (int e4 = t; e4 < 128 * 16; e4 += 256) {
            int fr = e4 >> 4, cq = e4 & 15;
            int fg = f0 + fr;
            float4v v;
            if (fg < 722)
                v = *(const float4v*)(W + (size_t)fg * 256 + c0 + cq * 4);
            else
                v = (float4v){0.f, 0.f, 0.f, 0.f};
            *(float4v*)(&Ws[fr * 68 + cq * 4]) = v;
        }
        __syncthreads();

        #pragma unroll 4
        for (int k = 0; k < 128; k++) {
            float a0 = As[(ty * 2 + 0) * 132 + k];
            float a1 = As[(ty * 2 + 1) * 132 + k];
            float4v w = *(const float4v*)(&Ws[k * 68 + tx * 4]);
            #pragma unroll
            for (int q = 0; q < 4; q++) {
                acc[0][q] += a0 * w[q];
                acc[1][q] += a1 * w[q];
            }
        }
        __syncthreads();
    }

    #pragma unroll
    for (int r = 0; r < 2; r++) {
        int row = r0 + ty * 2 + r;
        #pragma unroll
        for (int q = 0; q < 4; q++) {
            int c = c0 + tx * 4 + q;
            float v = acc[r][q] + bo[c];
            out[(size_t)row * 256 + c] = v > 0.f ? v : 0.f;
        }
    }
}

// ---------------------------------------------------------------------------
extern "C" void kernel_launch(void* const* d_in, const int* in_sizes, int n_in,
                              void* d_out, int out_size, void* d_ws, size_t ws_size,
                              hipStream_t stream)
{
    const float* atom_input = (const float*)d_in[0];
    const float* path_input = (const float*)d_in[1];
    const float* path_mask  = (const float*)d_in[2];
    const float* W_atom_i   = (const float*)d_in[3];
    const float* W_attn_h   = (const float*)d_in[4];
    const float* b_attn_h   = (const float*)d_in[5];
    const float* W_attn_o   = (const float*)d_in[6];
    const float* b_attn_o   = (const float*)d_in[7];
    const float* W_msg_h    = (const float*)d_in[8];
    const float* b_msg_h    = (const float*)d_in[9];
    const float* W_atom_o   = (const float*)d_in[10];
    const float* b_atom_o   = (const float*)d_in[11];
    float* out = (float*)d_out;

    // workspace carve-up (~71 MB)
    char* ws = (char*)d_ws;
    float* ah0   = (float*)ws;  ws += (size_t)16384 * 80 * 4;    // 5.25 MB
    float* ah1   = (float*)ws;  ws += (size_t)16384 * 80 * 4;    // 5.25 MB
    float* UVAM  = (float*)ws;  ws += (size_t)16384 * 240 * 4;   // 15.7 MB
    bf16*  P2    = (bf16*)ws;   ws += (size_t)131072 * 80 * 2;   // 21 MB
    bf16*  PM3   = (bf16*)ws;   ws += (size_t)131072 * 80 * 2;   // 21 MB
    bf16*  VB    = (bf16*)ws;   ws += (size_t)256 * 5120 * 2;    // 2.6 MB
    bf16*  WTg   = (bf16*)ws;   ws += (size_t)2 * 80 * 128 * 2;  // 40 KB
    float* Wuvam = (float*)ws;  ws += (size_t)4 * 80 * 80 * 4;
    float* buvam = (float*)ws;  ws += (size_t)4 * 80 * 4;
    float* X = UVAM;   // 2048*724*4 = 5.9 MB, aliases UVAM (dead by then)

    prep_kernel<<<100, 256, 0, stream>>>(W_attn_h, b_attn_h, W_msg_h,
                                         WTg, Wuvam, buvam);

    atom_proj_kernel<<<dim3(32, 8), 256, 0, stream>>>(atom_input, W_atom_i, ah0);

    path_gemm_mfma<<<2048, 320, 0, stream>>>(path_input, WTg, P2, PM3);

    const float* cur = ah0;
    float* nxt[2] = { ah1, ah1 };
    for (int layer = 0; layer < 2; layer++) {
        uvam_gemm_kernel<<<dim3(256, 4), 256, 0, stream>>>(
            cur, Wuvam, buvam, UVAM, VB);

        attn_layer_kernel<<<2048, 256, 0, stream>>>(
            UVAM, VB, P2, PM3, path_mask, W_attn_o, b_attn_o, b_msg_h,
            ah0, nxt[layer]);
        cur = nxt[layer];
    }

    merge_kernel<<<256, 256, 0, stream>>>(atom_input, cur, X);
    out_gemm_kernel<<<dim3(64, 4), 256, 0, stream>>>(X, W_atom_o, b_atom_o, out);
}

// Round 11
// 359.053 us; speedup vs baseline: 2.4014x; 1.0206x over previous
//
#include <hip/hip_runtime.h>
#include <hip/hip_bf16.h>

typedef __hip_bfloat16 bf16;
typedef _Float16 half2v __attribute__((ext_vector_type(2)));
typedef float  float4v __attribute__((ext_vector_type(4)));
typedef unsigned uint4v __attribute__((ext_vector_type(4)));
typedef short  short8 __attribute__((ext_vector_type(8)));
typedef float  f32x4  __attribute__((ext_vector_type(4)));

// B=32, N=64, F_ATOM=82, F_PATH=102, H=8, DK=80, HIDDEN=256, DEPTH=3
// Inputs fp32, output fp32. hb = h*32 + b.

__device__ inline float bflo(unsigned w) { return __uint_as_float(w << 16); }
__device__ inline float bfhi(unsigned w) { return __uint_as_float(w & 0xFFFF0000u); }
__device__ inline unsigned pack2bf(float x, float y) {
    bf16 a = (bf16)x, c = (bf16)y;
    unsigned short ua = *(unsigned short*)&a, uc = *(unsigned short*)&c;
    return (unsigned)ua | ((unsigned)uc << 16);
}
__device__ inline unsigned pack2h(float x, float y) {
    _Float16 a = (_Float16)x, c = (_Float16)y;
    unsigned short ua = *(unsigned short*)&a, uc = *(unsigned short*)&c;
    return (unsigned)ua | ((unsigned)uc << 16);
}
__device__ inline half2v ash2(unsigned u) { return __builtin_bit_cast(half2v, u); }
__device__ inline unsigned asu2(half2v h) { return __builtin_bit_cast(unsigned, h); }

__device__ inline float fdot2acc(half2v a, half2v b, float s) {
#if __has_builtin(__builtin_amdgcn_fdot2)
    return __builtin_amdgcn_fdot2(a, b, s, false);
#else
    return s + (float)a.x * (float)b.x + (float)a.y * (float)b.y;
#endif
}

// ---------------------------------------------------------------------------
// Prep: WTg[z][80][128] bf16 (transposed, K-padded); Wuvam fp32; buvam fp32.
// ---------------------------------------------------------------------------
__global__ __launch_bounds__(256) void prep_kernel(
    const float* __restrict__ W_attn_h, const float* __restrict__ b_attn_h,
    const float* __restrict__ W_msg_h,
    bf16* __restrict__ WTg, float* __restrict__ Wuvam, float* __restrict__ buvam)
{
    int t = blockIdx.x * 256 + threadIdx.x;
    if (t < 2 * 80 * 128) {
        int z = t / 10240, rem = t - z * 10240;
        int n = rem >> 7, k = rem & 127;
        const float* src = z ? W_msg_h : W_attn_h;
        float v = (k < 102) ? src[(160 + k) * 80 + n] : 0.f;
        WTg[t] = (bf16)v;
    }
    if (t < 4 * 80 * 80) {
        int z = t / 6400, rc = t - z * 6400;
        const float* src = (z < 2) ? W_attn_h : W_msg_h;
        Wuvam[t] = src[(z & 1) * 6400 + rc];
    }
    if (t < 320) buvam[t] = (t < 80) ? b_attn_h[t] : 0.f;
}

// ---------------------------------------------------------------------------
// Atom projection (unchanged).
// ---------------------------------------------------------------------------
__global__ __launch_bounds__(256) void atom_proj_kernel(
    const float* __restrict__ atom, const float* __restrict__ W,
    float* __restrict__ ah0)
{
    __shared__ float As[64 * 84];
    __shared__ float Ws[82 * 80];
    int rowBase = blockIdx.x * 64;
    int h = blockIdx.y;
    int t = threadIdx.x;

    for (int e = t; e < 64 * 82; e += 256) {
        int r = e / 82, c = e - r * 82;
        As[r * 84 + c] = atom[(size_t)(rowBase + r) * 82 + c];
    }
    for (int e = t; e < 82 * 80; e += 256) {
        int r = e / 80, c = e - r * 80;
        Ws[e] = W[(size_t)r * 640 + h * 80 + c];
    }
    __syncthreads();

    int tx = t & 15, ty = t >> 4;
    float acc[4][5];
    #pragma unroll
    for (int r = 0; r < 4; r++)
        #pragma unroll
        for (int c = 0; c < 5; c++) acc[r][c] = 0.f;

    for (int k = 0; k < 82; k++) {
        float a0 = As[(ty * 4 + 0) * 84 + k];
        float a1 = As[(ty * 4 + 1) * 84 + k];
        float a2 = As[(ty * 4 + 2) * 84 + k];
        float a3 = As[(ty * 4 + 3) * 84 + k];
        float w[5];
        #pragma unroll
        for (int c = 0; c < 5; c++) w[c] = Ws[k * 80 + c * 16 + tx];
        #pragma unroll
        for (int c = 0; c < 5; c++) {
            acc[0][c] += a0 * w[c];
            acc[1][c] += a1 * w[c];
            acc[2][c] += a2 * w[c];
            acc[3][c] += a3 * w[c];
        }
    }

    #pragma unroll
    for (int r = 0; r < 4; r++) {
        int row = rowBase + ty * 4 + r;
        int b = row >> 6, i = row & 63;
        size_t obase = (((size_t)(h * 32 + b)) * 64 + i) * 80;
        #pragma unroll
        for (int c = 0; c < 5; c++)
            ah0[obase + c * 16 + tx] = acc[r][c];
    }
}

// ---------------------------------------------------------------------------
// Path GEMM via MFMA v2 (R10 structure); P2 now stored fp16, PM3 bf16.
// ---------------------------------------------------------------------------
__global__ __launch_bounds__(320) void path_gemm_mfma(
    const float* __restrict__ A,      // [131072][102]
    const bf16* __restrict__ WTg,     // [2][80][128]
    _Float16* __restrict__ P2h, bf16* __restrict__ PM3)
{
    __shared__ bf16 Als[64 * 136];    // 17.4 KB

    int t = threadIdx.x;
    int bx = blockIdx.x;
    size_t abase = (size_t)bx * 6528;

    int wave = t >> 6, lane = t & 63;
    int ln = lane & 15, quad = lane >> 4;

    const short* Wp = (const short*)WTg;
    short8 bfrag[2][4];
    #pragma unroll
    for (int z = 0; z < 2; z++)
        #pragma unroll
        for (int kc = 0; kc < 4; kc++)
            bfrag[z][kc] = *(const short8*)(
                Wp + (size_t)(z * 80 + wave * 16 + ln) * 128 + kc * 32 + quad * 8);

    for (int e = t; e < 6528; e += 320) {
        int r = e / 102, c = e - r * 102;
        Als[r * 136 + c] = (bf16)A[abase + e];
    }
    for (int e = t; e < 2176; e += 320) {
        int r = e / 34, c = 102 + (e - r * 34);
        Als[r * 136 + c] = (bf16)0.f;
    }
    __syncthreads();

    const short* Ap = (const short*)Als;
    int nc = wave * 16 + ln;

    #pragma unroll
    for (int rt = 0; rt < 4; rt++) {
        f32x4 acc0 = (f32x4){0.f, 0.f, 0.f, 0.f};
        f32x4 acc1 = (f32x4){0.f, 0.f, 0.f, 0.f};
        #pragma unroll
        for (int kc = 0; kc < 4; kc++) {
            short8 af = *(const short8*)(
                Ap + (rt * 16 + ln) * 136 + kc * 32 + quad * 8);
            acc0 = __builtin_amdgcn_mfma_f32_16x16x32_bf16(af, bfrag[0][kc], acc0, 0, 0, 0);
            acc1 = __builtin_amdgcn_mfma_f32_16x16x32_bf16(af, bfrag[1][kc], acc1, 0, 0, 0);
        }
        #pragma unroll
        for (int r = 0; r < 4; r++) {
            int m = rt * 16 + quad * 4 + r;
            size_t row = (size_t)bx * 64 + m;
            P2h[row * 80 + nc] = (_Float16)acc0[r];
            PM3[row * 80 + nc] = (bf16)acc1[r];
        }
    }
}

// ---------------------------------------------------------------------------
// UVAM GEMM v2. grid (256, 4), blockIdx.x = hb. Outputs pre-packed pair
// buffers, all uint[256][64][40]:
//   z=0 -> Ug (fp16 pairs, U + b_attn_h)   [rows = i]
//   z=1 -> Vg (fp16 pairs)                  [rows = j]
//   z=2 -> A1g (bf16 pairs, AM1)            [rows = i]
//   z=3 -> AMg (bf16 pairs, AM2)            [rows = j]
// ---------------------------------------------------------------------------
__global__ __launch_bounds__(256) void uvam_gemm_kernel(
    const float* __restrict__ A, const float* __restrict__ Wuvam,
    const float* __restrict__ buvam,
    unsigned* __restrict__ Ug, unsigned* __restrict__ Vg,
    unsigned* __restrict__ A1g, unsigned* __restrict__ AMg)
{
    __shared__ float As[64 * 105];          // staging, then bounce [64][84]
    __shared__ float Ws[80 * 80];
    int z = blockIdx.y;
    const float* W = Wuvam + z * 6400;
    int hb = blockIdx.x;
    int rowBase = hb * 64;
    int t = threadIdx.x;

    for (int e = t; e < 64 * 80; e += 256) {
        int r = e / 80, c = e - r * 80;
        As[r * 105 + c] = A[(size_t)(rowBase + r) * 80 + c];
    }
    for (int e = t; e < 6400; e += 256) Ws[e] = W[e];
    __syncthreads();

    int tx = t & 15, ty = t >> 4;
    float acc[4][5];
    #pragma unroll
    for (int r = 0; r < 4; r++)
        #pragma unroll
        for (int c = 0; c < 5; c++) acc[r][c] = 0.f;

    for (int k = 0; k < 80; k++) {
        float a0 = As[(ty * 4 + 0) * 105 + k];
        float a1 = As[(ty * 4 + 1) * 105 + k];
        float a2 = As[(ty * 4 + 2) * 105 + k];
        float a3 = As[(ty * 4 + 3) * 105 + k];
        float w[5];
        #pragma unroll
        for (int c = 0; c < 5; c++) w[c] = Ws[k * 80 + c * 16 + tx];
        #pragma unroll
        for (int c = 0; c < 5; c++) {
            acc[0][c] += a0 * w[c];
            acc[1][c] += a1 * w[c];
            acc[2][c] += a2 * w[c];
            acc[3][c] += a3 * w[c];
        }
    }

    float bv[5];
    #pragma unroll
    for (int c = 0; c < 5; c++) bv[c] = buvam[z * 80 + c * 16 + tx];

    __syncthreads();                        // As dead, reuse as bounce [64][84]
    #pragma unroll
    for (int r = 0; r < 4; r++)
        #pragma unroll
        for (int c = 0; c < 5; c++)
            As[(ty * 4 + r) * 84 + c * 16 + tx] = acc[r][c] + bv[c];
    __syncthreads();

    unsigned* o = (z == 0) ? Ug : (z == 1) ? Vg : (z == 2) ? A1g : AMg;
    bool f16 = z < 2;
    size_t obase = (size_t)hb * 2560;
    for (int e = t; e < 2560; e += 256) {
        int j = e / 40, kp = e - j * 40;
        float x0 = As[j * 84 + 2 * kp], x1 = As[j * 84 + 2 * kp + 1];
        o[obase + e] = f16 ? pack2h(x0, x1) : pack2bf(x0, x1);
    }
}

// ---------------------------------------------------------------------------
// Fused attention layer v4: one wave per (hb,i)-pair block structure as R10,
// score in packed fp16 (pk_add/pk_fma + v_dot2_f32_f16), AM2 from global.
// LDS ~16 KB.
// ---------------------------------------------------------------------------
__global__ __launch_bounds__(256, 6) void attn_layer_kernel(
    const unsigned* __restrict__ Ug,   // [256][64][40] fp16 pairs (U+b)
    const unsigned* __restrict__ Vg,   // [256][64][40] fp16 pairs
    const unsigned* __restrict__ A1g,  // [256][64][40] bf16 pairs
    const unsigned* __restrict__ AMg,  // [256][64][40] bf16 pairs
    const _Float16* __restrict__ P2h,  // [131072][80] fp16
    const bf16* __restrict__ PM3,      // [131072][80] bf16
    const float* __restrict__ mask,
    const float* __restrict__ w_attn_o, const float* __restrict__ b_attn_o,
    const float* __restrict__ b_msg_h,
    const float* __restrict__ ah0, float* __restrict__ ah_next)
{
    __shared__ unsigned VBu[64 * 41];   // V rows fp16 pairs, pitch 41
    __shared__ unsigned Uu[8 * 40];     // U rows fp16 pairs
    __shared__ unsigned A1u[8 * 40];    // AM1 rows bf16 pairs
    __shared__ unsigned wo2[40];        // w_attn_o fp16 pairs
    __shared__ float bm[80];
    __shared__ float PS[4][2][64];

    int x = blockIdx.x;
    int hb = x & 255, it = x >> 8;
    int b = hb & 31;
    int i0 = it * 8;
    int t = threadIdx.x;
    size_t gbase = (size_t)hb * 2560;

    for (int e = t; e < 2560; e += 256) {
        int j = e / 40, w = e - j * 40;
        VBu[j * 41 + w] = Vg[gbase + e];
    }
    for (int e = t; e < 320; e += 256) {
        int iq = e / 40, kp = e - iq * 40;
        Uu[e]  = Ug[gbase + (size_t)(i0 + iq) * 40 + kp];
        A1u[e] = A1g[gbase + (size_t)(i0 + iq) * 40 + kp];
    }
    if (t < 40) wo2[t] = pack2h(w_attn_o[2 * t], w_attn_o[2 * t + 1]);
    if (t < 80) bm[t] = b_msg_h[t];
    __syncthreads();

    int wave = t >> 6, lane = t & 63;
    float b0 = b_attn_o[0];
    int iA = i0 + wave * 2;
    const half2v c06 = { (_Float16)0.6f, (_Float16)0.6f };
    const half2v c04 = { (_Float16)0.4f, (_Float16)0.4f };

    float sp[2];

    #pragma unroll
    for (int q = 0; q < 2; q++) {
        int i = iA + q;
        int iq = wave * 2 + q;

        // ---- score: lane = j; P row (80 fp16 = 40 uints) in 2 batches ----
        const uint4v* prow = (const uint4v*)(P2h + ((size_t)(b * 64 + i) * 64 + lane) * 80);
        float s = 0.f;
        #pragma unroll
        for (int half = 0; half < 2; half++) {
            uint4v pr4[5];
            #pragma unroll
            for (int u = 0; u < 5; u++) pr4[u] = prow[half * 5 + u];
            const unsigned* pu = (const unsigned*)pr4;
            int kb = half * 20;
            #pragma unroll
            for (int kp = 0; kp < 20; kp++) {
                half2v p2 = ash2(pu[kp]);
                half2v v2 = ash2(VBu[lane * 41 + kb + kp]);
                half2v u2 = ash2(Uu[iq * 40 + kb + kp]);
                half2v xx = u2 + v2 + p2;
                half2v ax = ash2(asu2(xx) & 0x7FFF7FFFu);
                half2v l  = xx * c06 + ax * c04;      // leaky_relu(0.2)
                s = fdot2acc(l, ash2(wo2[kb + kp]), s);
            }
        }

        float mj = mask[(size_t)b * 4096 + (size_t)i * 64 + lane];
        float sc = (s + b0) * mj;
        float m = sc;
        #pragma unroll
        for (int off = 1; off < 64; off <<= 1) m = fmaxf(m, __shfl_xor(m, off, 64));
        float e = expf(sc - m) * mj;
        float d = e;
        #pragma unroll
        for (int off = 1; off < 64; off <<= 1) d += __shfl_xor(d, off, 64);
        float p = e / (d + 1e-20f) * mj;
        PS[wave][q][lane] = p;
        float spv = p;
        #pragma unroll
        for (int off = 1; off < 64; off <<= 1) spv += __shfl_xor(spv, off, 64);
        sp[q] = spv;
    }

    // ---- message: lanes 0..39 handle k-pairs; AM2 from global (L2-hot) ----
    if (lane < 40) {
        const unsigned* pm0 = (const unsigned*)(PM3 + ((size_t)(b * 64 + iA) * 64) * 80);
        const unsigned* pm1 = pm0 + 2560;
        const unsigned* amp = AMg + gbase;
        float a00 = 0.f, a01 = 0.f, a10 = 0.f, a11 = 0.f;
        #pragma unroll 4
        for (int j = 0; j < 64; j++) {
            unsigned u0 = pm0[j * 40 + lane];
            unsigned u1 = pm1[j * 40 + lane];
            unsigned aw = amp[j * 40 + lane];
            float am0 = bflo(aw), am1 = bfhi(aw);
            float p0 = PS[wave][0][j];
            float p1 = PS[wave][1][j];
            a00 += p0 * (bflo(u0) + am0);
            a01 += p0 * (bfhi(u0) + am1);
            a10 += p1 * (bflo(u1) + am0);
            a11 += p1 * (bfhi(u1) + am1);
        }

        int k0 = 2 * lane, k1 = 2 * lane + 1;
        #pragma unroll
        for (int q = 0; q < 2; q++) {
            int i = iA + q;
            int iq = wave * 2 + q;
            unsigned aw1 = A1u[iq * 40 + lane];
            size_t orow = ((size_t)hb * 64 + i) * 80;
            float mlo = (q == 0) ? a00 : a10;
            float mhi = (q == 0) ? a01 : a11;
            float pre0 = sp[q] * bflo(aw1) + mlo + bm[k0] + ah0[orow + k0];
            float pre1 = sp[q] * bfhi(aw1) + mhi + bm[k1] + ah0[orow + k1];
            ah_next[orow + k0] = pre0 > 0.f ? pre0 : 0.f;
            ah_next[orow + k1] = pre1 > 0.f ? pre1 : 0.f;
        }
    }
}

// ---------------------------------------------------------------------------
// Merge: X[row][f] = concat(atom[row,:82], ah_merged[row,:640]); ld=724.
// ---------------------------------------------------------------------------
__global__ __launch_bounds__(256) void merge_kernel(
    const float* __restrict__ atom, const float* __restrict__ ah,
    float* __restrict__ X)
{
    int r0 = blockIdx.x * 8;
    int t = threadIdx.x;
    for (int e = t; e < 8 * 724; e += 256) {
        int r = e / 724, f = e - r * 724;
        int row = r0 + r;
        float v;
        if (f < 82) {
            v = atom[(size_t)row * 82 + f];
        } else if (f < 722) {
            int q = f - 82, h = q / 80, k = q - h * 80;
            int b = row >> 6, i = row & 63;
            v = ah[(((size_t)(h * 32 + b)) * 64 + i) * 80 + k];
        } else {
            v = 0.f;
        }
        X[(size_t)row * 724 + f] = v;
    }
}

// ---------------------------------------------------------------------------
// Out GEMM: out[row,c] = relu(X[row,:722] @ W[:,c] + b[c])
// ---------------------------------------------------------------------------
__global__ __launch_bounds__(256) void out_gemm_kernel(
    const float* __restrict__ X, const float* __restrict__ W,
    const float* __restrict__ bo, float* __restrict__ out)
{
    __shared__ float As[32 * 132];
    __shared__ float Ws[128 * 68];
    int r0 = blockIdx.x * 32, c0 = blockIdx.y * 64;
    int t = threadIdx.x;
    int tx = t & 15, ty = t >> 4;

    float acc[2][4];
    #pragma unroll
    for (int r = 0; r < 2; r++)
        #pragma unroll
        for (int q = 0; q < 4; q++) acc[r][q] = 0.f;

    for (int ch = 0; ch < 6; ch++) {
        int f0 = ch * 128;
        for (int e4 = t; e4 < 32 * 32; e4 += 256) {
            int r = e4 >> 5, fq = e4 & 31;
            float4v v;
            if (f0 + fq * 4 + 3 <= 723)
                v = *(const float4v*)(X + (size_t)(r0 + r) * 724 + f0 + fq * 4);
            else
                v = (float4v){0.f, 0.f, 0.f, 0.f};
            *(float4v*)(&As[r * 132 + fq * 4]) = v;
        }
        for (int e4 = t; e4 < 128 * 16; e4 += 256) {
            int fr = e4 >> 4, cq = e4 & 15;
            int fg = f0 + fr;
            float4v v;
            if (fg < 722)
                v = *(const float4v*)(W + (size_t)fg * 256 + c0 + cq * 4);
            else
                v = (float4v){0.f, 0.f, 0.f, 0.f};
            *(float4v*)(&Ws[fr * 68 + cq * 4]) = v;
        }
        __syncthreads();

        #pragma unroll 4
        for (int k = 0; k < 128; k++) {
            float a0 = As[(ty * 2 + 0) * 132 + k];
            float a1 = As[(ty * 2 + 1) * 132 + k];
            float4v w = *(const float4v*)(&Ws[k * 68 + tx * 4]);
            #pragma unroll
            for (int q = 0; q < 4; q++) {
                acc[0][q] += a0 * w[q];
                acc[1][q] += a1 * w[q];
            }
        }
        __syncthreads();
    }

    #pragma unroll
    for (int r = 0; r < 2; r++) {
        int row = r0 + ty * 2 + r;
        #pragma unroll
        for (int q = 0; q < 4; q++) {
            int c = c0 + tx * 4 + q;
            float v = acc[r][q] + bo[c];
            out[(size_t)row * 256 + c] = v > 0.f ? v : 0.f;
        }
    }
}

// ---------------------------------------------------------------------------
extern "C" void kernel_launch(void* const* d_in, const int* in_sizes, int n_in,
                              void* d_out, int out_size, void* d_ws, size_t ws_size,
                              hipStream_t stream)
{
    const float* atom_input = (const float*)d_in[0];
    const float* path_input = (const float*)d_in[1];
    const float* path_mask  = (const float*)d_in[2];
    const float* W_atom_i   = (const float*)d_in[3];
    const float* W_attn_h   = (const float*)d_in[4];
    const float* b_attn_h   = (const float*)d_in[5];
    const float* W_attn_o   = (const float*)d_in[6];
    const float* b_attn_o   = (const float*)d_in[7];
    const float* W_msg_h    = (const float*)d_in[8];
    const float* b_msg_h    = (const float*)d_in[9];
    const float* W_atom_o   = (const float*)d_in[10];
    const float* b_atom_o   = (const float*)d_in[11];
    float* out = (float*)d_out;

    // workspace carve-up (~69 MB)
    char* ws = (char*)d_ws;
    float*     ah0  = (float*)ws;     ws += (size_t)16384 * 80 * 4;    // 5.25 MB
    float*     ah1  = (float*)ws;     ws += (size_t)16384 * 80 * 4;    // 5.25 MB
    _Float16*  P2h  = (_Float16*)ws;  ws += (size_t)131072 * 80 * 2;   // 21 MB
    bf16*      PM3  = (bf16*)ws;      ws += (size_t)131072 * 80 * 2;   // 21 MB
    unsigned*  Ug   = (unsigned*)ws;  ws += (size_t)256 * 2560 * 4;    // 2.6 MB
    unsigned*  Vg   = (unsigned*)ws;  ws += (size_t)256 * 2560 * 4;    // 2.6 MB
    unsigned*  A1g  = (unsigned*)ws;  ws += (size_t)256 * 2560 * 4;    // 2.6 MB
    unsigned*  AMg  = (unsigned*)ws;  ws += (size_t)256 * 2560 * 4;    // 2.6 MB
    float*     X    = (float*)ws;     ws += (size_t)2048 * 724 * 4;    // 5.9 MB
    bf16*      WTg  = (bf16*)ws;      ws += (size_t)2 * 80 * 128 * 2;  // 40 KB
    float*     Wuvam= (float*)ws;     ws += (size_t)4 * 80 * 80 * 4;
    float*     buvam= (float*)ws;     ws += (size_t)4 * 80 * 4;

    prep_kernel<<<100, 256, 0, stream>>>(W_attn_h, b_attn_h, W_msg_h,
                                         WTg, Wuvam, buvam);

    atom_proj_kernel<<<dim3(32, 8), 256, 0, stream>>>(atom_input, W_atom_i, ah0);

    path_gemm_mfma<<<2048, 320, 0, stream>>>(path_input, WTg, P2h, PM3);

    const float* cur = ah0;
    float* nxt[2] = { ah1, ah1 };
    for (int layer = 0; layer < 2; layer++) {
        uvam_gemm_kernel<<<dim3(256, 4), 256, 0, stream>>>(
            cur, Wuvam, buvam, Ug, Vg, A1g, AMg);

        attn_layer_kernel<<<2048, 256, 0, stream>>>(
            Ug, Vg, A1g, AMg, P2h, PM3, path_mask, W_attn_o, b_attn_o, b_msg_h,
            ah0, nxt[layer]);
        cur = nxt[layer];
    }

    merge_kernel<<<256, 256, 0, stream>>>(atom_input, cur, X);
    out_gemm_kernel<<<dim3(64, 4), 256, 0, stream>>>(X, W_atom_o, b_atom_o, out);
}

// Round 12
// 294.133 us; speedup vs baseline: 2.9314x; 1.2207x over previous
//
#include <hip/hip_runtime.h>
#include <hip/hip_bf16.h>

typedef __hip_bfloat16 bf16;
typedef _Float16 half2v __attribute__((ext_vector_type(2)));
typedef float  float4v __attribute__((ext_vector_type(4)));
typedef unsigned uint4v __attribute__((ext_vector_type(4)));
typedef short  short8 __attribute__((ext_vector_type(8)));
typedef float  f32x4  __attribute__((ext_vector_type(4)));

// B=32, N=64, F_ATOM=82, F_PATH=102, H=8, DK=80, HIDDEN=256, DEPTH=3
// Inputs fp32, output fp32. hb = h*32 + b.

__device__ inline float bflo(unsigned w) { return __uint_as_float(w << 16); }
__device__ inline float bfhi(unsigned w) { return __uint_as_float(w & 0xFFFF0000u); }
__device__ inline unsigned pack2bf(float x, float y) {
    bf16 a = (bf16)x, c = (bf16)y;
    unsigned short ua = *(unsigned short*)&a, uc = *(unsigned short*)&c;
    return (unsigned)ua | ((unsigned)uc << 16);
}
__device__ inline unsigned pack2h(float x, float y) {
    _Float16 a = (_Float16)x, c = (_Float16)y;
    unsigned short ua = *(unsigned short*)&a, uc = *(unsigned short*)&c;
    return (unsigned)ua | ((unsigned)uc << 16);
}
__device__ inline half2v ash2(unsigned u) { return __builtin_bit_cast(half2v, u); }
__device__ inline unsigned asu2(half2v h) { return __builtin_bit_cast(unsigned, h); }

__device__ inline float fdot2acc(half2v a, half2v b, float s) {
#if __has_builtin(__builtin_amdgcn_fdot2)
    return __builtin_amdgcn_fdot2(a, b, s, false);
#else
    return s + (float)a.x * (float)b.x + (float)a.y * (float)b.y;
#endif
}

// ---------------------------------------------------------------------------
// Prep: WTg[2][80][128] bf16 (path weights, transposed, K-pad 128);
//       WTu[4][80][96] bf16 (uvam weights, transposed, K-pad 96);
//       buvam[4][80] fp32 (z0 = b_attn_h, rest 0).
// ---------------------------------------------------------------------------
__global__ __launch_bounds__(256) void prep_kernel(
    const float* __restrict__ W_attn_h, const float* __restrict__ b_attn_h,
    const float* __restrict__ W_msg_h,
    bf16* __restrict__ WTg, bf16* __restrict__ WTu, float* __restrict__ buvam)
{
    int t = blockIdx.x * 256 + threadIdx.x;
    if (t < 2 * 80 * 128) {
        int z = t / 10240, rem = t - z * 10240;
        int n = rem >> 7, k = rem & 127;
        const float* src = z ? W_msg_h : W_attn_h;
        float v = (k < 102) ? src[(160 + k) * 80 + n] : 0.f;
        WTg[t] = (bf16)v;
    }
    if (t < 4 * 80 * 96) {
        int z = t / 7680, rem = t - z * 7680;
        int n = rem / 96, k = rem - n * 96;
        const float* src = (z < 2) ? W_attn_h : W_msg_h;
        float v = (k < 80) ? src[((z & 1) * 80 + k) * 80 + n] : 0.f;
        WTu[t] = (bf16)v;
    }
    if (t < 320) buvam[t] = (t < 80) ? b_attn_h[t] : 0.f;
}

// ---------------------------------------------------------------------------
// Atom projection (unchanged).
// ---------------------------------------------------------------------------
__global__ __launch_bounds__(256) void atom_proj_kernel(
    const float* __restrict__ atom, const float* __restrict__ W,
    float* __restrict__ ah0)
{
    __shared__ float As[64 * 84];
    __shared__ float Ws[82 * 80];
    int rowBase = blockIdx.x * 64;
    int h = blockIdx.y;
    int t = threadIdx.x;

    for (int e = t; e < 64 * 82; e += 256) {
        int r = e / 82, c = e - r * 82;
        As[r * 84 + c] = atom[(size_t)(rowBase + r) * 82 + c];
    }
    for (int e = t; e < 82 * 80; e += 256) {
        int r = e / 80, c = e - r * 80;
        Ws[e] = W[(size_t)r * 640 + h * 80 + c];
    }
    __syncthreads();

    int tx = t & 15, ty = t >> 4;
    float acc[4][5];
    #pragma unroll
    for (int r = 0; r < 4; r++)
        #pragma unroll
        for (int c = 0; c < 5; c++) acc[r][c] = 0.f;

    for (int k = 0; k < 82; k++) {
        float a0 = As[(ty * 4 + 0) * 84 + k];
        float a1 = As[(ty * 4 + 1) * 84 + k];
        float a2 = As[(ty * 4 + 2) * 84 + k];
        float a3 = As[(ty * 4 + 3) * 84 + k];
        float w[5];
        #pragma unroll
        for (int c = 0; c < 5; c++) w[c] = Ws[k * 80 + c * 16 + tx];
        #pragma unroll
        for (int c = 0; c < 5; c++) {
            acc[0][c] += a0 * w[c];
            acc[1][c] += a1 * w[c];
            acc[2][c] += a2 * w[c];
            acc[3][c] += a3 * w[c];
        }
    }

    #pragma unroll
    for (int r = 0; r < 4; r++) {
        int row = rowBase + ty * 4 + r;
        int b = row >> 6, i = row & 63;
        size_t obase = (((size_t)(h * 32 + b)) * 64 + i) * 80;
        #pragma unroll
        for (int c = 0; c < 5; c++)
            ah0[obase + c * 16 + tx] = acc[r][c];
    }
}

// ---------------------------------------------------------------------------
// Path GEMM via MFMA (R10 structure); P2 fp16, PM3 bf16.
// ---------------------------------------------------------------------------
__global__ __launch_bounds__(320) void path_gemm_mfma(
    const float* __restrict__ A,      // [131072][102]
    const bf16* __restrict__ WTg,     // [2][80][128]
    _Float16* __restrict__ P2h, bf16* __restrict__ PM3)
{
    __shared__ bf16 Als[64 * 136];

    int t = threadIdx.x;
    int bx = blockIdx.x;
    size_t abase = (size_t)bx * 6528;

    int wave = t >> 6, lane = t & 63;
    int ln = lane & 15, quad = lane >> 4;

    const short* Wp = (const short*)WTg;
    short8 bfrag[2][4];
    #pragma unroll
    for (int z = 0; z < 2; z++)
        #pragma unroll
        for (int kc = 0; kc < 4; kc++)
            bfrag[z][kc] = *(const short8*)(
                Wp + (size_t)(z * 80 + wave * 16 + ln) * 128 + kc * 32 + quad * 8);

    for (int e = t; e < 6528; e += 320) {
        int r = e / 102, c = e - r * 102;
        Als[r * 136 + c] = (bf16)A[abase + e];
    }
    for (int e = t; e < 2176; e += 320) {
        int r = e / 34, c = 102 + (e - r * 34);
        Als[r * 136 + c] = (bf16)0.f;
    }
    __syncthreads();

    const short* Ap = (const short*)Als;
    int nc = wave * 16 + ln;

    #pragma unroll
    for (int rt = 0; rt < 4; rt++) {
        f32x4 acc0 = (f32x4){0.f, 0.f, 0.f, 0.f};
        f32x4 acc1 = (f32x4){0.f, 0.f, 0.f, 0.f};
        #pragma unroll
        for (int kc = 0; kc < 4; kc++) {
            short8 af = *(const short8*)(
                Ap + (rt * 16 + ln) * 136 + kc * 32 + quad * 8);
            acc0 = __builtin_amdgcn_mfma_f32_16x16x32_bf16(af, bfrag[0][kc], acc0, 0, 0, 0);
            acc1 = __builtin_amdgcn_mfma_f32_16x16x32_bf16(af, bfrag[1][kc], acc1, 0, 0, 0);
        }
        #pragma unroll
        for (int r = 0; r < 4; r++) {
            int m = rt * 16 + quad * 4 + r;
            size_t row = (size_t)bx * 64 + m;
            P2h[row * 80 + nc] = (_Float16)acc0[r];
            PM3[row * 80 + nc] = (bf16)acc1[r];
        }
    }
}

// ---------------------------------------------------------------------------
// UVAM GEMM via MFMA. grid (hb=256, z=4) x 320 threads (5 waves).
// Wave w owns cols w*16..+15; B-frags (3 K-chunks) in VGPRs from WTu.
// Epilogue: fp32 LDS bounce + pack pairs -> Ug/Vg (fp16) / A1g/AMg (bf16).
// ---------------------------------------------------------------------------
__global__ __launch_bounds__(320) void uvam_gemm_mfma(
    const float* __restrict__ A,        // [16384][80] current a_h
    const bf16* __restrict__ WTu,       // [4][80][96]
    const float* __restrict__ buvam,    // [4][80]
    unsigned* __restrict__ Ug, unsigned* __restrict__ Vg,
    unsigned* __restrict__ A1g, unsigned* __restrict__ AMg)
{
    __shared__ float Bounce[64 * 84];   // 21.5 KB; A-stage aliases front 12 KB
    bf16* Als = (bf16*)Bounce;          // [64][96]

    int t = threadIdx.x;
    int hb = blockIdx.x, z = blockIdx.y;
    int wave = t >> 6, lane = t & 63;
    int ln = lane & 15, quad = lane >> 4;

    const short* Wp = (const short*)(WTu + (size_t)z * 80 * 96);
    short8 bfrag[3];
    #pragma unroll
    for (int kc = 0; kc < 3; kc++)
        bfrag[kc] = *(const short8*)(Wp + (wave * 16 + ln) * 96 + kc * 32 + quad * 8);

    size_t abase = (size_t)hb * 64 * 80;
    for (int e = t; e < 5120; e += 320) {
        int r = e / 80, c = e - r * 80;
        Als[r * 96 + c] = (bf16)A[abase + e];
    }
    for (int e = t; e < 1024; e += 320) {
        int r = e >> 4, c = 80 + (e & 15);
        Als[r * 96 + c] = (bf16)0.f;
    }
    __syncthreads();

    const short* Ap = (const short*)Als;
    f32x4 acc[4];
    #pragma unroll
    for (int rt = 0; rt < 4; rt++) {
        acc[rt] = (f32x4){0.f, 0.f, 0.f, 0.f};
        #pragma unroll
        for (int kc = 0; kc < 3; kc++) {
            short8 af = *(const short8*)(Ap + (rt * 16 + ln) * 96 + kc * 32 + quad * 8);
            acc[rt] = __builtin_amdgcn_mfma_f32_16x16x32_bf16(af, bfrag[kc], acc[rt], 0, 0, 0);
        }
    }
    __syncthreads();                    // A-stage dead

    float bv = buvam[z * 80 + wave * 16 + ln];
    #pragma unroll
    for (int rt = 0; rt < 4; rt++)
        #pragma unroll
        for (int r = 0; r < 4; r++) {
            int m = rt * 16 + quad * 4 + r;
            Bounce[m * 84 + wave * 16 + ln] = acc[rt][r] + bv;
        }
    __syncthreads();

    unsigned* o = (z == 0) ? Ug : (z == 1) ? Vg : (z == 2) ? A1g : AMg;
    bool f16 = z < 2;
    size_t obase = (size_t)hb * 2560;
    for (int e = t; e < 2560; e += 320) {
        int j = e / 40, kp = e - j * 40;
        float x0 = Bounce[j * 84 + 2 * kp], x1 = Bounce[j * 84 + 2 * kp + 1];
        o[obase + e] = f16 ? pack2h(x0, x1) : pack2bf(x0, x1);
    }
}

// ---------------------------------------------------------------------------
// Fused attention layer v5: R11 structure + (a) P half-0 rows prefetched
// before the staging barrier, (b) both i fused in one k-loop per half,
// (c) message unroll 8.
// ---------------------------------------------------------------------------
__global__ __launch_bounds__(256, 5) void attn_layer_kernel(
    const unsigned* __restrict__ Ug,   // [256][64][40] fp16 pairs (U+b)
    const unsigned* __restrict__ Vg,   // [256][64][40] fp16 pairs
    const unsigned* __restrict__ A1g,  // [256][64][40] bf16 pairs
    const unsigned* __restrict__ AMg,  // [256][64][40] bf16 pairs
    const _Float16* __restrict__ P2h,  // [131072][80] fp16
    const bf16* __restrict__ PM3,      // [131072][80] bf16
    const float* __restrict__ mask,
    const float* __restrict__ w_attn_o, const float* __restrict__ b_attn_o,
    const float* __restrict__ b_msg_h,
    const float* __restrict__ ah0, float* __restrict__ ah_next)
{
    __shared__ unsigned VBu[64 * 41];
    __shared__ unsigned Uu[8 * 40];
    __shared__ unsigned A1u[8 * 40];
    __shared__ unsigned wo2[40];
    __shared__ float bm[80];
    __shared__ float PS[4][2][64];

    int x = blockIdx.x;
    int hb = x & 255, it = x >> 8;
    int b = hb & 31;
    int i0 = it * 8;
    int t = threadIdx.x;
    int wave = t >> 6, lane = t & 63;
    int iA = i0 + wave * 2;
    size_t gbase = (size_t)hb * 2560;

    // ---- prefetch P half-0 rows for both i (completed by barrier drain) ----
    const uint4v* prow0 = (const uint4v*)(P2h + ((size_t)(b * 64 + iA) * 64 + lane) * 80);
    const uint4v* prow1 = (const uint4v*)(P2h + ((size_t)(b * 64 + iA + 1) * 64 + lane) * 80);
    uint4v p0a[5], p1a[5];
    #pragma unroll
    for (int u = 0; u < 5; u++) { p0a[u] = prow0[u]; p1a[u] = prow1[u]; }

    // ---- staging ----
    for (int e = t; e < 2560; e += 256) {
        int j = e / 40, w = e - j * 40;
        VBu[j * 41 + w] = Vg[gbase + e];
    }
    for (int e = t; e < 320; e += 256) {
        int iq = e / 40, kp = e - iq * 40;
        Uu[e]  = Ug[gbase + (size_t)(i0 + iq) * 40 + kp];
        A1u[e] = A1g[gbase + (size_t)(i0 + iq) * 40 + kp];
    }
    if (t < 40) wo2[t] = pack2h(w_attn_o[2 * t], w_attn_o[2 * t + 1]);
    if (t < 80) bm[t] = b_msg_h[t];
    __syncthreads();

    float b0 = b_attn_o[0];
    int iq0 = wave * 2, iq1 = wave * 2 + 1;
    const half2v c06 = { (_Float16)0.6f, (_Float16)0.6f };
    const half2v c04 = { (_Float16)0.4f, (_Float16)0.4f };

    // ---- score: both i fused, lane = j ----
    float s0 = 0.f, s1 = 0.f;
    {
        const unsigned* pu0 = (const unsigned*)p0a;
        const unsigned* pu1 = (const unsigned*)p1a;
        #pragma unroll
        for (int kp = 0; kp < 20; kp++) {
            half2v v2 = ash2(VBu[lane * 41 + kp]);
            half2v w2 = ash2(wo2[kp]);
            half2v x0 = ash2(Uu[iq0 * 40 + kp]) + v2 + ash2(pu0[kp]);
            half2v a0 = ash2(asu2(x0) & 0x7FFF7FFFu);
            s0 = fdot2acc(x0 * c06 + a0 * c04, w2, s0);
            half2v x1 = ash2(Uu[iq1 * 40 + kp]) + v2 + ash2(pu1[kp]);
            half2v a1 = ash2(asu2(x1) & 0x7FFF7FFFu);
            s1 = fdot2acc(x1 * c06 + a1 * c04, w2, s1);
        }
    }
    {
        uint4v p0b[5], p1b[5];
        #pragma unroll
        for (int u = 0; u < 5; u++) { p0b[u] = prow0[5 + u]; p1b[u] = prow1[5 + u]; }
        const unsigned* pu0 = (const unsigned*)p0b;
        const unsigned* pu1 = (const unsigned*)p1b;
        #pragma unroll
        for (int kp = 0; kp < 20; kp++) {
            half2v v2 = ash2(VBu[lane * 41 + 20 + kp]);
            half2v w2 = ash2(wo2[20 + kp]);
            half2v x0 = ash2(Uu[iq0 * 40 + 20 + kp]) + v2 + ash2(pu0[kp]);
            half2v a0 = ash2(asu2(x0) & 0x7FFF7FFFu);
            s0 = fdot2acc(x0 * c06 + a0 * c04, w2, s0);
            half2v x1 = ash2(Uu[iq1 * 40 + 20 + kp]) + v2 + ash2(pu1[kp]);
            half2v a1 = ash2(asu2(x1) & 0x7FFF7FFFu);
            s1 = fdot2acc(x1 * c06 + a1 * c04, w2, s1);
        }
    }

    // ---- masked softmax per i (exact reference semantics) ----
    float sp[2];
    #pragma unroll
    for (int q = 0; q < 2; q++) {
        float s = q ? s1 : s0;
        float mj = mask[(size_t)b * 4096 + (size_t)(iA + q) * 64 + lane];
        float sc = (s + b0) * mj;
        float m = sc;
        #pragma unroll
        for (int off = 1; off < 64; off <<= 1) m = fmaxf(m, __shfl_xor(m, off, 64));
        float e = expf(sc - m) * mj;
        float d = e;
        #pragma unroll
        for (int off = 1; off < 64; off <<= 1) d += __shfl_xor(d, off, 64);
        float p = e / (d + 1e-20f) * mj;
        PS[wave][q][lane] = p;
        float spv = p;
        #pragma unroll
        for (int off = 1; off < 64; off <<= 1) spv += __shfl_xor(spv, off, 64);
        sp[q] = spv;
    }

    // ---- message: lanes 0..39 handle k-pairs; AM2 from global (L2-hot) ----
    if (lane < 40) {
        const unsigned* pm0 = (const unsigned*)(PM3 + ((size_t)(b * 64 + iA) * 64) * 80);
        const unsigned* pm1 = pm0 + 2560;
        const unsigned* amp = AMg + gbase;
        float a00 = 0.f, a01 = 0.f, a10 = 0.f, a11 = 0.f;
        #pragma unroll 8
        for (int j = 0; j < 64; j++) {
            unsigned u0 = pm0[j * 40 + lane];
            unsigned u1 = pm1[j * 40 + lane];
            unsigned aw = amp[j * 40 + lane];
            float am0 = bflo(aw), am1 = bfhi(aw);
            float p0 = PS[wave][0][j];
            float p1 = PS[wave][1][j];
            a00 += p0 * (bflo(u0) + am0);
            a01 += p0 * (bfhi(u0) + am1);
            a10 += p1 * (bflo(u1) + am0);
            a11 += p1 * (bfhi(u1) + am1);
        }

        int k0 = 2 * lane, k1 = 2 * lane + 1;
        #pragma unroll
        for (int q = 0; q < 2; q++) {
            int i = iA + q;
            int iq = wave * 2 + q;
            unsigned aw1 = A1u[iq * 40 + lane];
            size_t orow = ((size_t)hb * 64 + i) * 80;
            float mlo = (q == 0) ? a00 : a10;
            float mhi = (q == 0) ? a01 : a11;
            float pre0 = sp[q] * bflo(aw1) + mlo + bm[k0] + ah0[orow + k0];
            float pre1 = sp[q] * bfhi(aw1) + mhi + bm[k1] + ah0[orow + k1];
            ah_next[orow + k0] = pre0 > 0.f ? pre0 : 0.f;
            ah_next[orow + k1] = pre1 > 0.f ? pre1 : 0.f;
        }
    }
}

// ---------------------------------------------------------------------------
// Merge: X[row][f] = concat(atom[row,:82], ah_merged[row,:640]); ld=724.
// ---------------------------------------------------------------------------
__global__ __launch_bounds__(256) void merge_kernel(
    const float* __restrict__ atom, const float* __restrict__ ah,
    float* __restrict__ X)
{
    int r0 = blockIdx.x * 8;
    int t = threadIdx.x;
    for (int e = t; e < 8 * 724; e += 256) {
        int r = e / 724, f = e - r * 724;
        int row = r0 + r;
        float v;
        if (f < 82) {
            v = atom[(size_t)row * 82 + f];
        } else if (f < 722) {
            int q = f - 82, h = q / 80, k = q - h * 80;
            int b = row >> 6, i = row & 63;
            v = ah[(((size_t)(h * 32 + b)) * 64 + i) * 80 + k];
        } else {
            v = 0.f;
        }
        X[(size_t)row * 724 + f] = v;
    }
}

// ---------------------------------------------------------------------------
// Out GEMM: out[row,c] = relu(X[row,:722] @ W[:,c] + b[c])
// ---------------------------------------------------------------------------
__global__ __launch_bounds__(256) void out_gemm_kernel(
    const float* __restrict__ X, const float* __restrict__ W,
    const float* __restrict__ bo, float* __restrict__ out)
{
    __shared__ float As[32 * 132];
    __shared__ float Ws[128 * 68];
    int r0 = blockIdx.x * 32, c0 = blockIdx.y * 64;
    int t = threadIdx.x;
    int tx = t & 15, ty = t >> 4;

    float acc[2][4];
    #pragma unroll
    for (int r = 0; r < 2; r++)
        #pragma unroll
        for (int q = 0; q < 4; q++) acc[r][q] = 0.f;

    for (int ch = 0; ch < 6; ch++) {
        int f0 = ch * 128;
        for (int e4 = t; e4 < 32 * 32; e4 += 256) {
            int r = e4 >> 5, fq = e4 & 31;
            float4v v;
            if (f0 + fq * 4 + 3 <= 723)
                v = *(const float4v*)(X + (size_t)(r0 + r) * 724 + f0 + fq * 4);
            else
                v = (float4v){0.f, 0.f, 0.f, 0.f};
            *(float4v*)(&As[r * 132 + fq * 4]) = v;
        }
        for (int e4 = t; e4 < 128 * 16; e4 += 256) {
            int fr = e4 >> 4, cq = e4 & 15;
            int fg = f0 + fr;
            float4v v;
            if (fg < 722)
                v = *(const float4v*)(W + (size_t)fg * 256 + c0 + cq * 4);
            else
                v = (float4v){0.f, 0.f, 0.f, 0.f};
            *(float4v*)(&Ws[fr * 68 + cq * 4]) = v;
        }
        __syncthreads();

        #pragma unroll 4
        for (int k = 0; k < 128; k++) {
            float a0 = As[(ty * 2 + 0) * 132 + k];
            float a1 = As[(ty * 2 + 1) * 132 + k];
            float4v w = *(const float4v*)(&Ws[k * 68 + tx * 4]);
            #pragma unroll
            for (int q = 0; q < 4; q++) {
                acc[0][q] += a0 * w[q];
                acc[1][q] += a1 * w[q];
            }
        }
        __syncthreads();
    }

    #pragma unroll
    for (int r = 0; r < 2; r++) {
        int row = r0 + ty * 2 + r;
        #pragma unroll
        for (int q = 0; q < 4; q++) {
            int c = c0 + tx * 4 + q;
            float v = acc[r][q] + bo[c];
            out[(size_t)row * 256 + c] = v > 0.f ? v : 0.f;
        }
    }
}

// ---------------------------------------------------------------------------
extern "C" void kernel_launch(void* const* d_in, const int* in_sizes, int n_in,
                              void* d_out, int out_size, void* d_ws, size_t ws_size,
                              hipStream_t stream)
{
    const float* atom_input = (const float*)d_in[0];
    const float* path_input = (const float*)d_in[1];
    const float* path_mask  = (const float*)d_in[2];
    const float* W_atom_i   = (const float*)d_in[3];
    const float* W_attn_h   = (const float*)d_in[4];
    const float* b_attn_h   = (const float*)d_in[5];
    const float* W_attn_o   = (const float*)d_in[6];
    const float* b_attn_o   = (const float*)d_in[7];
    const float* W_msg_h    = (const float*)d_in[8];
    const float* b_msg_h    = (const float*)d_in[9];
    const float* W_atom_o   = (const float*)d_in[10];
    const float* b_atom_o   = (const float*)d_in[11];
    float* out = (float*)d_out;

    // workspace carve-up (~69 MB)
    char* ws = (char*)d_ws;
    float*     ah0  = (float*)ws;     ws += (size_t)16384 * 80 * 4;
    float*     ah1  = (float*)ws;     ws += (size_t)16384 * 80 * 4;
    _Float16*  P2h  = (_Float16*)ws;  ws += (size_t)131072 * 80 * 2;
    bf16*      PM3  = (bf16*)ws;      ws += (size_t)131072 * 80 * 2;
    unsigned*  Ug   = (unsigned*)ws;  ws += (size_t)256 * 2560 * 4;
    unsigned*  Vg   = (unsigned*)ws;  ws += (size_t)256 * 2560 * 4;
    unsigned*  A1g  = (unsigned*)ws;  ws += (size_t)256 * 2560 * 4;
    unsigned*  AMg  = (unsigned*)ws;  ws += (size_t)256 * 2560 * 4;
    float*     X    = (float*)ws;     ws += (size_t)2048 * 724 * 4;
    bf16*      WTg  = (bf16*)ws;      ws += (size_t)2 * 80 * 128 * 2;
    bf16*      WTu  = (bf16*)ws;      ws += (size_t)4 * 80 * 96 * 2;
    float*     buvam= (float*)ws;     ws += (size_t)4 * 80 * 4;

    prep_kernel<<<128, 256, 0, stream>>>(W_attn_h, b_attn_h, W_msg_h,
                                         WTg, WTu, buvam);

    atom_proj_kernel<<<dim3(32, 8), 256, 0, stream>>>(atom_input, W_atom_i, ah0);

    path_gemm_mfma<<<2048, 320, 0, stream>>>(path_input, WTg, P2h, PM3);

    const float* cur = ah0;
    float* nxt[2] = { ah1, ah1 };
    for (int layer = 0; layer < 2; layer++) {
        uvam_gemm_mfma<<<dim3(256, 4), 320, 0, stream>>>(
            cur, WTu, buvam, Ug, Vg, A1g, AMg);

        attn_layer_kernel<<<2048, 256, 0, stream>>>(
            Ug, Vg, A1g, AMg, P2h, PM3, path_mask, W_attn_o, b_attn_o, b_msg_h,
            ah0, nxt[layer]);
        cur = nxt[layer];
    }

    merge_kernel<<<256, 256, 0, stream>>>(atom_input, cur, X);
    out_gemm_kernel<<<dim3(64, 4), 256, 0, stream>>>(X, W_atom_o, b_atom_o, out);
}